// Round 4
// baseline (1197.040 us; speedup 1.0000x reference)
//
#include <hip/hip_runtime.h>
#include <hip/hip_bf16.h>
#include <math.h>

// Memory module: E=768, S=128, T=3, B=64, L=512. fp32 in/out.
// bf16 MFMA GEMMs (fp32 accum). Algebraic folds:
//  Fqk=Wq^T*Wk (write QK), Fwv=Wo*Wv (write V+O), Fvo=Ro*Rv (read V+O).
// scores = mLN . Kz^T + colbias(zv);  upd = A . Vwo^T + const_o;
// out = A_r . memVo^T + bvo.  Per-i score terms cancel in softmax.

typedef __attribute__((ext_vector_type(4))) float f32x4;
typedef __attribute__((ext_vector_type(8))) short short8;
typedef __attribute__((ext_vector_type(4))) unsigned short us4;

__device__ __forceinline__ unsigned short f2bf(float x) {
  union { float f; unsigned u; } v; v.f = x;
  unsigned r = v.u + 0x7fffu + ((v.u >> 16) & 1u);  // RNE
  return (unsigned short)(r >> 16);
}
__device__ __forceinline__ float bf2f(unsigned short u) {
  union { unsigned u; float f; } v; v.u = (unsigned)u << 16; return v.f;
}

__device__ __forceinline__ void g2l16(const void* g, void* l) {
  __builtin_amdgcn_global_load_lds(
      (const __attribute__((address_space(1))) unsigned int*)g,
      (__attribute__((address_space(3))) unsigned int*)l, 16, 0, 0);
}

__device__ __forceinline__ float wsum(float v) {
#pragma unroll
  for (int o = 32; o > 0; o >>= 1) v += __shfl_xor(v, o, 64);
  return v;
}
__device__ __forceinline__ float wmax(float v) {
#pragma unroll
  for (int o = 32; o > 0; o >>= 1) v = fmaxf(v, __shfl_xor(v, o, 64));
  return v;
}

// C = alpha*(A @ B^T) + bias. A[M,K] bf16 lda=K, B[N,K] bf16 ldb=K, C[M,N] ldc=N.
// Batched over z (element strides sA/sB/sC, bias stride sBias). OMODE 0 fp32, 1 bf16.
template<int OMODE, bool BIAS>
__global__ __launch_bounds__(256) void gemm_nt(
    const unsigned short* __restrict__ Ag, const unsigned short* __restrict__ Bg,
    const float* __restrict__ bias, void* __restrict__ Cg,
    int M, int N, int K, long long sA, long long sB, long long sC,
    long long sBias, float alpha)
{
  __shared__ __align__(16) unsigned short As[128 * 32];
  __shared__ __align__(16) unsigned short Bs[128 * 32];

  const int tid  = threadIdx.x;
  const int lane = tid & 63;
  const int wv   = tid >> 6;           // 0..3
  const int wr   = wv >> 1, wc = wv & 1;

  // T1 XCD-aware bijective swizzle (m204)
  const int gx = gridDim.x, gy = gridDim.y, gz = gridDim.z;
  const int nwg = gx * gy * gz;
  const int lin = blockIdx.x + gx * (blockIdx.y + gy * blockIdx.z);
  const int q = nwg >> 3, r = nwg & 7;
  const int xcd = lin & 7, jj = lin >> 3;
  const int w = (xcd < r ? xcd * (q + 1) : r * (q + 1) + (xcd - r) * q) + jj;
  const int tn = w % gx;
  const int t2 = w / gx;
  const int tm = t2 % gy;
  const long long bz = t2 / gy;

  const unsigned short* A = Ag + bz * sA + (size_t)tm * 128 * K;
  const unsigned short* B = Bg + bz * sB + (size_t)tn * 128 * K;

  const int srow = wv * 16 + (lane >> 2);   // staging row (+ i*64)
  const int kby  = (lane & 3) * 16;         // byte offset within 64B k-row

  f32x4 acc[4][4];
#pragma unroll
  for (int a = 0; a < 4; ++a)
#pragma unroll
    for (int b = 0; b < 4; ++b) acc[a][b] = (f32x4)(0.f);

  const int mrow = wr * 64 + (lane & 15);
  const int nrow = wc * 64 + (lane & 15);
  const int koff = (lane >> 4) * 8;

  for (int kt = 0; kt < K; kt += 32) {
#pragma unroll
    for (int i = 0; i < 2; ++i) {
      g2l16((const char*)(A + (size_t)(i * 64 + srow) * K + kt) + kby,
            (char*)As + i * 4096 + wv * 1024);
      g2l16((const char*)(B + (size_t)(i * 64 + srow) * K + kt) + kby,
            (char*)Bs + i * 4096 + wv * 1024);
    }
    __syncthreads();
    short8 af[4], bf[4];
#pragma unroll
    for (int a = 0; a < 4; ++a) af[a] = *(const short8*)&As[(mrow + a * 16) * 32 + koff];
#pragma unroll
    for (int b = 0; b < 4; ++b) bf[b] = *(const short8*)&Bs[(nrow + b * 16) * 32 + koff];
#pragma unroll
    for (int a = 0; a < 4; ++a)
#pragma unroll
      for (int b = 0; b < 4; ++b)
        acc[a][b] = __builtin_amdgcn_mfma_f32_16x16x32_bf16(af[a], bf[b], acc[a][b], 0, 0, 0);
    __syncthreads();
  }

  const size_t cb = (size_t)(bz * sC);
#pragma unroll
  for (int a = 0; a < 4; ++a) {
    const int row0 = tm * 128 + wr * 64 + a * 16 + (lane >> 4) * 4;
#pragma unroll
    for (int b = 0; b < 4; ++b) {
      const int col = tn * 128 + wc * 64 + b * 16 + (lane & 15);
      float bv = 0.f;
      if (BIAS) bv = bias[bz * sBias + col];
#pragma unroll
      for (int rr = 0; rr < 4; ++rr) {
        float v = acc[a][b][rr] * alpha + bv;
        if constexpr (OMODE == 0)
          ((float*)Cg)[cb + (size_t)(row0 + rr) * N + col] = v;
        else
          ((unsigned short*)Cg)[cb + (size_t)(row0 + rr) * N + col] = f2bf(v);
      }
    }
  }
}

// LayerNorm rows of 768 -> bf16. One wave per row, 4 rows/block.
__global__ __launch_bounds__(256) void ln_kernel(
    const float* __restrict__ x, unsigned short* __restrict__ yb,
    const float* __restrict__ g, const float* __restrict__ b)
{
  const int row  = blockIdx.x * 4 + (threadIdx.x >> 6);
  const int lane = threadIdx.x & 63;
  const float* xr = x + (size_t)row * 768;
  float v[12];
  float s = 0.f;
#pragma unroll
  for (int j = 0; j < 12; ++j) { v[j] = xr[lane + 64 * j]; s += v[j]; }
  s = wsum(s);
  const float mu = s * (1.f / 768.f);
  float q = 0.f;
#pragma unroll
  for (int j = 0; j < 12; ++j) { const float d = v[j] - mu; q += d * d; }
  q = wsum(q);
  const float rstd = rsqrtf(q * (1.f / 768.f) + 1e-5f);
  unsigned short* ybr = yb + (size_t)row * 768;
#pragma unroll
  for (int j = 0; j < 12; ++j) {
    const int c = lane + 64 * j;
    ybr[c] = f2bf((v[j] - mu) * rstd * g[c] + b[c]);
  }
}

template<int LR>
__global__ __launch_bounds__(256) void softmax_kernel(
    const float* __restrict__ sc, unsigned short* __restrict__ p)
{
  const int row  = blockIdx.x * 4 + (threadIdx.x >> 6);
  const int lane = threadIdx.x & 63;
  constexpr int PER = LR / 64;
  const float* sr = sc + (size_t)row * LR;
  float v[PER];
  float m = -1e30f;
#pragma unroll
  for (int j = 0; j < PER; ++j) { v[j] = sr[lane + 64 * j]; m = fmaxf(m, v[j]); }
  m = wmax(m);
  float s = 0.f;
#pragma unroll
  for (int j = 0; j < PER; ++j) { v[j] = __expf(v[j] - m); s += v[j]; }
  s = wsum(s);
  const float inv = 1.f / s;
  unsigned short* pr = p + (size_t)row * LR;
#pragma unroll
  for (int j = 0; j < PER; ++j) pr[lane + 64 * j] = f2bf(v[j] * inv);
}

// GRU combine with inline LN: h = LN(mem_row); gates gi/gh bf16 [rows,2304] (r,z,n).
__global__ __launch_bounds__(256) void gru_ln_combine(
    const unsigned short* __restrict__ gi, const unsigned short* __restrict__ gh,
    float* __restrict__ mem, const float* __restrict__ g, const float* __restrict__ b)
{
  __shared__ float ps[4], pq[4];
  const size_t row = blockIdx.x;
  const int tid = threadIdx.x, wv = tid >> 6, lane = tid & 63;
  float* mr = mem + row * 768;
  float v[3];
  float s = 0.f, q = 0.f;
#pragma unroll
  for (int k = 0; k < 3; ++k) {
    v[k] = mr[tid + 256 * k];
    s += v[k]; q += v[k] * v[k];
  }
  s = wsum(s); q = wsum(q);
  if (lane == 0) { ps[wv] = s; pq[wv] = q; }
  __syncthreads();
  s = ps[0] + ps[1] + ps[2] + ps[3];
  q = pq[0] + pq[1] + pq[2] + pq[3];
  const float mu = s * (1.f / 768.f);
  const float var = q * (1.f / 768.f) - mu * mu;
  const float rstd = rsqrtf(var + 1e-5f);
#pragma unroll
  for (int k = 0; k < 3; ++k) {
    const int c = tid + 256 * k;
    const float h = (v[k] - mu) * rstd * g[c] + b[c];
    const float ir  = bf2f(gi[row * 2304 + c]);
    const float iz  = bf2f(gi[row * 2304 + 768 + c]);
    const float in_ = bf2f(gi[row * 2304 + 1536 + c]);
    const float hr  = bf2f(gh[row * 2304 + c]);
    const float hz  = bf2f(gh[row * 2304 + 768 + c]);
    const float hn  = bf2f(gh[row * 2304 + 1536 + c]);
    const float rg = 1.f / (1.f + __expf(-(ir + hr)));
    const float zg = 1.f / (1.f + __expf(-(iz + hz)));
    const float n  = tanhf(in_ + rg * hn);
    mr[c] = (1.f - zg) * n + zg * h;
  }
}

__global__ __launch_bounds__(256) void cvt_bf16(
    const float* __restrict__ in, unsigned short* __restrict__ out, int n4)
{
  const int i = blockIdx.x * 256 + threadIdx.x;
  if (i >= n4) return;
  const float4 v = ((const float4*)in)[i];
  us4 o;
  o.x = f2bf(v.x); o.y = f2bf(v.y); o.z = f2bf(v.z); o.w = f2bf(v.w);
  ((us4*)out)[i] = o;
}

__global__ __launch_bounds__(256) void bcast_slots(
    const float* __restrict__ slots, float* __restrict__ mem)
{
  const int i = blockIdx.x * 256 + threadIdx.x;  // 1,572,864 float4s
  ((float4*)mem)[i] = ((const float4*)slots)[i % 24576];
}

// Batched bf16 transpose: in [R,C] -> out [C,R], batch stride R*C both sides.
__global__ void transpose_bf16(const unsigned short* __restrict__ in,
                               unsigned short* __restrict__ out, int R, int C)
{
  __shared__ unsigned short t[32][33];
  const size_t bofs = (size_t)blockIdx.z * R * C;
  const int c0 = blockIdx.x * 32, r0 = blockIdx.y * 32;
  const int x = threadIdx.x, y = threadIdx.y;
#pragma unroll
  for (int k = 0; k < 32; k += 8)
    t[y + k][x] = in[bofs + (size_t)(r0 + y + k) * C + c0 + x];
  __syncthreads();
#pragma unroll
  for (int k = 0; k < 32; k += 8)
    out[bofs + (size_t)(c0 + y + k) * R + r0 + x] = t[x][y + k];
}

// y[j] = (add?add[j]:0) + sum_k W[j,k]*x[k]  (T=0)  or  sum_k W[k,j]*x[k]  (T=1)
__global__ __launch_bounds__(256) void matvec768(
    const float* __restrict__ W, const float* __restrict__ x,
    const float* __restrict__ add, float* __restrict__ y, int T)
{
  const int j = blockIdx.x * 256 + threadIdx.x;
  if (j >= 768) return;
  float s = add ? add[j] : 0.f;
  if (T) { for (int k = 0; k < 768; ++k) s += W[(size_t)k * 768 + j] * x[k]; }
  else   { for (int k = 0; k < 768; ++k) s += W[(size_t)j * 768 + k] * x[k]; }
  y[j] = s;
}

// out[i] = scl * (dot(src_i, vec) + (cadd ? cadd[0] : 0))
__global__ __launch_bounds__(256) void rowdot768(
    const float* __restrict__ src, const float* __restrict__ vec,
    const float* __restrict__ cadd, float* __restrict__ out, float scl, int rows)
{
  const int row  = blockIdx.x * 4 + (threadIdx.x >> 6);
  if (row >= rows) return;
  const int lane = threadIdx.x & 63;
  const float* r = src + (size_t)row * 768;
  float s = 0.f;
#pragma unroll
  for (int j = 0; j < 12; ++j) s += r[lane + 64 * j] * vec[lane + 64 * j];
  s = wsum(s);
  if (lane == 0) out[row] = scl * (s + (cadd ? cadd[0] : 0.f));
}

__global__ __launch_bounds__(256) void diag_ws(float* __restrict__ out, float wsz, int n) {
  const int i = blockIdx.x * 256 + threadIdx.x;
  if (i < n) out[i] = (i == 0) ? wsz : 0.f;
}

extern "C" void kernel_launch(void* const* d_in, const int* in_sizes, int n_in,
                              void* d_out, int out_size, void* d_ws, size_t ws_size,
                              hipStream_t stream)
{
  const float* z     = (const float*)d_in[0];
  const float* slots = (const float*)d_in[1];
  const float* ln_g  = (const float*)d_in[2];
  const float* ln_b  = (const float*)d_in[3];
  const float* w_wq = (const float*)d_in[4];  const float* w_bq = (const float*)d_in[5];
  const float* w_wk = (const float*)d_in[6];  const float* w_bk = (const float*)d_in[7];
  const float* w_wv = (const float*)d_in[8];  const float* w_bv = (const float*)d_in[9];
  const float* w_wo = (const float*)d_in[10]; const float* w_bo = (const float*)d_in[11];
  const float* r_wq = (const float*)d_in[12]; const float* r_bq = (const float*)d_in[13];
  const float* r_wk = (const float*)d_in[14]; const float* r_bk = (const float*)d_in[15];
  const float* r_wv = (const float*)d_in[16]; const float* r_bv = (const float*)d_in[17];
  const float* r_wo = (const float*)d_in[18]; const float* r_bo = (const float*)d_in[19];
  const float* g_wih = (const float*)d_in[20]; const float* g_bih = (const float*)d_in[21];
  const float* g_whh = (const float*)d_in[22]; const float* g_bhh = (const float*)d_in[23];

  // ---- arena ----
  constexpr size_t O_W    = 0;             // 22MiB weights/folds/vectors
  constexpr size_t O_memf = 23068672;      // 24MiB fp32 memory state
  constexpr size_t O_Kz   = 48234496;      // 48MiB: Kz (loop) | Qr (end)
  constexpr size_t O_VwoT = 98566144;      // 48MiB: VwoT (loop) | memVo/memVoT/Sbr/Abr (end)
  constexpr size_t O_L    = 148897792;     // 73.7MiB phase scratch
  constexpr size_t NEED   = 226230272;

  if (ws_size < NEED) {
    hipLaunchKernelGGL(diag_ws, dim3((out_size + 255) / 256), dim3(256), 0, stream,
                       (float*)d_out, (float)ws_size, out_size);
    return;
  }

  char* ws = (char*)d_ws;
  // W region
  unsigned short* wqb  = (unsigned short*)(ws + O_W);
  unsigned short* wkb  = wqb + 589824;
  unsigned short* wvb  = wkb + 589824;
  unsigned short* wob  = wvb + 589824;
  unsigned short* rqb  = wob + 589824;
  unsigned short* rkb  = rqb + 589824;
  unsigned short* rvb  = rkb + 589824;
  unsigned short* rob  = rvb + 589824;
  unsigned short* wihb = rob + 589824;     // 2304x768
  unsigned short* whhb = wihb + 1769472;   // 2304x768
  unsigned short* Fqk  = whhb + 1769472;   // 768x768 folds
  unsigned short* Fwv  = Fqk + 589824;
  unsigned short* Fvo  = Fwv + 589824;
  unsigned short* tmpT1= Fvo + 589824;
  unsigned short* tmpT2= tmpT1 + 589824;
  float* bih_c   = (float*)(ws + O_W + 22413312);  // 2304, adjacent pair
  float* bhh_c   = bih_c + 2304;
  float* const_o = bhh_c + 2304;           // 768
  float* bvo     = const_o + 768;          // 768
  float* vw      = bvo + 768;              // 768
  float* cw      = vw + 768;               // 1
  float* zv      = cw + 64;                // 32768 (scaled col-bias)
  // persistent
  float* memf = (float*)(ws + O_memf);
  unsigned short* Kz   = (unsigned short*)(ws + O_Kz);
  unsigned short* Qr   = (unsigned short*)(ws + O_Kz);            // end
  unsigned short* VwoT = (unsigned short*)(ws + O_VwoT);
  unsigned short* memVo  = (unsigned short*)(ws + O_VwoT);        // end
  unsigned short* memVoT = (unsigned short*)(ws + O_VwoT + 12582912);
  float*          Sbr    = (float*)(ws + O_VwoT + 25165824);      // 16.8MB
  unsigned short* Abr    = (unsigned short*)(ws + O_VwoT + 41943040);
  // L region
  char* L = ws + O_L;
  unsigned short* zb    = (unsigned short*)(L + 0);          // prologue 48MB
  unsigned short* tmpV  = (unsigned short*)(L + 50331648);   // prologue 12.6MB
  unsigned short* memb  = (unsigned short*)(L + 0);          // loop
  unsigned short* updb  = (unsigned short*)(L + 12582912);
  float*          Sbuf  = (float*)(L + 25165824);            // 16.8MB
  unsigned short* Abuf  = (unsigned short*)(L + 41943040);   // 8.4MB
  unsigned short* gib   = (unsigned short*)(L + 25165824);   // gates (S/A dead)
  unsigned short* ghb   = (unsigned short*)(L + 44040192);
  unsigned short* zb2   = (unsigned short*)(L + 0);          // end 48MB
  unsigned short* Kr    = (unsigned short*)(L + 50331648);   // end 12.6MB
  unsigned short* memb2 = (unsigned short*)(L + 62914560);   // end 12.6MB

  const float scale = 1.0f / sqrtf(768.f);

  auto cvt = [&](const float* src, unsigned short* dst, size_t n) {
    const int n4 = (int)(n / 4);
    hipLaunchKernelGGL(cvt_bf16, dim3((n4 + 255) / 256), dim3(256), 0, stream, src, dst, n4);
  };

  // ---- prologue: weight converts ----
  cvt(w_wq, wqb, 589824);  cvt(w_wk, wkb, 589824);
  cvt(w_wv, wvb, 589824);  cvt(w_wo, wob, 589824);
  cvt(r_wq, rqb, 589824);  cvt(r_wk, rkb, 589824);
  cvt(r_wv, rvb, 589824);  cvt(r_wo, rob, 589824);
  cvt(g_wih, wihb, 1769472); cvt(g_whh, whhb, 1769472);
  hipMemcpyAsync(bih_c, g_bih, 2304 * 4, hipMemcpyDeviceToDevice, stream);
  hipMemcpyAsync(bhh_c, g_bhh, 2304 * 4, hipMemcpyDeviceToDevice, stream);

  // folds: Fqk = Wq^T*Wk ; Fwv = Wo*Wv ; Fvo = Ro*Rv
  hipLaunchKernelGGL(transpose_bf16, dim3(24, 24, 1), dim3(32, 8), 0, stream, wqb, tmpT1, 768, 768);
  hipLaunchKernelGGL(transpose_bf16, dim3(24, 24, 1), dim3(32, 8), 0, stream, wkb, tmpT2, 768, 768);
  hipLaunchKernelGGL((gemm_nt<1, false>), dim3(6, 6, 1), dim3(256), 0, stream,
      tmpT1, tmpT2, (const float*)nullptr, (void*)Fqk, 768, 768, 768, 0ll, 0ll, 0ll, 0ll, 1.0f);
  hipLaunchKernelGGL(transpose_bf16, dim3(24, 24, 1), dim3(32, 8), 0, stream, wvb, tmpT1, 768, 768);
  hipLaunchKernelGGL((gemm_nt<1, false>), dim3(6, 6, 1), dim3(256), 0, stream,
      wob, tmpT1, (const float*)nullptr, (void*)Fwv, 768, 768, 768, 0ll, 0ll, 0ll, 0ll, 1.0f);
  hipLaunchKernelGGL(transpose_bf16, dim3(24, 24, 1), dim3(32, 8), 0, stream, rvb, tmpT1, 768, 768);
  hipLaunchKernelGGL((gemm_nt<1, false>), dim3(6, 6, 1), dim3(256), 0, stream,
      rob, tmpT1, (const float*)nullptr, (void*)Fvo, 768, 768, 768, 0ll, 0ll, 0ll, 0ll, 1.0f);

  // bias vectors: vw = Wk^T*bq ; const_o = Wo*bv+bo ; bvo = Ro*bv_r+bo_r ; cw = bq.bk
  hipLaunchKernelGGL(matvec768, dim3(3), dim3(256), 0, stream, w_wk, w_bq, (const float*)nullptr, vw, 1);
  hipLaunchKernelGGL(matvec768, dim3(3), dim3(256), 0, stream, w_wo, w_bv, w_bo, const_o, 0);
  hipLaunchKernelGGL(matvec768, dim3(3), dim3(256), 0, stream, r_wo, r_bv, r_bo, bvo, 0);
  hipLaunchKernelGGL(rowdot768, dim3(1), dim3(256), 0, stream, w_bq, w_bk, (const float*)nullptr, cw, 1.0f, 1);
  hipLaunchKernelGGL(rowdot768, dim3(8192), dim3(256), 0, stream, z, vw, cw, zv, scale, 32768);

  cvt(z, zb, 32768ull * 768);
  hipLaunchKernelGGL(bcast_slots, dim3(6144), dim3(256), 0, stream, slots, memf);

  // Kz = z . Fqk^T  [32768,768]
  hipLaunchKernelGGL((gemm_nt<1, false>), dim3(6, 256, 1), dim3(256), 0, stream,
      zb, Fqk, (const float*)nullptr, (void*)Kz, 32768, 768, 768, 0ll, 0ll, 0ll, 0ll, 1.0f);
  // Vwo = z . Fwv^T, chunked + per-batch transpose into VwoT [64][768,512]
  for (int c = 0; c < 4; ++c) {
    hipLaunchKernelGGL((gemm_nt<1, false>), dim3(6, 64, 1), dim3(256), 0, stream,
        zb + (size_t)c * 6291456, Fwv, (const float*)nullptr, (void*)tmpV,
        8192, 768, 768, 0ll, 0ll, 0ll, 0ll, 1.0f);
    hipLaunchKernelGGL(transpose_bf16, dim3(24, 16, 16), dim3(32, 8), 0, stream,
        tmpV, VwoT + (size_t)c * 6291456, 512, 768);
  }

  const long long sA_g = (long long)(memb - updb);   // z=1 -> memb chunk
  const long long sC_g = (long long)(ghb - gib);

  // ---- T=3 recurrence ----
  for (int t = 0; t < 3; ++t) {
    hipLaunchKernelGGL(ln_kernel, dim3(2048), dim3(256), 0, stream, memf, memb, ln_g, ln_b);
    // scores = scale*(mLN . Kz^T) + zv[j]
    hipLaunchKernelGGL((gemm_nt<0, true>), dim3(4, 1, 64), dim3(256), 0, stream,
        memb, Kz, zv, (void*)Sbuf, 128, 512, 768,
        98304ll, 393216ll, 65536ll, 512ll, scale);
    hipLaunchKernelGGL((softmax_kernel<512>), dim3(2048), dim3(256), 0, stream, Sbuf, Abuf);
    // upd = A . VwoT^T + const_o
    hipLaunchKernelGGL((gemm_nt<1, true>), dim3(6, 1, 64), dim3(256), 0, stream,
        Abuf, VwoT, const_o, (void*)updb, 128, 768, 512,
        65536ll, 393216ll, 98304ll, 0ll, 1.0f);
    for (int c = 0; c < 2; ++c) {  // gates: gi,gh in one batched launch (4096 rows)
      hipLaunchKernelGGL((gemm_nt<1, true>), dim3(18, 32, 2), dim3(256), 0, stream,
          updb + (size_t)c * 3145728, wihb, bih_c, (void*)gib,
          4096, 2304, 768, sA_g, 1769472ll, sC_g, 2304ll, 1.0f);
      hipLaunchKernelGGL(gru_ln_combine, dim3(4096), dim3(256), 0, stream,
          gib, ghb, memf + (size_t)c * 3145728, ln_g, ln_b);
    }
  }

  // ---- read attention: out = A_r . memVo + bvo ----
  cvt(memf, memb2, 8192ull * 768);
  hipLaunchKernelGGL((gemm_nt<1, true>), dim3(6, 64, 1), dim3(256), 0, stream,
      memb2, rkb, r_bk, (void*)Kr, 8192, 768, 768, 0ll, 0ll, 0ll, 0ll, 1.0f);
  hipLaunchKernelGGL((gemm_nt<1, false>), dim3(6, 64, 1), dim3(256), 0, stream,
      memb2, Fvo, (const float*)nullptr, (void*)memVo, 8192, 768, 768, 0ll, 0ll, 0ll, 0ll, 1.0f);
  hipLaunchKernelGGL(transpose_bf16, dim3(24, 4, 64), dim3(32, 8), 0, stream,
      memVo, memVoT, 128, 768);
  cvt(z, zb2, 32768ull * 768);
  hipLaunchKernelGGL((gemm_nt<1, true>), dim3(6, 256, 1), dim3(256), 0, stream,
      zb2, rqb, r_bq, (void*)Qr, 32768, 768, 768, 0ll, 0ll, 0ll, 0ll, 1.0f);
  hipLaunchKernelGGL((gemm_nt<0, false>), dim3(1, 4, 64), dim3(256), 0, stream,
      Qr, Kr, (const float*)nullptr, (void*)Sbr, 512, 128, 768,
      393216ll, 98304ll, 65536ll, 0ll, scale);
  hipLaunchKernelGGL((softmax_kernel<128>), dim3(8192), dim3(256), 0, stream, Sbr, Abr);
  hipLaunchKernelGGL((gemm_nt<0, true>), dim3(6, 4, 64), dim3(256), 0, stream,
      Abr, memVoT, bvo, d_out, 512, 768, 128,
      65536ll, 98304ll, 393216ll, 0ll, 1.0f);
}

// Round 5
// 1107.188 us; speedup vs baseline: 1.0812x; 1.0812x over previous
//
#include <hip/hip_runtime.h>
#include <hip/hip_bf16.h>
#include <math.h>

// Memory module: E=768, S=128, T=3, B=64, L=512. fp32 in/out.
// bf16 MFMA GEMMs (fp32 accum). Algebraic folds:
//  Fqk=Wq^T*Wk, Fwv=Wo*Wv, Fvo=Ro*Rv, Frq=Rq^T*Rk.
// write scores = scale*(mLN.Kz^T) + zv[j], Kz = z.Fqk^T (hoisted)
// upd = A.Vwo^T + const_o, Vwo = z.Fwv^T (hoisted)
// read scores = scale*(z.memFr^T) + colb[j], memFr = mem.Frq^T
// out = A_r.(mem.Fvo^T)^T + bvo. Row-terms cancel in softmax.

typedef __attribute__((ext_vector_type(4))) float f32x4;
typedef __attribute__((ext_vector_type(8))) short short8;
typedef __attribute__((ext_vector_type(4))) unsigned short us4;

__device__ __forceinline__ unsigned short f2bf(float x) {
  union { float f; unsigned u; } v; v.f = x;
  unsigned r = v.u + 0x7fffu + ((v.u >> 16) & 1u);  // RNE
  return (unsigned short)(r >> 16);
}
__device__ __forceinline__ float bf2f(unsigned short u) {
  union { unsigned u; float f; } v; v.u = (unsigned)u << 16; return v.f;
}

__device__ __forceinline__ void g2l16(const void* g, void* l) {
  __builtin_amdgcn_global_load_lds(
      (const __attribute__((address_space(1))) unsigned int*)g,
      (__attribute__((address_space(3))) unsigned int*)l, 16, 0, 0);
}

__device__ __forceinline__ float wsum(float v) {
#pragma unroll
  for (int o = 32; o > 0; o >>= 1) v += __shfl_xor(v, o, 64);
  return v;
}
__device__ __forceinline__ float wmax(float v) {
#pragma unroll
  for (int o = 32; o > 0; o >>= 1) v = fmaxf(v, __shfl_xor(v, o, 64));
  return v;
}

// C = alpha*(A @ B^T) + bias. A[M,K] bf16 lda=K, B[N,K] bf16 ldb=K, C[M,N] ldc=N.
// Batched over z (element strides). OMODE 0 fp32, 1 bf16. T1 XCD swizzle (m204).
template<int OMODE, bool BIAS>
__global__ __launch_bounds__(256) void gemm_nt(
    const unsigned short* __restrict__ Ag, const unsigned short* __restrict__ Bg,
    const float* __restrict__ bias, void* __restrict__ Cg,
    int M, int N, int K, long long sA, long long sB, long long sC,
    long long sBias, float alpha)
{
  __shared__ __align__(16) unsigned short As[128 * 32];
  __shared__ __align__(16) unsigned short Bs[128 * 32];

  const int tid  = threadIdx.x;
  const int lane = tid & 63;
  const int wv   = tid >> 6;           // 0..3
  const int wr   = wv >> 1, wc = wv & 1;

  const int gx = gridDim.x, gy = gridDim.y, gz = gridDim.z;
  const int nwg = gx * gy * gz;
  const int lin = blockIdx.x + gx * (blockIdx.y + gy * blockIdx.z);
  const int q = nwg >> 3, r = nwg & 7;
  const int xcd = lin & 7, jj = lin >> 3;
  const int w = (xcd < r ? xcd * (q + 1) : r * (q + 1) + (xcd - r) * q) + jj;
  const int tn = w % gx;
  const int t2 = w / gx;
  const int tm = t2 % gy;
  const long long bz = t2 / gy;

  const unsigned short* A = Ag + bz * sA + (size_t)tm * 128 * K;
  const unsigned short* B = Bg + bz * sB + (size_t)tn * 128 * K;

  const int srow = wv * 16 + (lane >> 2);
  const int kby  = (lane & 3) * 16;

  f32x4 acc[4][4];
#pragma unroll
  for (int a = 0; a < 4; ++a)
#pragma unroll
    for (int b = 0; b < 4; ++b) acc[a][b] = (f32x4)(0.f);

  const int mrow = wr * 64 + (lane & 15);
  const int nrow = wc * 64 + (lane & 15);
  const int koff = (lane >> 4) * 8;

  for (int kt = 0; kt < K; kt += 32) {
#pragma unroll
    for (int i = 0; i < 2; ++i) {
      g2l16((const char*)(A + (size_t)(i * 64 + srow) * K + kt) + kby,
            (char*)As + i * 4096 + wv * 1024);
      g2l16((const char*)(B + (size_t)(i * 64 + srow) * K + kt) + kby,
            (char*)Bs + i * 4096 + wv * 1024);
    }
    __syncthreads();
    short8 af[4], bf[4];
#pragma unroll
    for (int a = 0; a < 4; ++a) af[a] = *(const short8*)&As[(mrow + a * 16) * 32 + koff];
#pragma unroll
    for (int b = 0; b < 4; ++b) bf[b] = *(const short8*)&Bs[(nrow + b * 16) * 32 + koff];
#pragma unroll
    for (int a = 0; a < 4; ++a)
#pragma unroll
      for (int b = 0; b < 4; ++b)
        acc[a][b] = __builtin_amdgcn_mfma_f32_16x16x32_bf16(af[a], bf[b], acc[a][b], 0, 0, 0);
    __syncthreads();
  }

  const size_t cb = (size_t)(bz * sC);
#pragma unroll
  for (int a = 0; a < 4; ++a) {
    const int row0 = tm * 128 + wr * 64 + a * 16 + (lane >> 4) * 4;
#pragma unroll
    for (int b = 0; b < 4; ++b) {
      const int col = tn * 128 + wc * 64 + b * 16 + (lane & 15);
      float bv = 0.f;
      if (BIAS) bv = bias[bz * sBias + col];
#pragma unroll
      for (int rr = 0; rr < 4; ++rr) {
        float v = acc[a][b][rr] * alpha + bv;
        if constexpr (OMODE == 0)
          ((float*)Cg)[cb + (size_t)(row0 + rr) * N + col] = v;
        else
          ((unsigned short*)Cg)[cb + (size_t)(row0 + rr) * N + col] = f2bf(v);
      }
    }
  }
}

// LayerNorm rows of 768 -> bf16. One wave per row, 4 rows/block.
__global__ __launch_bounds__(256) void ln_kernel(
    const float* __restrict__ x, unsigned short* __restrict__ yb,
    const float* __restrict__ g, const float* __restrict__ b)
{
  const int row  = blockIdx.x * 4 + (threadIdx.x >> 6);
  const int lane = threadIdx.x & 63;
  const float* xr = x + (size_t)row * 768;
  float v[12];
  float s = 0.f;
#pragma unroll
  for (int j = 0; j < 12; ++j) { v[j] = xr[lane + 64 * j]; s += v[j]; }
  s = wsum(s);
  const float mu = s * (1.f / 768.f);
  float q = 0.f;
#pragma unroll
  for (int j = 0; j < 12; ++j) { const float d = v[j] - mu; q += d * d; }
  q = wsum(q);
  const float rstd = rsqrtf(q * (1.f / 768.f) + 1e-5f);
  unsigned short* ybr = yb + (size_t)row * 768;
#pragma unroll
  for (int j = 0; j < 12; ++j) {
    const int c = lane + 64 * j;
    ybr[c] = f2bf((v[j] - mu) * rstd * g[c] + b[c]);
  }
}

template<int LR>
__global__ __launch_bounds__(256) void softmax_kernel(
    const float* __restrict__ sc, unsigned short* __restrict__ p)
{
  const int row  = blockIdx.x * 4 + (threadIdx.x >> 6);
  const int lane = threadIdx.x & 63;
  constexpr int PER = LR / 64;
  const float* sr = sc + (size_t)row * LR;
  float v[PER];
  float m = -1e30f;
#pragma unroll
  for (int j = 0; j < PER; ++j) { v[j] = sr[lane + 64 * j]; m = fmaxf(m, v[j]); }
  m = wmax(m);
  float s = 0.f;
#pragma unroll
  for (int j = 0; j < PER; ++j) { v[j] = __expf(v[j] - m); s += v[j]; }
  s = wsum(s);
  const float inv = 1.f / s;
  unsigned short* pr = p + (size_t)row * LR;
#pragma unroll
  for (int j = 0; j < PER; ++j) pr[lane + 64 * j] = f2bf(v[j] * inv);
}

// GRU combine with inline LN over memf rows. gates bf16 [rows,2304] (r,z,n).
__global__ __launch_bounds__(256) void gru_ln_combine(
    const unsigned short* __restrict__ gi, const unsigned short* __restrict__ gh,
    float* __restrict__ mem, const float* __restrict__ g, const float* __restrict__ b)
{
  __shared__ float ps[4], pq[4];
  const size_t row = blockIdx.x;
  const int tid = threadIdx.x, wv = tid >> 6, lane = tid & 63;
  float* mr = mem + row * 768;
  float v[3];
  float s = 0.f, q = 0.f;
#pragma unroll
  for (int k = 0; k < 3; ++k) {
    v[k] = mr[tid + 256 * k];
    s += v[k]; q += v[k] * v[k];
  }
  s = wsum(s); q = wsum(q);
  if (lane == 0) { ps[wv] = s; pq[wv] = q; }
  __syncthreads();
  s = ps[0] + ps[1] + ps[2] + ps[3];
  q = pq[0] + pq[1] + pq[2] + pq[3];
  const float mu = s * (1.f / 768.f);
  const float var = q * (1.f / 768.f) - mu * mu;
  const float rstd = rsqrtf(var + 1e-5f);
#pragma unroll
  for (int k = 0; k < 3; ++k) {
    const int c = tid + 256 * k;
    const float h = (v[k] - mu) * rstd * g[c] + b[c];
    const float ir  = bf2f(gi[row * 2304 + c]);
    const float iz  = bf2f(gi[row * 2304 + 768 + c]);
    const float in_ = bf2f(gi[row * 2304 + 1536 + c]);
    const float hr  = bf2f(gh[row * 2304 + c]);
    const float hz  = bf2f(gh[row * 2304 + 768 + c]);
    const float hn  = bf2f(gh[row * 2304 + 1536 + c]);
    const float rg = 1.f / (1.f + __expf(-(ir + hr)));
    const float zg = 1.f / (1.f + __expf(-(iz + hz)));
    const float n  = tanhf(in_ + rg * hn);
    mr[c] = (1.f - zg) * n + zg * h;
  }
}

__global__ __launch_bounds__(256) void cvt_bf16(
    const float* __restrict__ in, unsigned short* __restrict__ out, int n4)
{
  const int i = blockIdx.x * 256 + threadIdx.x;
  if (i >= n4) return;
  const float4 v = ((const float4*)in)[i];
  us4 o;
  o.x = f2bf(v.x); o.y = f2bf(v.y); o.z = f2bf(v.z); o.w = f2bf(v.w);
  ((us4*)out)[i] = o;
}

// Merged weight conversion: 10 fp32 sources -> contiguous bf16 arena region.
__global__ __launch_bounds__(256) void cvt_weights(
    const float* p0, const float* p1, const float* p2, const float* p3,
    const float* p4, const float* p5, const float* p6, const float* p7,
    const float* p8, const float* p9, unsigned short* __restrict__ dst)
{
  const int i = blockIdx.x * 256 + threadIdx.x;  // f4 index, total 2064384
  if (i >= 2064384) return;
  const float* src; int base;
  if      (i < 147456)  { src = p0; base = 0; }
  else if (i < 294912)  { src = p1; base = 147456; }
  else if (i < 442368)  { src = p2; base = 294912; }
  else if (i < 589824)  { src = p3; base = 442368; }
  else if (i < 737280)  { src = p4; base = 589824; }
  else if (i < 884736)  { src = p5; base = 737280; }
  else if (i < 1032192) { src = p6; base = 884736; }
  else if (i < 1179648) { src = p7; base = 1032192; }
  else if (i < 1622016) { src = p8; base = 1179648; }
  else                  { src = p9; base = 1622016; }
  const float4 v = ((const float4*)src)[i - base];
  us4 o;
  o.x = f2bf(v.x); o.y = f2bf(v.y); o.z = f2bf(v.z); o.w = f2bf(v.w);
  ((us4*)dst)[i] = o;
}

__global__ __launch_bounds__(256) void bcast_slots(
    const float* __restrict__ slots, float* __restrict__ mem)
{
  const int i = blockIdx.x * 256 + threadIdx.x;
  ((float4*)mem)[i] = ((const float4*)slots)[i % 24576];
}

// Batched bf16 transpose: in [R,C] -> out [C,R], batch stride R*C both sides.
__global__ void transpose_bf16(const unsigned short* __restrict__ in,
                               unsigned short* __restrict__ out, int R, int C)
{
  __shared__ unsigned short t[32][33];
  const size_t bofs = (size_t)blockIdx.z * R * C;
  const int c0 = blockIdx.x * 32, r0 = blockIdx.y * 32;
  const int x = threadIdx.x, y = threadIdx.y;
#pragma unroll
  for (int k = 0; k < 32; k += 8)
    t[y + k][x] = in[bofs + (size_t)(r0 + y + k) * C + c0 + x];
  __syncthreads();
#pragma unroll
  for (int k = 0; k < 32; k += 8)
    out[bofs + (size_t)(c0 + y + k) * R + r0 + x] = t[x][y + k];
}

// y[j] = sum_k W[k,j]*x[k]  (thread-per-output, coalesced row reads)
__global__ __launch_bounds__(256) void matvec_T(
    const float* __restrict__ W, const float* __restrict__ x, float* __restrict__ y)
{
  const int j = blockIdx.x * 256 + threadIdx.x;
  if (j >= 768) return;
  float s = 0.f;
  for (int k = 0; k < 768; ++k) s += W[(size_t)k * 768 + j] * x[k];
  y[j] = s;
}

// y[row] = add[row] + dot(W[row,:], x). Wave per row, 4 rows/block.
__global__ __launch_bounds__(256) void matvec_row(
    const float* __restrict__ W, const float* __restrict__ x,
    const float* __restrict__ add, float* __restrict__ y)
{
  const int row  = blockIdx.x * 4 + (threadIdx.x >> 6);
  if (row >= 768) return;
  const int lane = threadIdx.x & 63;
  const float* r = W + (size_t)row * 768;
  float s = 0.f;
#pragma unroll
  for (int j = 0; j < 12; ++j) s += r[lane + 64 * j] * x[lane + 64 * j];
  s = wsum(s);
  if (lane == 0) y[row] = s + add[row];
}

// out[i] = scl * (dot(src_i, vec) + (cadd ? cadd[0] : 0))
__global__ __launch_bounds__(256) void rowdot768(
    const float* __restrict__ src, const float* __restrict__ vec,
    const float* __restrict__ cadd, float* __restrict__ out, float scl, int rows)
{
  const int row  = blockIdx.x * 4 + (threadIdx.x >> 6);
  if (row >= rows) return;
  const int lane = threadIdx.x & 63;
  const float* r = src + (size_t)row * 768;
  float s = 0.f;
#pragma unroll
  for (int j = 0; j < 12; ++j) s += r[lane + 64 * j] * vec[lane + 64 * j];
  s = wsum(s);
  if (lane == 0) out[row] = scl * (s + (cadd ? cadd[0] : 0.f));
}

__global__ __launch_bounds__(256) void diag_ws(float* __restrict__ out, float wsz, int n) {
  const int i = blockIdx.x * 256 + threadIdx.x;
  if (i < n) out[i] = (i == 0) ? wsz : 0.f;
}

extern "C" void kernel_launch(void* const* d_in, const int* in_sizes, int n_in,
                              void* d_out, int out_size, void* d_ws, size_t ws_size,
                              hipStream_t stream)
{
  const float* z     = (const float*)d_in[0];
  const float* slots = (const float*)d_in[1];
  const float* ln_g  = (const float*)d_in[2];
  const float* ln_b  = (const float*)d_in[3];
  const float* w_wq = (const float*)d_in[4];  const float* w_bq = (const float*)d_in[5];
  const float* w_wk = (const float*)d_in[6];  const float* w_bk = (const float*)d_in[7];
  const float* w_wv = (const float*)d_in[8];  const float* w_bv = (const float*)d_in[9];
  const float* w_wo = (const float*)d_in[10]; const float* w_bo = (const float*)d_in[11];
  const float* r_wq = (const float*)d_in[12]; const float* r_bq = (const float*)d_in[13];
  const float* r_wk = (const float*)d_in[14]; const float* r_bk = (const float*)d_in[15];
  const float* r_wv = (const float*)d_in[16]; const float* r_bv = (const float*)d_in[17];
  const float* r_wo = (const float*)d_in[18]; const float* r_bo = (const float*)d_in[19];
  const float* g_wih = (const float*)d_in[20]; const float* g_bih = (const float*)d_in[21];
  const float* g_whh = (const float*)d_in[22]; const float* g_bhh = (const float*)d_in[23];

  // ---- arena (bytes) ----
  constexpr size_t O_memf = 23787776;
  constexpr size_t O_Kz   = 48953600;   // 48MB: tmpV (pre-Kz) -> Kz
  constexpr size_t O_VwoT = 99285248;   // 48MB: VwoT | end: memVo/memVoT/Sbr/Abr
  constexpr size_t O_L    = 149616896;  // 73.1MB scratch
  constexpr size_t NEED   = 226230272;

  if (ws_size < NEED) {
    hipLaunchKernelGGL(diag_ws, dim3((out_size + 255) / 256), dim3(256), 0, stream,
                       (float*)d_out, (float)ws_size, out_size);
    return;
  }

  char* ws = (char*)d_ws;
  // W region (contiguous bf16 weights first: cvt_weights dst)
  unsigned short* wqb  = (unsigned short*)(ws + 0);
  unsigned short* wkb  = wqb + 589824;
  unsigned short* wvb  = wkb + 589824;
  unsigned short* wob  = wvb + 589824;
  unsigned short* rqb  = wob + 589824;
  unsigned short* rkb  = rqb + 589824;
  unsigned short* rvb  = rkb + 589824;
  unsigned short* rob  = rvb + 589824;
  unsigned short* wihb = rob + 589824;     // 2304x768
  unsigned short* whhb = wihb + 1769472;   // end 16515072 B
  unsigned short* Fqk  = (unsigned short*)(ws + 16515072);
  unsigned short* Fwv  = Fqk + 589824;
  unsigned short* Fvo  = Fwv + 589824;
  unsigned short* Frq  = Fvo + 589824;
  unsigned short* tmpT1= Frq + 589824;
  unsigned short* tmpT2= tmpT1 + 589824;   // end 23592960 B
  float* bih_c   = (float*)(ws + 23592960);   // 2304
  float* bhh_c   = bih_c + 2304;
  float* const_o = bhh_c + 2304;              // 768
  float* bvo     = const_o + 768;
  float* vw      = bvo + 768;
  float* vr      = vw + 768;
  float* cw      = vr + 768;                  // 64
  float* zv      = cw + 64;                   // 32768
  float* colb    = zv + 32768;                // 8192 -> end 23787776
  // persistent
  float* memf = (float*)(ws + O_memf);
  unsigned short* tmpV = (unsigned short*)(ws + O_Kz);   // pre-Kz alias
  unsigned short* Kz   = (unsigned short*)(ws + O_Kz);
  unsigned short* VwoT = (unsigned short*)(ws + O_VwoT);
  unsigned short* memVo  = (unsigned short*)(ws + O_VwoT);             // end
  unsigned short* memVoT = (unsigned short*)(ws + O_VwoT + 12582912);  // end
  float*          Sbr    = (float*)(ws + O_VwoT + 25165824);           // end
  unsigned short* Abr    = (unsigned short*)(ws + O_VwoT + 41943040);  // end
  // L region
  char* L = ws + O_L;
  unsigned short* zb    = (unsigned short*)(L + 0);          // prologue 48MB
  unsigned short* memb  = (unsigned short*)(L + 0);          // loop
  unsigned short* updb  = (unsigned short*)(L + 12582912);
  float*          Sbuf  = (float*)(L + 25165824);            // 16.8MB
  unsigned short* Abuf  = (unsigned short*)(L + 41943040);   // 8.4MB
  unsigned short* gib   = (unsigned short*)(L + 25165824);   // gates (S/A dead)
  unsigned short* ghb   = (unsigned short*)(L + 44040192);
  unsigned short* memb2 = (unsigned short*)(L + 0);          // end
  unsigned short* memFr = (unsigned short*)(L + 12582912);   // end
  unsigned short* zb2   = (unsigned short*)(L + 25165824);   // end 48MB

  const float scale = 1.0f / sqrtf(768.f);

  auto cvt = [&](const float* src, unsigned short* dst, size_t n) {
    const int n4 = (int)(n / 4);
    hipLaunchKernelGGL(cvt_bf16, dim3((n4 + 255) / 256), dim3(256), 0, stream, src, dst, n4);
  };

  // ---- prologue ----
  hipLaunchKernelGGL(cvt_weights, dim3(8064), dim3(256), 0, stream,
      w_wq, w_wk, w_wv, w_wo, r_wq, r_wk, r_wv, r_wo, g_wih, g_whh, wqb);
  hipMemcpyAsync(bih_c, g_bih, 2304 * 4, hipMemcpyDeviceToDevice, stream);
  hipMemcpyAsync(bhh_c, g_bhh, 2304 * 4, hipMemcpyDeviceToDevice, stream);

  // folds
  hipLaunchKernelGGL(transpose_bf16, dim3(24, 24, 1), dim3(32, 8), 0, stream, wqb, tmpT1, 768, 768);
  hipLaunchKernelGGL(transpose_bf16, dim3(24, 24, 1), dim3(32, 8), 0, stream, wkb, tmpT2, 768, 768);
  hipLaunchKernelGGL((gemm_nt<1, false>), dim3(6, 6, 1), dim3(256), 0, stream,
      tmpT1, tmpT2, (const float*)nullptr, (void*)Fqk, 768, 768, 768, 0ll, 0ll, 0ll, 0ll, 1.0f);
  hipLaunchKernelGGL(transpose_bf16, dim3(24, 24, 1), dim3(32, 8), 0, stream, wvb, tmpT1, 768, 768);
  hipLaunchKernelGGL((gemm_nt<1, false>), dim3(6, 6, 1), dim3(256), 0, stream,
      wob, tmpT1, (const float*)nullptr, (void*)Fwv, 768, 768, 768, 0ll, 0ll, 0ll, 0ll, 1.0f);
  hipLaunchKernelGGL(transpose_bf16, dim3(24, 24, 1), dim3(32, 8), 0, stream, rvb, tmpT1, 768, 768);
  hipLaunchKernelGGL((gemm_nt<1, false>), dim3(6, 6, 1), dim3(256), 0, stream,
      rob, tmpT1, (const float*)nullptr, (void*)Fvo, 768, 768, 768, 0ll, 0ll, 0ll, 0ll, 1.0f);
  hipLaunchKernelGGL(transpose_bf16, dim3(24, 24, 1), dim3(32, 8), 0, stream, rqb, tmpT1, 768, 768);
  hipLaunchKernelGGL(transpose_bf16, dim3(24, 24, 1), dim3(32, 8), 0, stream, rkb, tmpT2, 768, 768);
  hipLaunchKernelGGL((gemm_nt<1, false>), dim3(6, 6, 1), dim3(256), 0, stream,
      tmpT1, tmpT2, (const float*)nullptr, (void*)Frq, 768, 768, 768, 0ll, 0ll, 0ll, 0ll, 1.0f);

  // bias vectors
  hipLaunchKernelGGL(matvec_T, dim3(3), dim3(256), 0, stream, w_wk, w_bq, vw);
  hipLaunchKernelGGL(matvec_T, dim3(3), dim3(256), 0, stream, r_wk, r_bq, vr);
  hipLaunchKernelGGL(matvec_row, dim3(192), dim3(256), 0, stream, w_wo, w_bv, w_bo, const_o);
  hipLaunchKernelGGL(matvec_row, dim3(192), dim3(256), 0, stream, r_wo, r_bv, r_bo, bvo);
  hipLaunchKernelGGL(rowdot768, dim3(1), dim3(256), 0, stream,
      w_bq, w_bk, (const float*)nullptr, cw, 1.0f, 1);
  hipLaunchKernelGGL(rowdot768, dim3(8192), dim3(256), 0, stream, z, vw, cw, zv, scale, 32768);

  cvt(z, zb, 32768ull * 768);
  hipLaunchKernelGGL(bcast_slots, dim3(6144), dim3(256), 0, stream, slots, memf);

  // Vwo = z.Fwv^T (full, into Kz region) -> transpose -> VwoT; then Kz = z.Fqk^T
  hipLaunchKernelGGL((gemm_nt<1, false>), dim3(6, 256, 1), dim3(256), 0, stream,
      zb, Fwv, (const float*)nullptr, (void*)tmpV, 32768, 768, 768, 0ll, 0ll, 0ll, 0ll, 1.0f);
  hipLaunchKernelGGL(transpose_bf16, dim3(24, 16, 64), dim3(32, 8), 0, stream,
      tmpV, VwoT, 512, 768);
  hipLaunchKernelGGL((gemm_nt<1, false>), dim3(6, 256, 1), dim3(256), 0, stream,
      zb, Fqk, (const float*)nullptr, (void*)Kz, 32768, 768, 768, 0ll, 0ll, 0ll, 0ll, 1.0f);

  const long long sA_g = (long long)(memb - updb);  // -6291456
  const long long sC_g = (long long)(ghb - gib);

  // ---- T=3 recurrence ----
  for (int t = 0; t < 3; ++t) {
    hipLaunchKernelGGL(ln_kernel, dim3(2048), dim3(256), 0, stream, memf, memb, ln_g, ln_b);
    hipLaunchKernelGGL((gemm_nt<0, true>), dim3(4, 1, 64), dim3(256), 0, stream,
        memb, Kz, zv, (void*)Sbuf, 128, 512, 768,
        98304ll, 393216ll, 65536ll, 512ll, scale);
    hipLaunchKernelGGL((softmax_kernel<512>), dim3(2048), dim3(256), 0, stream, Sbuf, Abuf);
    hipLaunchKernelGGL((gemm_nt<1, true>), dim3(6, 1, 64), dim3(256), 0, stream,
        Abuf, VwoT, const_o, (void*)updb, 128, 768, 512,
        65536ll, 393216ll, 98304ll, 0ll, 1.0f);
    for (int c = 0; c < 2; ++c) {
      hipLaunchKernelGGL((gemm_nt<1, true>), dim3(18, 32, 2), dim3(256), 0, stream,
          updb + (size_t)c * 3145728, wihb, bih_c, (void*)gib,
          4096, 2304, 768, sA_g, 1769472ll, sC_g, 2304ll, 1.0f);
      hipLaunchKernelGGL(gru_ln_combine, dim3(4096), dim3(256), 0, stream,
          gib, ghb, memf + (size_t)c * 3145728, ln_g, ln_b);
    }
  }

  // ---- read attention ----
  cvt(memf, memb2, 8192ull * 768);
  hipLaunchKernelGGL((gemm_nt<1, false>), dim3(6, 64, 1), dim3(256), 0, stream,
      memb2, Frq, (const float*)nullptr, (void*)memFr, 8192, 768, 768, 0ll, 0ll, 0ll, 0ll, 1.0f);
  hipLaunchKernelGGL((gemm_nt<1, false>), dim3(6, 64, 1), dim3(256), 0, stream,
      memb2, Fvo, (const float*)nullptr, (void*)memVo, 8192, 768, 768, 0ll, 0ll, 0ll, 0ll, 1.0f);
  hipLaunchKernelGGL(transpose_bf16, dim3(24, 4, 64), dim3(32, 8), 0, stream,
      memVo, memVoT, 128, 768);
  hipLaunchKernelGGL(rowdot768, dim3(2048), dim3(256), 0, stream,
      memf, vr, (const float*)nullptr, colb, scale, 8192);
  cvt(z, zb2, 32768ull * 768);
  hipLaunchKernelGGL((gemm_nt<0, true>), dim3(1, 4, 64), dim3(256), 0, stream,
      zb2, memFr, colb, (void*)Sbr, 512, 128, 768,
      393216ll, 98304ll, 65536ll, 128ll, scale);
  hipLaunchKernelGGL((softmax_kernel<128>), dim3(8192), dim3(256), 0, stream, Sbr, Abr);
  hipLaunchKernelGGL((gemm_nt<0, true>), dim3(6, 4, 64), dim3(256), 0, stream,
      Abr, memVoT, bvo, d_out, 512, 768, 128,
      65536ll, 98304ll, 393216ll, 0ll, 1.0f);
}

// Round 7
// 887.689 us; speedup vs baseline: 1.3485x; 1.2473x over previous
//
#include <hip/hip_runtime.h>
#include <hip/hip_bf16.h>
#include <math.h>

// Memory module: E=768, S=128, T=3, B=64, L=512. fp32 in/out.
// bf16 MFMA GEMMs (fp32 accum). Folds: Fqk=Wq^T Wk, Fwv=Wo Wv, Fvo=Ro Rv, Frq=Rq^T Rk.
// write scores = scale*(mLN.Kz^T)+zv[j]; upd = A.Vwo^T+const_o;
// read scores = scale*(z.memFr^T)+colb[j]; out = A_r.(mem.Fvo^T)^T+bvo.
// Iter-0 gh gates computed once (memory rows identical across batch).
// GRU combine emits next LN(mem) (t<2) or raw bf16 (t=2) directly.
// ORDER HAZARD (round-6 bug): memb aliases zb (L+0) — init_mem MUST launch
// after the last zb reader (the Kz GEMM).

typedef __attribute__((ext_vector_type(4))) float f32x4;
typedef __attribute__((ext_vector_type(8))) short short8;
typedef __attribute__((ext_vector_type(4))) unsigned short us4;

__device__ __forceinline__ unsigned short f2bf(float x) {
  union { float f; unsigned u; } v; v.f = x;
  unsigned r = v.u + 0x7fffu + ((v.u >> 16) & 1u);  // RNE
  return (unsigned short)(r >> 16);
}
__device__ __forceinline__ float bf2f(unsigned short u) {
  union { unsigned u; float f; } v; v.u = (unsigned)u << 16; return v.f;
}

__device__ __forceinline__ void g2l16(const void* g, void* l) {
  __builtin_amdgcn_global_load_lds(
      (const __attribute__((address_space(1))) unsigned int*)g,
      (__attribute__((address_space(3))) unsigned int*)l, 16, 0, 0);
}

__device__ __forceinline__ float wsum(float v) {
#pragma unroll
  for (int o = 32; o > 0; o >>= 1) v += __shfl_xor(v, o, 64);
  return v;
}
__device__ __forceinline__ float wmax(float v) {
#pragma unroll
  for (int o = 32; o > 0; o >>= 1) v = fmaxf(v, __shfl_xor(v, o, 64));
  return v;
}

// ---- shared 128x128-tile NT GEMM body (m97 structure, validated) ----
template<int OMODE, bool BIAS>
__device__ __forceinline__ void gemm_body(
    const unsigned short* __restrict__ A, const unsigned short* __restrict__ B,
    const float* __restrict__ bias, void* __restrict__ Cg, size_t cb,
    int N, int K, int tm, int tn, float alpha,
    unsigned short* As, unsigned short* Bs)
{
  const int tid  = threadIdx.x;
  const int lane = tid & 63;
  const int wv   = tid >> 6;
  const int wr   = wv >> 1, wc = wv & 1;

  A += (size_t)tm * 128 * K;
  B += (size_t)tn * 128 * K;

  const int srow = wv * 16 + (lane >> 2);
  const int kby  = (lane & 3) * 16;

  f32x4 acc[4][4];
#pragma unroll
  for (int a = 0; a < 4; ++a)
#pragma unroll
    for (int b = 0; b < 4; ++b) acc[a][b] = (f32x4)(0.f);

  const int mrow = wr * 64 + (lane & 15);
  const int nrow = wc * 64 + (lane & 15);
  const int koff = (lane >> 4) * 8;

  for (int kt = 0; kt < K; kt += 32) {
#pragma unroll
    for (int i = 0; i < 2; ++i) {
      g2l16((const char*)(A + (size_t)(i * 64 + srow) * K + kt) + kby,
            (char*)As + i * 4096 + wv * 1024);
      g2l16((const char*)(B + (size_t)(i * 64 + srow) * K + kt) + kby,
            (char*)Bs + i * 4096 + wv * 1024);
    }
    __syncthreads();
    short8 af[4], bf[4];
#pragma unroll
    for (int a = 0; a < 4; ++a) af[a] = *(const short8*)&As[(mrow + a * 16) * 32 + koff];
#pragma unroll
    for (int b = 0; b < 4; ++b) bf[b] = *(const short8*)&Bs[(nrow + b * 16) * 32 + koff];
#pragma unroll
    for (int a = 0; a < 4; ++a)
#pragma unroll
      for (int b = 0; b < 4; ++b)
        acc[a][b] = __builtin_amdgcn_mfma_f32_16x16x32_bf16(af[a], bf[b], acc[a][b], 0, 0, 0);
    __syncthreads();
  }

#pragma unroll
  for (int a = 0; a < 4; ++a) {
    const int row0 = tm * 128 + wr * 64 + a * 16 + (lane >> 4) * 4;
#pragma unroll
    for (int b = 0; b < 4; ++b) {
      const int col = tn * 128 + wc * 64 + b * 16 + (lane & 15);
      float bv = 0.f;
      if (BIAS) bv = bias[col];
#pragma unroll
      for (int rr = 0; rr < 4; ++rr) {
        float v = acc[a][b][rr] * alpha + bv;
        if constexpr (OMODE == 0)
          ((float*)Cg)[cb + (size_t)(row0 + rr) * N + col] = v;
        else
          ((unsigned short*)Cg)[cb + (size_t)(row0 + rr) * N + col] = f2bf(v);
      }
    }
  }
}

// Stride-batched wrapper with T1 XCD swizzle (m204 bijective).
template<int OMODE, bool BIAS>
__global__ __launch_bounds__(256) void gemm_nt(
    const unsigned short* __restrict__ Ag, const unsigned short* __restrict__ Bg,
    const float* __restrict__ bias, void* __restrict__ Cg,
    int M, int N, int K, long long sA, long long sB, long long sC,
    long long sBias, float alpha)
{
  __shared__ __align__(16) unsigned short As[128 * 32];
  __shared__ __align__(16) unsigned short Bs[128 * 32];

  const int gx = gridDim.x, gy = gridDim.y, gz = gridDim.z;
  const int nwg = gx * gy * gz;
  const int lin = blockIdx.x + gx * (blockIdx.y + gy * blockIdx.z);
  const int q = nwg >> 3, r = nwg & 7;
  const int xcd = lin & 7, jj = lin >> 3;
  const int w = (xcd < r ? xcd * (q + 1) : r * (q + 1) + (xcd - r) * q) + jj;
  const int tn = w % gx;
  const int t2 = w / gx;
  const int tm = t2 % gy;
  const long long bz = t2 / gy;

  const float* bp = BIAS ? bias + bz * sBias : (const float*)nullptr;
  gemm_body<OMODE, BIAS>(Ag + bz * sA, Bg + bz * sB, bp, Cg,
                         (size_t)(bz * sC), N, K, tm, tn, alpha, As, Bs);
}

// 4 independent 768^3 NT GEMMs in one launch (fold products). bf16 out, no bias.
struct QuadPtrs {
  const unsigned short* a[4];
  const unsigned short* b[4];
  unsigned short* c[4];
};
__global__ __launch_bounds__(256) void gemm_nt_quad(QuadPtrs p) {
  __shared__ __align__(16) unsigned short As[128 * 32];
  __shared__ __align__(16) unsigned short Bs[128 * 32];
  const int zi = blockIdx.z;
  gemm_body<1, false>(p.a[zi], p.b[zi], nullptr, (void*)p.c[zi], 0,
                      768, 768, blockIdx.y, blockIdx.x, 1.0f, As, Bs);
}

template<int LR>
__global__ __launch_bounds__(256) void softmax_kernel(
    const float* __restrict__ sc, unsigned short* __restrict__ p)
{
  const int row  = blockIdx.x * 4 + (threadIdx.x >> 6);
  const int lane = threadIdx.x & 63;
  constexpr int PER = LR / 64;
  const float* sr = sc + (size_t)row * LR;
  float v[PER];
  float m = -1e30f;
#pragma unroll
  for (int j = 0; j < PER; ++j) { v[j] = sr[lane + 64 * j]; m = fmaxf(m, v[j]); }
  m = wmax(m);
  float s = 0.f;
#pragma unroll
  for (int j = 0; j < PER; ++j) { v[j] = __expf(v[j] - m); s += v[j]; }
  s = wsum(s);
  const float inv = 1.f / s;
  unsigned short* pr = p + (size_t)row * LR;
#pragma unroll
  for (int j = 0; j < PER; ++j) pr[lane + 64 * j] = f2bf(v[j] * inv);
}

// GRU combine with inline LN of old mem (h) AND emit of next-iter operand:
// EMITLN: outb = LN(mem_new) bf16; else outb = bf16(mem_new).
// GHB: gh is [128,2304] broadcast (iter 0).
template<bool GHB, bool EMITLN>
__global__ __launch_bounds__(256) void gru_ln_combine(
    const unsigned short* __restrict__ gi, const unsigned short* __restrict__ gh,
    float* __restrict__ mem, const float* __restrict__ g, const float* __restrict__ b,
    unsigned short* __restrict__ outb)
{
  __shared__ float ps[4], pq[4];
  const size_t row = blockIdx.x;
  const int tid = threadIdx.x, wv = tid >> 6, lane = tid & 63;
  float* mr = mem + row * 768;
  const size_t ghrow = GHB ? (row & 127) : row;
  float v[3];
  float s = 0.f, q = 0.f;
#pragma unroll
  for (int k = 0; k < 3; ++k) {
    v[k] = mr[tid + 256 * k];
    s += v[k]; q += v[k] * v[k];
  }
  s = wsum(s); q = wsum(q);
  if (lane == 0) { ps[wv] = s; pq[wv] = q; }
  __syncthreads();
  s = ps[0] + ps[1] + ps[2] + ps[3];
  q = pq[0] + pq[1] + pq[2] + pq[3];
  const float mu = s * (1.f / 768.f);
  const float rstd = rsqrtf(q * (1.f / 768.f) - mu * mu + 1e-5f);
  float nv[3];
  float s2 = 0.f, q2 = 0.f;
#pragma unroll
  for (int k = 0; k < 3; ++k) {
    const int c = tid + 256 * k;
    const float h = (v[k] - mu) * rstd * g[c] + b[c];
    const float ir  = bf2f(gi[row * 2304 + c]);
    const float iz  = bf2f(gi[row * 2304 + 768 + c]);
    const float in_ = bf2f(gi[row * 2304 + 1536 + c]);
    const float hr  = bf2f(gh[ghrow * 2304 + c]);
    const float hz  = bf2f(gh[ghrow * 2304 + 768 + c]);
    const float hn  = bf2f(gh[ghrow * 2304 + 1536 + c]);
    const float rg = 1.f / (1.f + __expf(-(ir + hr)));
    const float zg = 1.f / (1.f + __expf(-(iz + hz)));
    const float n  = tanhf(in_ + rg * hn);
    nv[k] = (1.f - zg) * n + zg * h;
    mr[c] = nv[k];
    s2 += nv[k]; q2 += nv[k] * nv[k];
  }
  if (EMITLN) {
    s2 = wsum(s2); q2 = wsum(q2);
    __syncthreads();
    if (lane == 0) { ps[wv] = s2; pq[wv] = q2; }
    __syncthreads();
    s2 = ps[0] + ps[1] + ps[2] + ps[3];
    q2 = pq[0] + pq[1] + pq[2] + pq[3];
    const float mu2 = s2 * (1.f / 768.f);
    const float rstd2 = rsqrtf(q2 * (1.f / 768.f) - mu2 * mu2 + 1e-5f);
#pragma unroll
    for (int k = 0; k < 3; ++k) {
      const int c = tid + 256 * k;
      outb[row * 768 + c] = f2bf((nv[k] - mu2) * rstd2 * g[c] + b[c]);
    }
  } else {
#pragma unroll
    for (int k = 0; k < 3; ++k) {
      const int c = tid + 256 * k;
      outb[row * 768 + c] = f2bf(nv[k]);
    }
  }
}

__global__ __launch_bounds__(256) void cvt_bf16(
    const float* __restrict__ in, unsigned short* __restrict__ out, int n4)
{
  const int i = blockIdx.x * 256 + threadIdx.x;
  if (i >= n4) return;
  const float4 v = ((const float4*)in)[i];
  us4 o;
  o.x = f2bf(v.x); o.y = f2bf(v.y); o.z = f2bf(v.z); o.w = f2bf(v.w);
  ((us4*)out)[i] = o;
}

// Merged weight conversion: 10 fp32 sources -> contiguous bf16 region.
__global__ __launch_bounds__(256) void cvt_weights(
    const float* p0, const float* p1, const float* p2, const float* p3,
    const float* p4, const float* p5, const float* p6, const float* p7,
    const float* p8, const float* p9, unsigned short* __restrict__ dst)
{
  const int i = blockIdx.x * 256 + threadIdx.x;  // f4 index, total 2064384
  if (i >= 2064384) return;
  const float* src; int base;
  if      (i < 147456)  { src = p0; base = 0; }
  else if (i < 294912)  { src = p1; base = 147456; }
  else if (i < 442368)  { src = p2; base = 294912; }
  else if (i < 589824)  { src = p3; base = 442368; }
  else if (i < 737280)  { src = p4; base = 589824; }
  else if (i < 884736)  { src = p5; base = 737280; }
  else if (i < 1032192) { src = p6; base = 884736; }
  else if (i < 1179648) { src = p7; base = 1032192; }
  else if (i < 1622016) { src = p8; base = 1179648; }
  else                  { src = p9; base = 1622016; }
  const float4 v = ((const float4*)src)[i - base];
  us4 o;
  o.x = f2bf(v.x); o.y = f2bf(v.y); o.z = f2bf(v.z); o.w = f2bf(v.w);
  ((us4*)dst)[i] = o;
}

// memf[b,s,:] = slots[s,:]; memb[b,s,:] = bf16(LN(slots[s,:])). One block per slot.
__global__ __launch_bounds__(256) void init_mem(
    const float* __restrict__ slots, const float* __restrict__ g,
    const float* __restrict__ b, float* __restrict__ memf,
    unsigned short* __restrict__ memb)
{
  __shared__ float ps[4], pq[4];
  const int s = blockIdx.x;            // 0..127
  const int tid = threadIdx.x, wv = tid >> 6, lane = tid & 63;
  const float* sr = slots + (size_t)s * 768;
  float v[3];
  float su = 0.f, qu = 0.f;
#pragma unroll
  for (int k = 0; k < 3; ++k) { v[k] = sr[tid + 256 * k]; su += v[k]; qu += v[k] * v[k]; }
  su = wsum(su); qu = wsum(qu);
  if (lane == 0) { ps[wv] = su; pq[wv] = qu; }
  __syncthreads();
  su = ps[0] + ps[1] + ps[2] + ps[3];
  qu = pq[0] + pq[1] + pq[2] + pq[3];
  const float mu = su * (1.f / 768.f);
  const float rstd = rsqrtf(qu * (1.f / 768.f) - mu * mu + 1e-5f);
  unsigned short lb[3];
#pragma unroll
  for (int k = 0; k < 3; ++k) {
    const int c = tid + 256 * k;
    lb[k] = f2bf((v[k] - mu) * rstd * g[c] + b[c]);
  }
  for (int bb = 0; bb < 64; ++bb) {
    float* mrow = memf + ((size_t)bb * 128 + s) * 768;
    unsigned short* brow = memb + ((size_t)bb * 128 + s) * 768;
#pragma unroll
    for (int k = 0; k < 3; ++k) { mrow[tid + 256 * k] = v[k]; brow[tid + 256 * k] = lb[k]; }
  }
}

// Batched bf16 transpose: in [R,C] -> out [C,R], batch stride R*C.
__global__ void transpose_bf16(const unsigned short* __restrict__ in,
                               unsigned short* __restrict__ out, int R, int C)
{
  __shared__ unsigned short t[32][33];
  const size_t bofs = (size_t)blockIdx.z * R * C;
  const int c0 = blockIdx.x * 32, r0 = blockIdx.y * 32;
  const int x = threadIdx.x, y = threadIdx.y;
#pragma unroll
  for (int k = 0; k < 32; k += 8)
    t[y + k][x] = in[bofs + (size_t)(r0 + y + k) * C + c0 + x];
  __syncthreads();
#pragma unroll
  for (int k = 0; k < 32; k += 8)
    out[bofs + (size_t)(c0 + y + k) * R + r0 + x] = t[x][y + k];
}

// 6 independent 768x768 transposes in one launch.
struct TPtrs { const unsigned short* s[6]; unsigned short* d[6]; };
__global__ void transpose_multi(TPtrs p) {
  __shared__ unsigned short t[32][33];
  const unsigned short* in = p.s[blockIdx.z];
  unsigned short* out = p.d[blockIdx.z];
  const int c0 = blockIdx.x * 32, r0 = blockIdx.y * 32;
  const int x = threadIdx.x, y = threadIdx.y;
#pragma unroll
  for (int k = 0; k < 32; k += 8)
    t[y + k][x] = in[(size_t)(r0 + y + k) * 768 + c0 + x];
  __syncthreads();
#pragma unroll
  for (int k = 0; k < 32; k += 8)
    out[(size_t)(c0 + y + k) * 768 + r0 + x] = t[x][y + k];
}

// Two y = W^T x jobs in one launch (grid 6: task = bx/3).
__global__ __launch_bounds__(256) void matvec_T2(
    const float* __restrict__ W0, const float* __restrict__ x0, float* __restrict__ y0,
    const float* __restrict__ W1, const float* __restrict__ x1, float* __restrict__ y1)
{
  const int task = blockIdx.x / 3;
  const int j = (blockIdx.x % 3) * 256 + threadIdx.x;
  const float* W = task ? W1 : W0;
  const float* x = task ? x1 : x0;
  float* y = task ? y1 : y0;
  float s = 0.f;
  for (int k = 0; k < 768; ++k) s += W[(size_t)k * 768 + j] * x[k];
  y[j] = s;
}

// Two y[row]=add[row]+dot(W[row,:],x) jobs (grid 384: task = bx/192).
__global__ __launch_bounds__(256) void matvec_row2(
    const float* __restrict__ W0, const float* __restrict__ x0,
    const float* __restrict__ a0, float* __restrict__ y0,
    const float* __restrict__ W1, const float* __restrict__ x1,
    const float* __restrict__ a1, float* __restrict__ y1)
{
  const int task = blockIdx.x / 192;
  const int row = (blockIdx.x % 192) * 4 + (threadIdx.x >> 6);
  const int lane = threadIdx.x & 63;
  const float* W = task ? W1 : W0;
  const float* x = task ? x1 : x0;
  const float* ad = task ? a1 : a0;
  float* y = task ? y1 : y0;
  const float* r = W + (size_t)row * 768;
  float s = 0.f;
#pragma unroll
  for (int j = 0; j < 12; ++j) s += r[lane + 64 * j] * x[lane + 64 * j];
  s = wsum(s);
  if (lane == 0) y[row] = s + ad[row];
}

// out[i] = scl * (dot(src_i, vec) + (cadd ? cadd[0] : 0))
__global__ __launch_bounds__(256) void rowdot768(
    const float* __restrict__ src, const float* __restrict__ vec,
    const float* __restrict__ cadd, float* __restrict__ out, float scl, int rows)
{
  const int row  = blockIdx.x * 4 + (threadIdx.x >> 6);
  if (row >= rows) return;
  const int lane = threadIdx.x & 63;
  const float* r = src + (size_t)row * 768;
  float s = 0.f;
#pragma unroll
  for (int j = 0; j < 12; ++j) s += r[lane + 64 * j] * vec[lane + 64 * j];
  s = wsum(s);
  if (lane == 0) out[row] = scl * (s + (cadd ? cadd[0] : 0.f));
}

// Fused: zb = bf16(z) AND zv[row] = scl*(dot(z_row, vw) + cw[0]). Wave per row.
__global__ __launch_bounds__(256) void cvt_z_zv(
    const float* __restrict__ z, unsigned short* __restrict__ zb,
    const float* __restrict__ vw, const float* __restrict__ cw,
    float* __restrict__ zv, float scl)
{
  const int row = blockIdx.x * 4 + (threadIdx.x >> 6);
  const int lane = threadIdx.x & 63;
  const float* zr = z + (size_t)row * 768;
  unsigned short* zbr = zb + (size_t)row * 768;
  float s = 0.f;
#pragma unroll
  for (int j = 0; j < 12; ++j) {
    const float v = zr[lane + 64 * j];
    s += v * vw[lane + 64 * j];
    zbr[lane + 64 * j] = f2bf(v);
  }
  s = wsum(s);
  if (lane == 0) zv[row] = scl * (s + cw[0]);
}

__global__ __launch_bounds__(256) void diag_ws(float* __restrict__ out, float wsz, int n) {
  const int i = blockIdx.x * 256 + threadIdx.x;
  if (i < n) out[i] = (i == 0) ? wsz : 0.f;
}

extern "C" void kernel_launch(void* const* d_in, const int* in_sizes, int n_in,
                              void* d_out, int out_size, void* d_ws, size_t ws_size,
                              hipStream_t stream)
{
  const float* z     = (const float*)d_in[0];
  const float* slots = (const float*)d_in[1];
  const float* ln_g  = (const float*)d_in[2];
  const float* ln_b  = (const float*)d_in[3];
  const float* w_wq = (const float*)d_in[4];  const float* w_bq = (const float*)d_in[5];
  const float* w_wk = (const float*)d_in[6];  const float* w_bk = (const float*)d_in[7];
  const float* w_wv = (const float*)d_in[8];  const float* w_bv = (const float*)d_in[9];
  const float* w_wo = (const float*)d_in[10]; const float* w_bo = (const float*)d_in[11];
  const float* r_wq = (const float*)d_in[12]; const float* r_bq = (const float*)d_in[13];
  const float* r_wk = (const float*)d_in[14]; const float* r_bk = (const float*)d_in[15];
  const float* r_wv = (const float*)d_in[16]; const float* r_bv = (const float*)d_in[17];
  const float* r_wo = (const float*)d_in[18]; const float* r_bo = (const float*)d_in[19];
  const float* g_wih = (const float*)d_in[20]; const float* g_bih = (const float*)d_in[21];
  const float* g_whh = (const float*)d_in[22]; const float* g_bhh = (const float*)d_in[23];

  // ---- arena (bytes) ----
  constexpr size_t O_F    = 16515072;    // Fqk,Fwv,Fvo,Frq (4 x 1179648)
  constexpr size_t O_T6   = 21233664;    // 6 x 1179648 transposed weights
  constexpr size_t O_GH0  = 28311552;    // 589824
  constexpr size_t O_FL   = 28901376;    // float vectors
  constexpr size_t O_memf = 29096192;    // 25165824
  constexpr size_t O_Kz   = 54262016;    // 50331648: tmpV -> Kz | end: memFr
  constexpr size_t O_VwoT = 104593664;   // 50331648: VwoT | end: memVo/memVoT/Sbr/Abr
  constexpr size_t O_L    = 154925312;   // 62914560 scratch
  constexpr size_t NEED   = 217839872;

  if (ws_size < NEED) {
    hipLaunchKernelGGL(diag_ws, dim3((out_size + 255) / 256), dim3(256), 0, stream,
                       (float*)d_out, (float)ws_size, out_size);
    return;
  }

  char* ws = (char*)d_ws;
  unsigned short* wqb  = (unsigned short*)(ws + 0);
  unsigned short* wkb  = wqb + 589824;
  unsigned short* wvb  = wkb + 589824;
  unsigned short* wob  = wvb + 589824;
  unsigned short* rqb  = wob + 589824;
  unsigned short* rkb  = rqb + 589824;
  unsigned short* rvb  = rkb + 589824;
  unsigned short* rob  = rvb + 589824;
  unsigned short* wihb = rob + 589824;
  unsigned short* whhb = wihb + 1769472;
  unsigned short* Fqk  = (unsigned short*)(ws + O_F);
  unsigned short* Fwv  = Fqk + 589824;
  unsigned short* Fvo  = Fwv + 589824;
  unsigned short* Frq  = Fvo + 589824;
  unsigned short* T0   = (unsigned short*)(ws + O_T6);  // WqT
  unsigned short* T1   = T0 + 589824;                   // WkT
  unsigned short* T2   = T1 + 589824;                   // WvT
  unsigned short* T3   = T2 + 589824;                   // RvT
  unsigned short* T4   = T3 + 589824;                   // RqT
  unsigned short* T5   = T4 + 589824;                   // RkT
  unsigned short* gh0  = (unsigned short*)(ws + O_GH0);
  float* bih_c   = (float*)(ws + O_FL);     // 2304
  float* bhh_c   = bih_c + 2304;            // 2304 (adjacent: sBias=2304)
  float* const_o = bhh_c + 2304;            // 768
  float* bvo     = const_o + 768;
  float* vw      = bvo + 768;
  float* vr      = vw + 768;
  float* cw      = vr + 768;                // 64
  float* zv      = cw + 64;                 // 32768
  float* colb    = zv + 32768;              // 8192
  float* memf = (float*)(ws + O_memf);
  unsigned short* tmpV  = (unsigned short*)(ws + O_Kz);
  unsigned short* Kz    = (unsigned short*)(ws + O_Kz);
  unsigned short* memFr = (unsigned short*)(ws + O_Kz);            // end
  unsigned short* VwoT  = (unsigned short*)(ws + O_VwoT);
  unsigned short* memVo   = (unsigned short*)(ws + O_VwoT);             // end
  unsigned short* memVoT  = (unsigned short*)(ws + O_VwoT + 12582912);  // end
  float*          Sbr     = (float*)(ws + O_VwoT + 25165824);           // end
  unsigned short* Abr     = (unsigned short*)(ws + O_VwoT + 41943040);  // end
  char* L = ws + O_L;
  unsigned short* zb    = (unsigned short*)(L + 0);          // prologue 48MiB
  unsigned short* memb  = (unsigned short*)(L + 0);          // loop (aliases zb!)
  unsigned short* updb  = (unsigned short*)(L + 12582912);
  float*          Sbuf  = (float*)(L + 25165824);            // 16MiB
  unsigned short* Abuf  = (unsigned short*)(L + 41943040);   // 8MiB
  unsigned short* gib   = (unsigned short*)(L + 25165824);   // gates (S/A dead)
  unsigned short* ghb   = (unsigned short*)(L + 44040192);
  unsigned short* zb2   = (unsigned short*)(L + 12582912);   // end 48MiB

  const float scale = 1.0f / sqrtf(768.f);

  // ---- prologue ----
  hipLaunchKernelGGL(cvt_weights, dim3(8064), dim3(256), 0, stream,
      w_wq, w_wk, w_wv, w_wo, r_wq, r_wk, r_wv, r_wo, g_wih, g_whh, wqb);
  hipMemcpyAsync(bih_c, g_bih, 2304 * 4, hipMemcpyDeviceToDevice, stream);
  hipMemcpyAsync(bhh_c, g_bhh, 2304 * 4, hipMemcpyDeviceToDevice, stream);

  {
    TPtrs tp;
    tp.s[0] = wqb; tp.d[0] = T0;
    tp.s[1] = wkb; tp.d[1] = T1;
    tp.s[2] = wvb; tp.d[2] = T2;
    tp.s[3] = rvb; tp.d[3] = T3;
    tp.s[4] = rqb; tp.d[4] = T4;
    tp.s[5] = rkb; tp.d[5] = T5;
    hipLaunchKernelGGL(transpose_multi, dim3(24, 24, 6), dim3(32, 8), 0, stream, tp);
  }
  {
    QuadPtrs qp;
    qp.a[0] = T0;  qp.b[0] = T1; qp.c[0] = Fqk;  // Wq^T Wk
    qp.a[1] = wob; qp.b[1] = T2; qp.c[1] = Fwv;  // Wo Wv
    qp.a[2] = rob; qp.b[2] = T3; qp.c[2] = Fvo;  // Ro Rv
    qp.a[3] = T4;  qp.b[3] = T5; qp.c[3] = Frq;  // Rq^T Rk
    hipLaunchKernelGGL(gemm_nt_quad, dim3(6, 6, 4), dim3(256), 0, stream, qp);
  }

  hipLaunchKernelGGL(matvec_T2, dim3(6), dim3(256), 0, stream,
      w_wk, w_bq, vw, r_wk, r_bq, vr);
  hipLaunchKernelGGL(matvec_row2, dim3(384), dim3(256), 0, stream,
      w_wo, w_bv, w_bo, const_o, r_wo, r_bv, r_bo, bvo);
  hipLaunchKernelGGL(rowdot768, dim3(1), dim3(256), 0, stream,
      w_bq, w_bk, (const float*)nullptr, cw, 1.0f, 1);
  hipLaunchKernelGGL(cvt_z_zv, dim3(8192), dim3(256), 0, stream, z, zb, vw, cw, zv, scale);

  // Vwo = z.Fwv^T into tmpV -> transpose -> VwoT; then Kz = z.Fqk^T.
  // NOTE: these read zb (L+0). init_mem writes memb (L+0) and MUST come after.
  hipLaunchKernelGGL((gemm_nt<1, false>), dim3(6, 256, 1), dim3(256), 0, stream,
      zb, Fwv, (const float*)nullptr, (void*)tmpV, 32768, 768, 768, 0ll, 0ll, 0ll, 0ll, 1.0f);
  hipLaunchKernelGGL(transpose_bf16, dim3(24, 16, 64), dim3(32, 8), 0, stream,
      tmpV, VwoT, 512, 768);
  hipLaunchKernelGGL((gemm_nt<1, false>), dim3(6, 256, 1), dim3(256), 0, stream,
      zb, Fqk, (const float*)nullptr, (void*)Kz, 32768, 768, 768, 0ll, 0ll, 0ll, 0ll, 1.0f);

  // init AFTER last zb reader (fixes round-6 clobber)
  hipLaunchKernelGGL(init_mem, dim3(128), dim3(256), 0, stream,
      slots, ln_g, ln_b, memf, memb);

  const long long sA_g = (long long)(memb - updb);  // -6291456 (z=1 -> memb)
  const long long sC_g = (long long)(ghb - gib);    //  9437184

  // ---- T=3 recurrence ----
  for (int t = 0; t < 3; ++t) {
    hipLaunchKernelGGL((gemm_nt<0, true>), dim3(4, 1, 64), dim3(256), 0, stream,
        memb, Kz, zv, (void*)Sbuf, 128, 512, 768,
        98304ll, 393216ll, 65536ll, 512ll, scale);
    hipLaunchKernelGGL((softmax_kernel<512>), dim3(2048), dim3(256), 0, stream, Sbuf, Abuf);
    hipLaunchKernelGGL((gemm_nt<1, true>), dim3(6, 1, 64), dim3(256), 0, stream,
        Abuf, VwoT, const_o, (void*)updb, 128, 768, 512,
        65536ll, 393216ll, 98304ll, 0ll, 1.0f);
    if (t == 0) {
      // gh identical across batch at t=0: compute once from memb rows 0..127
      hipLaunchKernelGGL((gemm_nt<1, true>), dim3(18, 1, 1), dim3(256), 0, stream,
          memb, whhb, bhh_c, (void*)gh0, 128, 2304, 768, 0ll, 0ll, 0ll, 0ll, 1.0f);
      for (int c = 0; c < 2; ++c) {
        hipLaunchKernelGGL((gemm_nt<1, true>), dim3(18, 32, 1), dim3(256), 0, stream,
            updb + (size_t)c * 3145728, wihb, bih_c, (void*)gib,
            4096, 2304, 768, 0ll, 0ll, 0ll, 0ll, 1.0f);
        hipLaunchKernelGGL((gru_ln_combine<true, true>), dim3(4096), dim3(256), 0, stream,
            gib, gh0, memf + (size_t)c * 3145728, ln_g, ln_b,
            memb + (size_t)c * 3145728);
      }
    } else {
      for (int c = 0; c < 2; ++c) {
        hipLaunchKernelGGL((gemm_nt<1, true>), dim3(18, 32, 2), dim3(256), 0, stream,
            updb + (size_t)c * 3145728, wihb, bih_c, (void*)gib,
            4096, 2304, 768, sA_g, 1769472ll, sC_g, 2304ll, 1.0f);
        if (t < 2)
          hipLaunchKernelGGL((gru_ln_combine<false, true>), dim3(4096), dim3(256), 0, stream,
              gib, ghb, memf + (size_t)c * 3145728, ln_g, ln_b,
              memb + (size_t)c * 3145728);
        else
          hipLaunchKernelGGL((gru_ln_combine<false, false>), dim3(4096), dim3(256), 0, stream,
              gib, ghb, memf + (size_t)c * 3145728, ln_g, ln_b,
              memb + (size_t)c * 3145728);
      }
    }
  }
  // memb now holds bf16(mem_final) (raw, t=2 emit)

  // ---- read attention ----
  // memFr = mem.Frq^T (-> Kz region), memVo = mem.Fvo^T (one batched launch)
  hipLaunchKernelGGL((gemm_nt<1, false>), dim3(6, 64, 2), dim3(256), 0, stream,
      memb, Frq, (const float*)nullptr, (void*)memFr, 8192, 768, 768,
      0ll, (long long)(Fvo - Frq), 25165824ll, 0ll, 1.0f);
  hipLaunchKernelGGL(transpose_bf16, dim3(24, 4, 64), dim3(32, 8), 0, stream,
      memVo, memVoT, 128, 768);
  hipLaunchKernelGGL(rowdot768, dim3(2048), dim3(256), 0, stream,
      memf, vr, (const float*)nullptr, colb, scale, 8192);
  {
    const int n4 = 6291456;
    hipLaunchKernelGGL(cvt_bf16, dim3(24576), dim3(256), 0, stream, z, zb2, n4);
  }
  hipLaunchKernelGGL((gemm_nt<0, true>), dim3(1, 4, 64), dim3(256), 0, stream,
      zb2, memFr, colb, (void*)Sbr, 512, 128, 768,
      393216ll, 98304ll, 65536ll, 128ll, scale);
  hipLaunchKernelGGL((softmax_kernel<128>), dim3(8192), dim3(256), 0, stream, Sbr, Abr);
  hipLaunchKernelGGL((gemm_nt<0, true>), dim3(6, 4, 64), dim3(256), 0, stream,
      Abr, memVoT, bvo, d_out, 512, 768, 128,
      65536ll, 98304ll, 393216ll, 0ll, 1.0f);
}

// Round 8
// 871.673 us; speedup vs baseline: 1.3733x; 1.0184x over previous
//
#include <hip/hip_runtime.h>
#include <hip/hip_bf16.h>
#include <math.h>

// Memory module: E=768, S=128, T=3, B=64, L=512. fp32 in/out.
// bf16 MFMA GEMMs (fp32 accum). Folds: Fqk=Wq^T Wk, Fwv=Wo Wv, Fvo=Ro Rv, Frq=Rq^T Rk.
// Big GEMMs (M,N mult of 256, K mult of 64) use gemm_nt8: 256x256 tile, BK=64,
// 8 waves, 128KiB LDS dbuf, counted vmcnt(8), XOR-swizzled LDS (both-sides involution).
// gh gates for t>=1 are staged in d_out scratch (written-before-read; final GEMM
// overwrites all of d_out last).

typedef __attribute__((ext_vector_type(4))) float f32x4;
typedef __attribute__((ext_vector_type(8))) short short8;
typedef __attribute__((ext_vector_type(4))) unsigned short us4;

__device__ __forceinline__ unsigned short f2bf(float x) {
  union { float f; unsigned u; } v; v.f = x;
  unsigned r = v.u + 0x7fffu + ((v.u >> 16) & 1u);  // RNE
  return (unsigned short)(r >> 16);
}
__device__ __forceinline__ float bf2f(unsigned short u) {
  union { unsigned u; float f; } v; v.u = (unsigned)u << 16; return v.f;
}

__device__ __forceinline__ void g2l16(const void* g, void* l) {
  __builtin_amdgcn_global_load_lds(
      (const __attribute__((address_space(1))) unsigned int*)g,
      (__attribute__((address_space(3))) unsigned int*)l, 16, 0, 0);
}

__device__ __forceinline__ float wsum(float v) {
#pragma unroll
  for (int o = 32; o > 0; o >>= 1) v += __shfl_xor(v, o, 64);
  return v;
}
__device__ __forceinline__ float wmax(float v) {
#pragma unroll
  for (int o = 32; o > 0; o >>= 1) v = fmaxf(v, __shfl_xor(v, o, 64));
  return v;
}

// m204 bijective XCD swizzle of flattened grid -> (tn, tm, bz)
__device__ __forceinline__ void xcd_map(int& tn, int& tm, long long& bz) {
  const int gx = gridDim.x, gy = gridDim.y, gz = gridDim.z;
  const int nwg = gx * gy * gz;
  const int lin = blockIdx.x + gx * (blockIdx.y + gy * blockIdx.z);
  const int q = nwg >> 3, r = nwg & 7;
  const int xcd = lin & 7, jj = lin >> 3;
  const int w = (xcd < r ? xcd * (q + 1) : r * (q + 1) + (xcd - r) * q) + jj;
  tn = w % gx;
  const int t2 = w / gx;
  tm = t2 % gy;
  bz = t2 / gy;
}

// ---- m97 128x128 NT GEMM body (kept for small/odd shapes) ----
template<int OMODE, bool BIAS>
__device__ __forceinline__ void gemm_body(
    const unsigned short* __restrict__ A, const unsigned short* __restrict__ B,
    const float* __restrict__ bias, void* __restrict__ Cg, size_t cb,
    int N, int K, int tm, int tn, float alpha,
    unsigned short* As, unsigned short* Bs)
{
  const int tid  = threadIdx.x;
  const int lane = tid & 63;
  const int wv   = tid >> 6;
  const int wr   = wv >> 1, wc = wv & 1;

  A += (size_t)tm * 128 * K;
  B += (size_t)tn * 128 * K;

  const int srow = wv * 16 + (lane >> 2);
  const int kby  = (lane & 3) * 16;

  f32x4 acc[4][4];
#pragma unroll
  for (int a = 0; a < 4; ++a)
#pragma unroll
    for (int b = 0; b < 4; ++b) acc[a][b] = (f32x4)(0.f);

  const int mrow = wr * 64 + (lane & 15);
  const int nrow = wc * 64 + (lane & 15);
  const int koff = (lane >> 4) * 8;

  for (int kt = 0; kt < K; kt += 32) {
#pragma unroll
    for (int i = 0; i < 2; ++i) {
      g2l16((const char*)(A + (size_t)(i * 64 + srow) * K + kt) + kby,
            (char*)As + i * 4096 + wv * 1024);
      g2l16((const char*)(B + (size_t)(i * 64 + srow) * K + kt) + kby,
            (char*)Bs + i * 4096 + wv * 1024);
    }
    __syncthreads();
    short8 af[4], bf[4];
#pragma unroll
    for (int a = 0; a < 4; ++a) af[a] = *(const short8*)&As[(mrow + a * 16) * 32 + koff];
#pragma unroll
    for (int b = 0; b < 4; ++b) bf[b] = *(const short8*)&Bs[(nrow + b * 16) * 32 + koff];
#pragma unroll
    for (int a = 0; a < 4; ++a)
#pragma unroll
      for (int b = 0; b < 4; ++b)
        acc[a][b] = __builtin_amdgcn_mfma_f32_16x16x32_bf16(af[a], bf[b], acc[a][b], 0, 0, 0);
    __syncthreads();
  }

#pragma unroll
  for (int a = 0; a < 4; ++a) {
    const int row0 = tm * 128 + wr * 64 + a * 16 + (lane >> 4) * 4;
#pragma unroll
    for (int b = 0; b < 4; ++b) {
      const int col = tn * 128 + wc * 64 + b * 16 + (lane & 15);
      float bv = 0.f;
      if (BIAS) bv = bias[col];
#pragma unroll
      for (int rr = 0; rr < 4; ++rr) {
        float v = acc[a][b][rr] * alpha + bv;
        if constexpr (OMODE == 0)
          ((float*)Cg)[cb + (size_t)(row0 + rr) * N + col] = v;
        else
          ((unsigned short*)Cg)[cb + (size_t)(row0 + rr) * N + col] = f2bf(v);
      }
    }
  }
}

template<int OMODE, bool BIAS>
__global__ __launch_bounds__(256) void gemm_nt(
    const unsigned short* __restrict__ Ag, const unsigned short* __restrict__ Bg,
    const float* __restrict__ bias, void* __restrict__ Cg,
    int M, int N, int K, long long sA, long long sB, long long sC,
    long long sBias, float alpha)
{
  __shared__ __align__(16) unsigned short As[128 * 32];
  __shared__ __align__(16) unsigned short Bs[128 * 32];
  int tn, tm; long long bz;
  xcd_map(tn, tm, bz);
  const float* bp = BIAS ? bias + bz * sBias : (const float*)nullptr;
  gemm_body<OMODE, BIAS>(Ag + bz * sA, Bg + bz * sB, bp, Cg,
                         (size_t)(bz * sC), N, K, tm, tn, alpha, As, Bs);
}

// ---- 256x256 8-wave deep-pipelined NT GEMM (BK=64, counted vmcnt, swizzled LDS) ----
// Requires per-batch M%256==0, N%256==0, K%64==0, K>=128.
template<int OMODE, bool BIAS>
__global__ __launch_bounds__(512, 2) void gemm_nt8(
    const unsigned short* __restrict__ Ag, const unsigned short* __restrict__ Bg,
    const float* __restrict__ bias, void* __restrict__ Cg,
    int M, int N, int K, long long sA, long long sB, long long sC,
    long long sBias, float alpha)
{
  __shared__ __align__(16) unsigned short As[2][256 * 64];
  __shared__ __align__(16) unsigned short Bs[2][256 * 64];

  const int tid  = threadIdx.x;
  const int lane = tid & 63;
  const int wv   = tid >> 6;      // 0..7
  const int wr   = wv >> 2;       // 0..1 (M half)
  const int wc   = wv & 3;        // 0..3 (N quarter)

  int tn, tm; long long bz;
  xcd_map(tn, tm, bz);

  const unsigned short* A = Ag + bz * sA + (size_t)tm * 256 * K;
  const unsigned short* B = Bg + bz * sB + (size_t)tn * 256 * K;

  // staging: linear LDS dest (wave-uniform base + lane*16); global source
  // pre-swizzled with the same involution the reads use: s(o)=o^(((o>>7)&7)<<4)
  auto stage = [&](int bi, int kt) {
#pragma unroll
    for (int c = 0; c < 4; ++c) {
      const int olin = c * 8192 + tid * 16;
      const int olog = olin ^ (((olin >> 7) & 7) << 4);
      const int row = olog >> 7, cbyte = olog & 127;
      g2l16((const char*)(A + (size_t)row * K + kt) + cbyte,
            (char*)As[bi] + c * 8192 + wv * 1024);
      g2l16((const char*)(B + (size_t)row * K + kt) + cbyte,
            (char*)Bs[bi] + c * 8192 + wv * 1024);
    }
  };

  const int arow = wr * 128 + (lane & 15);   // + i*16
  const int brow = wc * 64 + (lane & 15);    // + j*16
  const int kb   = (lane >> 4) * 16;         // byte offset within 32-elem k-group
  auto swz = [](int o) { return o ^ (((o >> 7) & 7) << 4); };

  f32x4 acc[8][4];
#pragma unroll
  for (int i = 0; i < 8; ++i)
#pragma unroll
    for (int j = 0; j < 4; ++j) acc[i][j] = (f32x4)(0.f);

  const int nt = K >> 6;
  stage(0, 0);
  stage(1, 64);
  asm volatile("s_waitcnt vmcnt(8)" ::: "memory");
  __builtin_amdgcn_s_barrier();
  __builtin_amdgcn_sched_barrier(0);

  for (int t = 0; t < nt; ++t) {
    const int bi = t & 1;
    const char* Ab = (const char*)As[bi];
    const char* Bb = (const char*)Bs[bi];

    short8 bfr[2][4];
#pragma unroll
    for (int ks = 0; ks < 2; ++ks)
#pragma unroll
      for (int j = 0; j < 4; ++j)
        bfr[ks][j] = *(const short8*)(Bb + swz((brow + j * 16) * 128 + ks * 64 + kb));

#pragma unroll
    for (int ph = 0; ph < 4; ++ph) {
      const int pr = ph >> 1, pk = ph & 1;
      short8 afr[4];
#pragma unroll
      for (int i = 0; i < 4; ++i)
        afr[i] = *(const short8*)(Ab + swz((arow + (pr * 4 + i) * 16) * 128 + pk * 64 + kb));
      __builtin_amdgcn_s_setprio(1);
#pragma unroll
      for (int i = 0; i < 4; ++i)
#pragma unroll
        for (int j = 0; j < 4; ++j)
          acc[pr * 4 + i][j] = __builtin_amdgcn_mfma_f32_16x16x32_bf16(
              afr[i], bfr[pk][j], acc[pr * 4 + i][j], 0, 0, 0);
      __builtin_amdgcn_s_setprio(0);
    }

    __builtin_amdgcn_sched_barrier(0);
    __builtin_amdgcn_s_barrier();           // all waves done reading buf bi
    if (t + 2 < nt) stage(bi, (t + 2) << 6);
    if (t + 1 < nt) {
      if (t + 2 < nt) asm volatile("s_waitcnt vmcnt(8)" ::: "memory");
      else            asm volatile("s_waitcnt vmcnt(0)" ::: "memory");
      __builtin_amdgcn_s_barrier();         // tile t+1 visible to all waves
      __builtin_amdgcn_sched_barrier(0);
    }
  }

  const size_t cb = (size_t)(bz * sC);
#pragma unroll
  for (int i = 0; i < 8; ++i) {
    const int row0 = tm * 256 + wr * 128 + i * 16 + (lane >> 4) * 4;
#pragma unroll
    for (int j = 0; j < 4; ++j) {
      const int col = tn * 256 + wc * 64 + j * 16 + (lane & 15);
      float bv = 0.f;
      if (BIAS) bv = bias[bz * sBias + col];
#pragma unroll
      for (int rr = 0; rr < 4; ++rr) {
        float v = acc[i][j][rr] * alpha + bv;
        if constexpr (OMODE == 0)
          ((float*)Cg)[cb + (size_t)(row0 + rr) * N + col] = v;
        else
          ((unsigned short*)Cg)[cb + (size_t)(row0 + rr) * N + col] = f2bf(v);
      }
    }
  }
}

// 4 independent 768^3 NT GEMMs in one launch (fold products). bf16 out, no bias.
struct QuadPtrs {
  const unsigned short* a[4];
  const unsigned short* b[4];
  unsigned short* c[4];
};
__global__ __launch_bounds__(256) void gemm_nt_quad(QuadPtrs p) {
  __shared__ __align__(16) unsigned short As[128 * 32];
  __shared__ __align__(16) unsigned short Bs[128 * 32];
  const int zi = blockIdx.z;
  gemm_body<1, false>(p.a[zi], p.b[zi], nullptr, (void*)p.c[zi], 0,
                      768, 768, blockIdx.y, blockIdx.x, 1.0f, As, Bs);
}

template<int LR>
__global__ __launch_bounds__(256) void softmax_kernel(
    const float* __restrict__ sc, unsigned short* __restrict__ p)
{
  const int row  = blockIdx.x * 4 + (threadIdx.x >> 6);
  const int lane = threadIdx.x & 63;
  constexpr int PER = LR / 64;
  const float* sr = sc + (size_t)row * LR;
  float v[PER];
  float m = -1e30f;
#pragma unroll
  for (int j = 0; j < PER; ++j) { v[j] = sr[lane + 64 * j]; m = fmaxf(m, v[j]); }
  m = wmax(m);
  float s = 0.f;
#pragma unroll
  for (int j = 0; j < PER; ++j) { v[j] = __expf(v[j] - m); s += v[j]; }
  s = wsum(s);
  const float inv = 1.f / s;
  unsigned short* pr = p + (size_t)row * LR;
#pragma unroll
  for (int j = 0; j < PER; ++j) pr[lane + 64 * j] = f2bf(v[j] * inv);
}

// GRU combine with inline LN of old mem (h) + emit next operand.
template<bool GHB, bool EMITLN>
__global__ __launch_bounds__(256) void gru_ln_combine(
    const unsigned short* __restrict__ gi, const unsigned short* __restrict__ gh,
    float* __restrict__ mem, const float* __restrict__ g, const float* __restrict__ b,
    unsigned short* __restrict__ outb)
{
  __shared__ float ps[4], pq[4];
  const size_t row = blockIdx.x;
  const int tid = threadIdx.x, wv = tid >> 6, lane = tid & 63;
  float* mr = mem + row * 768;
  const size_t ghrow = GHB ? (row & 127) : row;
  float v[3];
  float s = 0.f, q = 0.f;
#pragma unroll
  for (int k = 0; k < 3; ++k) {
    v[k] = mr[tid + 256 * k];
    s += v[k]; q += v[k] * v[k];
  }
  s = wsum(s); q = wsum(q);
  if (lane == 0) { ps[wv] = s; pq[wv] = q; }
  __syncthreads();
  s = ps[0] + ps[1] + ps[2] + ps[3];
  q = pq[0] + pq[1] + pq[2] + pq[3];
  const float mu = s * (1.f / 768.f);
  const float rstd = rsqrtf(q * (1.f / 768.f) - mu * mu + 1e-5f);
  float nv[3];
  float s2 = 0.f, q2 = 0.f;
#pragma unroll
  for (int k = 0; k < 3; ++k) {
    const int c = tid + 256 * k;
    const float h = (v[k] - mu) * rstd * g[c] + b[c];
    const float ir  = bf2f(gi[row * 2304 + c]);
    const float iz  = bf2f(gi[row * 2304 + 768 + c]);
    const float in_ = bf2f(gi[row * 2304 + 1536 + c]);
    const float hr  = bf2f(gh[ghrow * 2304 + c]);
    const float hz  = bf2f(gh[ghrow * 2304 + 768 + c]);
    const float hn  = bf2f(gh[ghrow * 2304 + 1536 + c]);
    const float rg = 1.f / (1.f + __expf(-(ir + hr)));
    const float zg = 1.f / (1.f + __expf(-(iz + hz)));
    const float n  = tanhf(in_ + rg * hn);
    nv[k] = (1.f - zg) * n + zg * h;
    mr[c] = nv[k];
    s2 += nv[k]; q2 += nv[k] * nv[k];
  }
  if (EMITLN) {
    s2 = wsum(s2); q2 = wsum(q2);
    __syncthreads();
    if (lane == 0) { ps[wv] = s2; pq[wv] = q2; }
    __syncthreads();
    s2 = ps[0] + ps[1] + ps[2] + ps[3];
    q2 = pq[0] + pq[1] + pq[2] + pq[3];
    const float mu2 = s2 * (1.f / 768.f);
    const float rstd2 = rsqrtf(q2 * (1.f / 768.f) - mu2 * mu2 + 1e-5f);
#pragma unroll
    for (int k = 0; k < 3; ++k) {
      const int c = tid + 256 * k;
      outb[row * 768 + c] = f2bf((nv[k] - mu2) * rstd2 * g[c] + b[c]);
    }
  } else {
#pragma unroll
    for (int k = 0; k < 3; ++k) {
      const int c = tid + 256 * k;
      outb[row * 768 + c] = f2bf(nv[k]);
    }
  }
}

__global__ __launch_bounds__(256) void cvt_bf16(
    const float* __restrict__ in, unsigned short* __restrict__ out, int n4)
{
  const int i = blockIdx.x * 256 + threadIdx.x;
  if (i >= n4) return;
  const float4 v = ((const float4*)in)[i];
  us4 o;
  o.x = f2bf(v.x); o.y = f2bf(v.y); o.z = f2bf(v.z); o.w = f2bf(v.w);
  ((us4*)out)[i] = o;
}

// Merged weight conversion: 10 fp32 sources -> contiguous bf16 region.
__global__ __launch_bounds__(256) void cvt_weights(
    const float* p0, const float* p1, const float* p2, const float* p3,
    const float* p4, const float* p5, const float* p6, const float* p7,
    const float* p8, const float* p9, unsigned short* __restrict__ dst)
{
  const int i = blockIdx.x * 256 + threadIdx.x;  // f4 index, total 2064384
  if (i >= 2064384) return;
  const float* src; int base;
  if      (i < 147456)  { src = p0; base = 0; }
  else if (i < 294912)  { src = p1; base = 147456; }
  else if (i < 442368)  { src = p2; base = 294912; }
  else if (i < 589824)  { src = p3; base = 442368; }
  else if (i < 737280)  { src = p4; base = 589824; }
  else if (i < 884736)  { src = p5; base = 737280; }
  else if (i < 1032192) { src = p6; base = 884736; }
  else if (i < 1179648) { src = p7; base = 1032192; }
  else if (i < 1622016) { src = p8; base = 1179648; }
  else                  { src = p9; base = 1622016; }
  const float4 v = ((const float4*)src)[i - base];
  us4 o;
  o.x = f2bf(v.x); o.y = f2bf(v.y); o.z = f2bf(v.z); o.w = f2bf(v.w);
  ((us4*)dst)[i] = o;
}

// memf[b,s,:] = slots[s,:]; memb[b,s,:] = bf16(LN(slots[s,:])). One block per slot.
__global__ __launch_bounds__(256) void init_mem(
    const float* __restrict__ slots, const float* __restrict__ g,
    const float* __restrict__ b, float* __restrict__ memf,
    unsigned short* __restrict__ memb)
{
  __shared__ float ps[4], pq[4];
  const int s = blockIdx.x;            // 0..127
  const int tid = threadIdx.x, wv = tid >> 6, lane = tid & 63;
  const float* sr = slots + (size_t)s * 768;
  float v[3];
  float su = 0.f, qu = 0.f;
#pragma unroll
  for (int k = 0; k < 3; ++k) { v[k] = sr[tid + 256 * k]; su += v[k]; qu += v[k] * v[k]; }
  su = wsum(su); qu = wsum(qu);
  if (lane == 0) { ps[wv] = su; pq[wv] = qu; }
  __syncthreads();
  su = ps[0] + ps[1] + ps[2] + ps[3];
  qu = pq[0] + pq[1] + pq[2] + pq[3];
  const float mu = su * (1.f / 768.f);
  const float rstd = rsqrtf(qu * (1.f / 768.f) - mu * mu + 1e-5f);
  unsigned short lb[3];
#pragma unroll
  for (int k = 0; k < 3; ++k) {
    const int c = tid + 256 * k;
    lb[k] = f2bf((v[k] - mu) * rstd * g[c] + b[c]);
  }
  for (int bb = 0; bb < 64; ++bb) {
    float* mrow = memf + ((size_t)bb * 128 + s) * 768;
    unsigned short* brow = memb + ((size_t)bb * 128 + s) * 768;
#pragma unroll
    for (int k = 0; k < 3; ++k) { mrow[tid + 256 * k] = v[k]; brow[tid + 256 * k] = lb[k]; }
  }
}

// Batched bf16 transpose: in [R,C] -> out [C,R], batch stride R*C.
__global__ void transpose_bf16(const unsigned short* __restrict__ in,
                               unsigned short* __restrict__ out, int R, int C)
{
  __shared__ unsigned short t[32][33];
  const size_t bofs = (size_t)blockIdx.z * R * C;
  const int c0 = blockIdx.x * 32, r0 = blockIdx.y * 32;
  const int x = threadIdx.x, y = threadIdx.y;
#pragma unroll
  for (int k = 0; k < 32; k += 8)
    t[y + k][x] = in[bofs + (size_t)(r0 + y + k) * C + c0 + x];
  __syncthreads();
#pragma unroll
  for (int k = 0; k < 32; k += 8)
    out[bofs + (size_t)(c0 + y + k) * R + r0 + x] = t[x][y + k];
}

// 6 independent 768x768 transposes in one launch.
struct TPtrs { const unsigned short* s[6]; unsigned short* d[6]; };
__global__ void transpose_multi(TPtrs p) {
  __shared__ unsigned short t[32][33];
  const unsigned short* in = p.s[blockIdx.z];
  unsigned short* out = p.d[blockIdx.z];
  const int c0 = blockIdx.x * 32, r0 = blockIdx.y * 32;
  const int x = threadIdx.x, y = threadIdx.y;
#pragma unroll
  for (int k = 0; k < 32; k += 8)
    t[y + k][x] = in[(size_t)(r0 + y + k) * 768 + c0 + x];
  __syncthreads();
#pragma unroll
  for (int k = 0; k < 32; k += 8)
    out[(size_t)(c0 + y + k) * 768 + r0 + x] = t[x][y + k];
}

// Two y = W^T x jobs in one launch (grid 6: task = bx/3).
__global__ __launch_bounds__(256) void matvec_T2(
    const float* __restrict__ W0, const float* __restrict__ x0, float* __restrict__ y0,
    const float* __restrict__ W1, const float* __restrict__ x1, float* __restrict__ y1)
{
  const int task = blockIdx.x / 3;
  const int j = (blockIdx.x % 3) * 256 + threadIdx.x;
  const float* W = task ? W1 : W0;
  const float* x = task ? x1 : x0;
  float* y = task ? y1 : y0;
  float s = 0.f;
  for (int k = 0; k < 768; ++k) s += W[(size_t)k * 768 + j] * x[k];
  y[j] = s;
}

// Two y[row]=add[row]+dot(W[row,:],x) jobs (grid 384: task = bx/192).
__global__ __launch_bounds__(256) void matvec_row2(
    const float* __restrict__ W0, const float* __restrict__ x0,
    const float* __restrict__ a0, float* __restrict__ y0,
    const float* __restrict__ W1, const float* __restrict__ x1,
    const float* __restrict__ a1, float* __restrict__ y1)
{
  const int task = blockIdx.x / 192;
  const int row = (blockIdx.x % 192) * 4 + (threadIdx.x >> 6);
  const int lane = threadIdx.x & 63;
  const float* W = task ? W1 : W0;
  const float* x = task ? x1 : x0;
  const float* ad = task ? a1 : a0;
  float* y = task ? y1 : y0;
  const float* r = W + (size_t)row * 768;
  float s = 0.f;
#pragma unroll
  for (int j = 0; j < 12; ++j) s += r[lane + 64 * j] * x[lane + 64 * j];
  s = wsum(s);
  if (lane == 0) y[row] = s + ad[row];
}

// out[i] = scl * (dot(src_i, vec) + (cadd ? cadd[0] : 0))
__global__ __launch_bounds__(256) void rowdot768(
    const float* __restrict__ src, const float* __restrict__ vec,
    const float* __restrict__ cadd, float* __restrict__ out, float scl, int rows)
{
  const int row  = blockIdx.x * 4 + (threadIdx.x >> 6);
  if (row >= rows) return;
  const int lane = threadIdx.x & 63;
  const float* r = src + (size_t)row * 768;
  float s = 0.f;
#pragma unroll
  for (int j = 0; j < 12; ++j) s += r[lane + 64 * j] * vec[lane + 64 * j];
  s = wsum(s);
  if (lane == 0) out[row] = scl * (s + (cadd ? cadd[0] : 0.f));
}

// Fused: zb = bf16(z) AND zv[row] = scl*(dot(z_row, vw) + cw[0]). Wave per row.
__global__ __launch_bounds__(256) void cvt_z_zv(
    const float* __restrict__ z, unsigned short* __restrict__ zb,
    const float* __restrict__ vw, const float* __restrict__ cw,
    float* __restrict__ zv, float scl)
{
  const int row = blockIdx.x * 4 + (threadIdx.x >> 6);
  const int lane = threadIdx.x & 63;
  const float* zr = z + (size_t)row * 768;
  unsigned short* zbr = zb + (size_t)row * 768;
  float s = 0.f;
#pragma unroll
  for (int j = 0; j < 12; ++j) {
    const float v = zr[lane + 64 * j];
    s += v * vw[lane + 64 * j];
    zbr[lane + 64 * j] = f2bf(v);
  }
  s = wsum(s);
  if (lane == 0) zv[row] = scl * (s + cw[0]);
}

__global__ __launch_bounds__(256) void diag_ws(float* __restrict__ out, float wsz, int n) {
  const int i = blockIdx.x * 256 + threadIdx.x;
  if (i < n) out[i] = (i == 0) ? wsz : 0.f;
}

extern "C" void kernel_launch(void* const* d_in, const int* in_sizes, int n_in,
                              void* d_out, int out_size, void* d_ws, size_t ws_size,
                              hipStream_t stream)
{
  const float* z     = (const float*)d_in[0];
  const float* slots = (const float*)d_in[1];
  const float* ln_g  = (const float*)d_in[2];
  const float* ln_b  = (const float*)d_in[3];
  const float* w_wq = (const float*)d_in[4];  const float* w_bq = (const float*)d_in[5];
  const float* w_wk = (const float*)d_in[6];  const float* w_bk = (const float*)d_in[7];
  const float* w_wv = (const float*)d_in[8];  const float* w_bv = (const float*)d_in[9];
  const float* w_wo = (const float*)d_in[10]; const float* w_bo = (const float*)d_in[11];
  const float* r_wq = (const float*)d_in[12]; const float* r_bq = (const float*)d_in[13];
  const float* r_wk = (const float*)d_in[14]; const float* r_bk = (const float*)d_in[15];
  const float* r_wv = (const float*)d_in[16]; const float* r_bv = (const float*)d_in[17];
  const float* r_wo = (const float*)d_in[18]; const float* r_bo = (const float*)d_in[19];
  const float* g_wih = (const float*)d_in[20]; const float* g_bih = (const float*)d_in[21];
  const float* g_whh = (const float*)d_in[22]; const float* g_bhh = (const float*)d_in[23];

  // ---- arena (bytes) ----
  constexpr size_t O_F    = 16515072;    // Fqk,Fwv,Fvo,Frq
  constexpr size_t O_T6   = 21233664;    // 6 transposed weights
  constexpr size_t O_GH0  = 28311552;    // 589824
  constexpr size_t O_FL   = 28901376;    // float vectors
  constexpr size_t O_memf = 29096192;    // 25165824
  constexpr size_t O_Kz   = 54262016;    // 50331648: tmpV -> Kz | end: memFr
  constexpr size_t O_VwoT = 104593664;   // 50331648: VwoT | end: memVo/memVoT/Sbr/Abr
  constexpr size_t O_L    = 154925312;   // 62914560 scratch
  constexpr size_t NEED   = 217839872;

  if (ws_size < NEED) {
    hipLaunchKernelGGL(diag_ws, dim3((out_size + 255) / 256), dim3(256), 0, stream,
                       (float*)d_out, (float)ws_size, out_size);
    return;
  }

  char* ws = (char*)d_ws;
  unsigned short* wqb  = (unsigned short*)(ws + 0);
  unsigned short* wkb  = wqb + 589824;
  unsigned short* wvb  = wkb + 589824;
  unsigned short* wob  = wvb + 589824;
  unsigned short* rqb  = wob + 589824;
  unsigned short* rkb  = rqb + 589824;
  unsigned short* rvb  = rkb + 589824;
  unsigned short* rob  = rvb + 589824;
  unsigned short* wihb = rob + 589824;
  unsigned short* whhb = wihb + 1769472;
  unsigned short* Fqk  = (unsigned short*)(ws + O_F);
  unsigned short* Fwv  = Fqk + 589824;
  unsigned short* Fvo  = Fwv + 589824;
  unsigned short* Frq  = Fvo + 589824;
  unsigned short* T0   = (unsigned short*)(ws + O_T6);
  unsigned short* T1   = T0 + 589824;
  unsigned short* T2   = T1 + 589824;
  unsigned short* T3   = T2 + 589824;
  unsigned short* T4   = T3 + 589824;
  unsigned short* T5   = T4 + 589824;
  unsigned short* gh0  = (unsigned short*)(ws + O_GH0);
  float* bih_c   = (float*)(ws + O_FL);     // 2304 (+2304 bhh adjacent)
  float* bhh_c   = bih_c + 2304;
  float* const_o = bhh_c + 2304;
  float* bvo     = const_o + 768;
  float* vw      = bvo + 768;
  float* vr      = vw + 768;
  float* cw      = vr + 768;
  float* zv      = cw + 64;                 // 32768
  float* colb    = zv + 32768;              // 8192
  float* memf = (float*)(ws + O_memf);
  unsigned short* tmpV  = (unsigned short*)(ws + O_Kz);
  unsigned short* Kz    = (unsigned short*)(ws + O_Kz);
  unsigned short* memFr = (unsigned short*)(ws + O_Kz);            // end
  unsigned short* VwoT  = (unsigned short*)(ws + O_VwoT);
  unsigned short* memVo   = (unsigned short*)(ws + O_VwoT);             // end
  unsigned short* memVoT  = (unsigned short*)(ws + O_VwoT + 12582912);  // end
  float*          Sbr     = (float*)(ws + O_VwoT + 25165824);           // end
  unsigned short* Abr     = (unsigned short*)(ws + O_VwoT + 41943040);  // end
  char* L = ws + O_L;
  unsigned short* zb    = (unsigned short*)(L + 0);          // prologue 48MiB
  unsigned short* memb  = (unsigned short*)(L + 0);          // loop (aliases zb!)
  unsigned short* updb  = (unsigned short*)(L + 12582912);
  float*          Sbuf  = (float*)(L + 25165824);            // 16MiB
  unsigned short* Abuf  = (unsigned short*)(L + 41943040);   // 8MiB
  unsigned short* gib   = (unsigned short*)(L + 25165824);   // 37.7MiB full (S/A dead)
  unsigned short* ghb   = (unsigned short*)d_out;            // 37.7MiB in d_out scratch
  unsigned short* zb2   = (unsigned short*)(L + 12582912);   // end 48MiB

  const float scale = 1.0f / sqrtf(768.f);

  // ---- prologue ----
  hipLaunchKernelGGL(cvt_weights, dim3(8064), dim3(256), 0, stream,
      w_wq, w_wk, w_wv, w_wo, r_wq, r_wk, r_wv, r_wo, g_wih, g_whh, wqb);
  hipMemcpyAsync(bih_c, g_bih, 2304 * 4, hipMemcpyDeviceToDevice, stream);
  hipMemcpyAsync(bhh_c, g_bhh, 2304 * 4, hipMemcpyDeviceToDevice, stream);

  {
    TPtrs tp;
    tp.s[0] = wqb; tp.d[0] = T0;
    tp.s[1] = wkb; tp.d[1] = T1;
    tp.s[2] = wvb; tp.d[2] = T2;
    tp.s[3] = rvb; tp.d[3] = T3;
    tp.s[4] = rqb; tp.d[4] = T4;
    tp.s[5] = rkb; tp.d[5] = T5;
    hipLaunchKernelGGL(transpose_multi, dim3(24, 24, 6), dim3(32, 8), 0, stream, tp);
  }
  {
    QuadPtrs qp;
    qp.a[0] = T0;  qp.b[0] = T1; qp.c[0] = Fqk;  // Wq^T Wk
    qp.a[1] = wob; qp.b[1] = T2; qp.c[1] = Fwv;  // Wo Wv
    qp.a[2] = rob; qp.b[2] = T3; qp.c[2] = Fvo;  // Ro Rv
    qp.a[3] = T4;  qp.b[3] = T5; qp.c[3] = Frq;  // Rq^T Rk
    hipLaunchKernelGGL(gemm_nt_quad, dim3(6, 6, 4), dim3(256), 0, stream, qp);
  }

  hipLaunchKernelGGL(matvec_T2, dim3(6), dim3(256), 0, stream,
      w_wk, w_bq, vw, r_wk, r_bq, vr);
  hipLaunchKernelGGL(matvec_row2, dim3(384), dim3(256), 0, stream,
      w_wo, w_bv, w_bo, const_o, r_wo, r_bv, r_bo, bvo);
  hipLaunchKernelGGL(rowdot768, dim3(1), dim3(256), 0, stream,
      w_bq, w_bk, (const float*)nullptr, cw, 1.0f, 1);
  hipLaunchKernelGGL(cvt_z_zv, dim3(8192), dim3(256), 0, stream, z, zb, vw, cw, zv, scale);

  // Vwo = z.Fwv^T -> tmpV -> transpose -> VwoT; then Kz = z.Fqk^T.  (8-phase engine)
  hipLaunchKernelGGL((gemm_nt8<1, false>), dim3(3, 128, 1), dim3(512), 0, stream,
      zb, Fwv, (const float*)nullptr, (void*)tmpV, 32768, 768, 768, 0ll, 0ll, 0ll, 0ll, 1.0f);
  hipLaunchKernelGGL(transpose_bf16, dim3(24, 16, 64), dim3(32, 8), 0, stream,
      tmpV, VwoT, 512, 768);
  hipLaunchKernelGGL((gemm_nt8<1, false>), dim3(3, 128, 1), dim3(512), 0, stream,
      zb, Fqk, (const float*)nullptr, (void*)Kz, 32768, 768, 768, 0ll, 0ll, 0ll, 0ll, 1.0f);

  // init AFTER last zb reader (memb aliases zb)
  hipLaunchKernelGGL(init_mem, dim3(128), dim3(256), 0, stream,
      slots, ln_g, ln_b, memf, memb);

  const long long sA_g = (long long)(memb - updb);  // z=1 -> memb
  const long long sC_g = (long long)(ghb - gib);    // z=1 -> gh in d_out scratch

  // ---- T=3 recurrence ----
  for (int t = 0; t < 3; ++t) {
    hipLaunchKernelGGL((gemm_nt<0, true>), dim3(4, 1, 64), dim3(256), 0, stream,
        memb, Kz, zv, (void*)Sbuf, 128, 512, 768,
        98304ll, 393216ll, 65536ll, 512ll, scale);
    hipLaunchKernelGGL((softmax_kernel<512>), dim3(2048), dim3(256), 0, stream, Sbuf, Abuf);
    hipLaunchKernelGGL((gemm_nt<1, true>), dim3(6, 1, 64), dim3(256), 0, stream,
        Abuf, VwoT, const_o, (void*)updb, 128, 768, 512,
        65536ll, 393216ll, 98304ll, 0ll, 1.0f);
    if (t == 0) {
      hipLaunchKernelGGL((gemm_nt<1, true>), dim3(18, 1, 1), dim3(256), 0, stream,
          memb, whhb, bhh_c, (void*)gh0, 128, 2304, 768, 0ll, 0ll, 0ll, 0ll, 1.0f);
      hipLaunchKernelGGL((gemm_nt8<1, true>), dim3(9, 32, 1), dim3(512), 0, stream,
          updb, wihb, bih_c, (void*)gib, 8192, 2304, 768, 0ll, 0ll, 0ll, 0ll, 1.0f);
      hipLaunchKernelGGL((gru_ln_combine<true, true>), dim3(8192), dim3(256), 0, stream,
          gib, gh0, memf, ln_g, ln_b, memb);
    } else {
      hipLaunchKernelGGL((gemm_nt8<1, true>), dim3(9, 32, 2), dim3(512), 0, stream,
          updb, wihb, bih_c, (void*)gib, 8192, 2304, 768,
          sA_g, 1769472ll, sC_g, 2304ll, 1.0f);
      if (t < 2)
        hipLaunchKernelGGL((gru_ln_combine<false, true>), dim3(8192), dim3(256), 0, stream,
            gib, ghb, memf, ln_g, ln_b, memb);
      else
        hipLaunchKernelGGL((gru_ln_combine<false, false>), dim3(8192), dim3(256), 0, stream,
            gib, ghb, memf, ln_g, ln_b, memb);
    }
  }
  // memb now holds bf16(mem_final)

  // ---- read attention ----
  hipLaunchKernelGGL((gemm_nt8<1, false>), dim3(3, 32, 2), dim3(512), 0, stream,
      memb, Frq, (const float*)nullptr, (void*)memFr, 8192, 768, 768,
      0ll, (long long)(Fvo - Frq), 25165824ll, 0ll, 1.0f);
  hipLaunchKernelGGL(transpose_bf16, dim3(24, 4, 64), dim3(32, 8), 0, stream,
      memVo, memVoT, 128, 768);
  hipLaunchKernelGGL(rowdot768, dim3(2048), dim3(256), 0, stream,
      memf, vr, (const float*)nullptr, colb, scale, 8192);
  {
    const int n4 = 6291456;
    hipLaunchKernelGGL(cvt_bf16, dim3(24576), dim3(256), 0, stream, z, zb2, n4);
  }
  hipLaunchKernelGGL((gemm_nt<0, true>), dim3(1, 4, 64), dim3(256), 0, stream,
      zb2, memFr, colb, (void*)Sbr, 512, 128, 768,
      393216ll, 98304ll, 65536ll, 128ll, scale);
  hipLaunchKernelGGL((softmax_kernel<128>), dim3(8192), dim3(256), 0, stream, Sbr, Abr);
  hipLaunchKernelGGL((gemm_nt8<0, true>), dim3(3, 2, 64), dim3(512), 0, stream,
      Abr, memVoT, bvo, d_out, 512, 768, 128,
      65536ll, 98304ll, 393216ll, 0ll, 1.0f);
}

// Round 9
// 866.316 us; speedup vs baseline: 1.3818x; 1.0062x over previous
//
#include <hip/hip_runtime.h>
#include <hip/hip_bf16.h>
#include <math.h>

// Memory module: E=768, S=128, T=3, B=64, L=512. fp32 in/out.
// bf16 MFMA GEMMs (fp32 accum). Folds: Fqk=Wq^T Wk, Fwv=Wo Wv, Fvo=Ro Rv, Frq=Rq^T Rk.
// gemm_nt8: 256x256 tile, BK=64, 8 waves, per-phase barriers (4 phases/K-tile),
// half-tile staged prefetch with counted vmcnt(8), swizzled LDS (2-way, free).
// gh gates for t>=1 staged in d_out scratch (final GEMM overwrites d_out last).

typedef __attribute__((ext_vector_type(4))) float f32x4;
typedef __attribute__((ext_vector_type(8))) short short8;
typedef __attribute__((ext_vector_type(4))) unsigned short us4;

__device__ __forceinline__ unsigned short f2bf(float x) {
  union { float f; unsigned u; } v; v.f = x;
  unsigned r = v.u + 0x7fffu + ((v.u >> 16) & 1u);  // RNE
  return (unsigned short)(r >> 16);
}
__device__ __forceinline__ float bf2f(unsigned short u) {
  union { unsigned u; float f; } v; v.u = (unsigned)u << 16; return v.f;
}

__device__ __forceinline__ void g2l16(const void* g, void* l) {
  __builtin_amdgcn_global_load_lds(
      (const __attribute__((address_space(1))) unsigned int*)g,
      (__attribute__((address_space(3))) unsigned int*)l, 16, 0, 0);
}

__device__ __forceinline__ float wsum(float v) {
#pragma unroll
  for (int o = 32; o > 0; o >>= 1) v += __shfl_xor(v, o, 64);
  return v;
}
__device__ __forceinline__ float wmax(float v) {
#pragma unroll
  for (int o = 32; o > 0; o >>= 1) v = fmaxf(v, __shfl_xor(v, o, 64));
  return v;
}

// m204 bijective XCD swizzle of flattened grid -> (tn, tm, bz)
__device__ __forceinline__ void xcd_map(int& tn, int& tm, long long& bz) {
  const int gx = gridDim.x, gy = gridDim.y, gz = gridDim.z;
  const int nwg = gx * gy * gz;
  const int lin = blockIdx.x + gx * (blockIdx.y + gy * blockIdx.z);
  const int q = nwg >> 3, r = nwg & 7;
  const int xcd = lin & 7, jj = lin >> 3;
  const int w = (xcd < r ? xcd * (q + 1) : r * (q + 1) + (xcd - r) * q) + jj;
  tn = w % gx;
  const int t2 = w / gx;
  tm = t2 % gy;
  bz = t2 / gy;
}

// ---- m97 128x128 NT GEMM body (small/odd shapes) ----
template<int OMODE, bool BIAS>
__device__ __forceinline__ void gemm_body(
    const unsigned short* __restrict__ A, const unsigned short* __restrict__ B,
    const float* __restrict__ bias, void* __restrict__ Cg, size_t cb,
    int N, int K, int tm, int tn, float alpha,
    unsigned short* As, unsigned short* Bs)
{
  const int tid  = threadIdx.x;
  const int lane = tid & 63;
  const int wv   = tid >> 6;
  const int wr   = wv >> 1, wc = wv & 1;

  A += (size_t)tm * 128 * K;
  B += (size_t)tn * 128 * K;

  const int srow = wv * 16 + (lane >> 2);
  const int kby  = (lane & 3) * 16;

  f32x4 acc[4][4];
#pragma unroll
  for (int a = 0; a < 4; ++a)
#pragma unroll
    for (int b = 0; b < 4; ++b) acc[a][b] = (f32x4)(0.f);

  const int mrow = wr * 64 + (lane & 15);
  const int nrow = wc * 64 + (lane & 15);
  const int koff = (lane >> 4) * 8;

  for (int kt = 0; kt < K; kt += 32) {
#pragma unroll
    for (int i = 0; i < 2; ++i) {
      g2l16((const char*)(A + (size_t)(i * 64 + srow) * K + kt) + kby,
            (char*)As + i * 4096 + wv * 1024);
      g2l16((const char*)(B + (size_t)(i * 64 + srow) * K + kt) + kby,
            (char*)Bs + i * 4096 + wv * 1024);
    }
    __syncthreads();
    short8 af[4], bf[4];
#pragma unroll
    for (int a = 0; a < 4; ++a) af[a] = *(const short8*)&As[(mrow + a * 16) * 32 + koff];
#pragma unroll
    for (int b = 0; b < 4; ++b) bf[b] = *(const short8*)&Bs[(nrow + b * 16) * 32 + koff];
#pragma unroll
    for (int a = 0; a < 4; ++a)
#pragma unroll
      for (int b = 0; b < 4; ++b)
        acc[a][b] = __builtin_amdgcn_mfma_f32_16x16x32_bf16(af[a], bf[b], acc[a][b], 0, 0, 0);
    __syncthreads();
  }

#pragma unroll
  for (int a = 0; a < 4; ++a) {
    const int row0 = tm * 128 + wr * 64 + a * 16 + (lane >> 4) * 4;
#pragma unroll
    for (int b = 0; b < 4; ++b) {
      const int col = tn * 128 + wc * 64 + b * 16 + (lane & 15);
      float bv = 0.f;
      if (BIAS) bv = bias[col];
#pragma unroll
      for (int rr = 0; rr < 4; ++rr) {
        float v = acc[a][b][rr] * alpha + bv;
        if constexpr (OMODE == 0)
          ((float*)Cg)[cb + (size_t)(row0 + rr) * N + col] = v;
        else
          ((unsigned short*)Cg)[cb + (size_t)(row0 + rr) * N + col] = f2bf(v);
      }
    }
  }
}

template<int OMODE, bool BIAS>
__global__ __launch_bounds__(256) void gemm_nt(
    const unsigned short* __restrict__ Ag, const unsigned short* __restrict__ Bg,
    const float* __restrict__ bias, void* __restrict__ Cg,
    int M, int N, int K, long long sA, long long sB, long long sC,
    long long sBias, float alpha)
{
  __shared__ __align__(16) unsigned short As[128 * 32];
  __shared__ __align__(16) unsigned short Bs[128 * 32];
  int tn, tm; long long bz;
  xcd_map(tn, tm, bz);
  const float* bp = BIAS ? bias + bz * sBias : (const float*)nullptr;
  gemm_body<OMODE, BIAS>(Ag + bz * sA, Bg + bz * sB, bp, Cg,
                         (size_t)(bz * sC), N, K, tm, tn, alpha, As, Bs);
}

// ---- 256x256 8-wave per-phase-scheduled NT GEMM ----
// LDS: [buf][khalf][256 rows][64B] per operand; stage unit = one 16KB k-half.
// Phase (p=0..3 per K-tile): reads+stage -> barrier -> lgkm0 -> 16 MFMA -> vmcnt -> barrier.
// Swizzle involution s(o)=o^(((o>>7)&3)<<4) on LDS bytes (read) and global src (stage).
// Requires per-batch M%256==0, N%256==0, K%64==0, K>=128 (nt>=2).
template<int OMODE, bool BIAS>
__global__ __launch_bounds__(512, 2) void gemm_nt8(
    const unsigned short* __restrict__ Ag, const unsigned short* __restrict__ Bg,
    const float* __restrict__ bias, void* __restrict__ Cg,
    int M, int N, int K, long long sA, long long sB, long long sC,
    long long sBias, float alpha)
{
  __shared__ __align__(16) unsigned short As[2][2][8192];  // [buf][khalf][256x32]
  __shared__ __align__(16) unsigned short Bs[2][2][8192];

  const int tid  = threadIdx.x;
  const int lane = tid & 63;
  const int wv   = tid >> 6;      // 0..7
  const int wr   = wv >> 2;       // 0..1 (M half)
  const int wc   = wv & 3;        // 0..3 (N quarter)
  const int kb16 = (lane >> 4) * 16;

  int tn, tm; long long bz;
  xcd_map(tn, tm, bz);

  const unsigned short* A = Ag + bz * sA + (size_t)tm * 256 * K;
  const unsigned short* B = Bg + bz * sB + (size_t)tn * 256 * K;

  // stage one 16KB k-half unit: linear LDS dest, pre-swizzled global source
  auto stageU = [&](const unsigned short* P, int ktile, int ks, char* ldsbase) {
#pragma unroll
    for (int c = 0; c < 2; ++c) {
      const int olin = c * 8192 + tid * 16;
      const int olog = olin ^ (((olin >> 7) & 3) << 4);
      const int row = olog >> 6, kbyte = olog & 63;
      g2l16((const char*)(P + (size_t)row * K) + ktile * 128 + ks * 64 + kbyte,
            ldsbase + c * 8192 + wv * 1024);
    }
  };

  f32x4 acc[8][4];
#pragma unroll
  for (int i = 0; i < 8; ++i)
#pragma unroll
    for (int j = 0; j < 4; ++j) acc[i][j] = (f32x4)(0.f);

  const int nt = K >> 6;

  // prologue: t0.A.k0, t0.B.k0, t0.A.k1, t0.B.k1, t1.A.k0, t1.B.k0
  stageU(A, 0, 0, (char*)&As[0][0][0]);
  stageU(B, 0, 0, (char*)&Bs[0][0][0]);
  stageU(A, 0, 1, (char*)&As[0][1][0]);
  stageU(B, 0, 1, (char*)&Bs[0][1][0]);
  stageU(A, 1, 0, (char*)&As[1][0][0]);
  stageU(B, 1, 0, (char*)&Bs[1][0][0]);
  asm volatile("s_waitcnt vmcnt(8)" ::: "memory");   // t0.k0 landed
  __builtin_amdgcn_s_barrier();
  __builtin_amdgcn_sched_barrier(0);

  short8 bf[4];
  for (int u = 0; u < nt; ++u) {
    const int bi = u & 1;
#pragma unroll
    for (int p = 0; p < 4; ++p) {
      const int ks = p >> 1, pr = p & 1;
      // ds-reads for this phase
      short8 af[4];
      {
        const char* base = (const char*)&As[bi][ks][0];
#pragma unroll
        for (int i = 0; i < 4; ++i) {
          int byt = (wr * 128 + (pr * 4 + i) * 16 + (lane & 15)) * 64 + kb16;
          byt ^= ((byt >> 7) & 3) << 4;
          af[i] = *(const short8*)(base + byt);
        }
      }
      if (pr == 0) {
        const char* base = (const char*)&Bs[bi][ks][0];
#pragma unroll
        for (int j = 0; j < 4; ++j) {
          int byt = (wc * 64 + j * 16 + (lane & 15)) * 64 + kb16;
          byt ^= ((byt >> 7) & 3) << 4;
          bf[j] = *(const short8*)(base + byt);
        }
      }
      // staged prefetch (targets proven read-complete; see schedule notes)
      if (p == 0 && u + 1 < nt) stageU(A, u + 1, 1, (char*)&As[(u + 1) & 1][1][0]);
      if (p == 1 && u + 1 < nt) stageU(B, u + 1, 1, (char*)&Bs[(u + 1) & 1][1][0]);
      if (p == 2 && u + 2 < nt) stageU(A, u + 2, 0, (char*)&As[bi][0][0]);
      if (p == 3 && u + 2 < nt) stageU(B, u + 2, 0, (char*)&Bs[bi][0][0]);

      __builtin_amdgcn_s_barrier();
      asm volatile("s_waitcnt lgkmcnt(0)" ::: "memory");
      __builtin_amdgcn_sched_barrier(0);
      __builtin_amdgcn_s_setprio(1);
#pragma unroll
      for (int i = 0; i < 4; ++i)
#pragma unroll
        for (int j = 0; j < 4; ++j)
          acc[pr * 4 + i][j] = __builtin_amdgcn_mfma_f32_16x16x32_bf16(
              af[i], bf[j], acc[pr * 4 + i][j], 0, 0, 0);
      __builtin_amdgcn_s_setprio(0);
      // counted vmcnt protecting the NEXT phases' reads (in-order retirement)
      if (p == 1) {
        if (u < nt - 1) asm volatile("s_waitcnt vmcnt(8)" ::: "memory");
        else            asm volatile("s_waitcnt vmcnt(0)" ::: "memory");
      }
      if (p == 3) {
        if (u < nt - 2)       asm volatile("s_waitcnt vmcnt(8)" ::: "memory");
        else if (u == nt - 2) asm volatile("s_waitcnt vmcnt(4)" ::: "memory");
      }
      __builtin_amdgcn_s_barrier();
    }
  }

  const size_t cb = (size_t)(bz * sC);
#pragma unroll
  for (int i = 0; i < 8; ++i) {
    const int row0 = tm * 256 + wr * 128 + i * 16 + (lane >> 4) * 4;
#pragma unroll
    for (int j = 0; j < 4; ++j) {
      const int col = tn * 256 + wc * 64 + j * 16 + (lane & 15);
      float bv = 0.f;
      if (BIAS) bv = bias[bz * sBias + col];
#pragma unroll
      for (int rr = 0; rr < 4; ++rr) {
        float v = acc[i][j][rr] * alpha + bv;
        if constexpr (OMODE == 0)
          ((float*)Cg)[cb + (size_t)(row0 + rr) * N + col] = v;
        else
          ((unsigned short*)Cg)[cb + (size_t)(row0 + rr) * N + col] = f2bf(v);
      }
    }
  }
}

// 4 independent 768^3 NT GEMMs in one launch (fold products). bf16 out, no bias.
struct QuadPtrs {
  const unsigned short* a[4];
  const unsigned short* b[4];
  unsigned short* c[4];
};
__global__ __launch_bounds__(256) void gemm_nt_quad(QuadPtrs p) {
  __shared__ __align__(16) unsigned short As[128 * 32];
  __shared__ __align__(16) unsigned short Bs[128 * 32];
  const int zi = blockIdx.z;
  gemm_body<1, false>(p.a[zi], p.b[zi], nullptr, (void*)p.c[zi], 0,
                      768, 768, blockIdx.y, blockIdx.x, 1.0f, As, Bs);
}

template<int LR>
__global__ __launch_bounds__(256) void softmax_kernel(
    const float* __restrict__ sc, unsigned short* __restrict__ p)
{
  const int row  = blockIdx.x * 4 + (threadIdx.x >> 6);
  const int lane = threadIdx.x & 63;
  constexpr int PER = LR / 64;
  const float* sr = sc + (size_t)row * LR;
  float v[PER];
  float m = -1e30f;
#pragma unroll
  for (int j = 0; j < PER; ++j) { v[j] = sr[lane + 64 * j]; m = fmaxf(m, v[j]); }
  m = wmax(m);
  float s = 0.f;
#pragma unroll
  for (int j = 0; j < PER; ++j) { v[j] = __expf(v[j] - m); s += v[j]; }
  s = wsum(s);
  const float inv = 1.f / s;
  unsigned short* pr = p + (size_t)row * LR;
#pragma unroll
  for (int j = 0; j < PER; ++j) pr[lane + 64 * j] = f2bf(v[j] * inv);
}

// GRU combine with inline LN of old mem (h) + emit next operand.
template<bool GHB, bool EMITLN>
__global__ __launch_bounds__(256) void gru_ln_combine(
    const unsigned short* __restrict__ gi, const unsigned short* __restrict__ gh,
    float* __restrict__ mem, const float* __restrict__ g, const float* __restrict__ b,
    unsigned short* __restrict__ outb)
{
  __shared__ float ps[4], pq[4];
  const size_t row = blockIdx.x;
  const int tid = threadIdx.x, wv = tid >> 6, lane = tid & 63;
  float* mr = mem + row * 768;
  const size_t ghrow = GHB ? (row & 127) : row;
  float v[3];
  float s = 0.f, q = 0.f;
#pragma unroll
  for (int k = 0; k < 3; ++k) {
    v[k] = mr[tid + 256 * k];
    s += v[k]; q += v[k] * v[k];
  }
  s = wsum(s); q = wsum(q);
  if (lane == 0) { ps[wv] = s; pq[wv] = q; }
  __syncthreads();
  s = ps[0] + ps[1] + ps[2] + ps[3];
  q = pq[0] + pq[1] + pq[2] + pq[3];
  const float mu = s * (1.f / 768.f);
  const float rstd = rsqrtf(q * (1.f / 768.f) - mu * mu + 1e-5f);
  float nv[3];
  float s2 = 0.f, q2 = 0.f;
#pragma unroll
  for (int k = 0; k < 3; ++k) {
    const int c = tid + 256 * k;
    const float h = (v[k] - mu) * rstd * g[c] + b[c];
    const float ir  = bf2f(gi[row * 2304 + c]);
    const float iz  = bf2f(gi[row * 2304 + 768 + c]);
    const float in_ = bf2f(gi[row * 2304 + 1536 + c]);
    const float hr  = bf2f(gh[ghrow * 2304 + c]);
    const float hz  = bf2f(gh[ghrow * 2304 + 768 + c]);
    const float hn  = bf2f(gh[ghrow * 2304 + 1536 + c]);
    const float rg = 1.f / (1.f + __expf(-(ir + hr)));
    const float zg = 1.f / (1.f + __expf(-(iz + hz)));
    const float n  = tanhf(in_ + rg * hn);
    nv[k] = (1.f - zg) * n + zg * h;
    mr[c] = nv[k];
    s2 += nv[k]; q2 += nv[k] * nv[k];
  }
  if (EMITLN) {
    s2 = wsum(s2); q2 = wsum(q2);
    __syncthreads();
    if (lane == 0) { ps[wv] = s2; pq[wv] = q2; }
    __syncthreads();
    s2 = ps[0] + ps[1] + ps[2] + ps[3];
    q2 = pq[0] + pq[1] + pq[2] + pq[3];
    const float mu2 = s2 * (1.f / 768.f);
    const float rstd2 = rsqrtf(q2 * (1.f / 768.f) - mu2 * mu2 + 1e-5f);
#pragma unroll
    for (int k = 0; k < 3; ++k) {
      const int c = tid + 256 * k;
      outb[row * 768 + c] = f2bf((nv[k] - mu2) * rstd2 * g[c] + b[c]);
    }
  } else {
#pragma unroll
    for (int k = 0; k < 3; ++k) {
      const int c = tid + 256 * k;
      outb[row * 768 + c] = f2bf(nv[k]);
    }
  }
}

__global__ __launch_bounds__(256) void cvt_bf16(
    const float* __restrict__ in, unsigned short* __restrict__ out, int n4)
{
  const int i = blockIdx.x * 256 + threadIdx.x;
  if (i >= n4) return;
  const float4 v = ((const float4*)in)[i];
  us4 o;
  o.x = f2bf(v.x); o.y = f2bf(v.y); o.z = f2bf(v.z); o.w = f2bf(v.w);
  ((us4*)out)[i] = o;
}

// Merged weight conversion: 10 fp32 sources -> contiguous bf16 region.
__global__ __launch_bounds__(256) void cvt_weights(
    const float* p0, const float* p1, const float* p2, const float* p3,
    const float* p4, const float* p5, const float* p6, const float* p7,
    const float* p8, const float* p9, unsigned short* __restrict__ dst)
{
  const int i = blockIdx.x * 256 + threadIdx.x;  // f4 index, total 2064384
  if (i >= 2064384) return;
  const float* src; int base;
  if      (i < 147456)  { src = p0; base = 0; }
  else if (i < 294912)  { src = p1; base = 147456; }
  else if (i < 442368)  { src = p2; base = 294912; }
  else if (i < 589824)  { src = p3; base = 442368; }
  else if (i < 737280)  { src = p4; base = 589824; }
  else if (i < 884736)  { src = p5; base = 737280; }
  else if (i < 1032192) { src = p6; base = 884736; }
  else if (i < 1179648) { src = p7; base = 1032192; }
  else if (i < 1622016) { src = p8; base = 1179648; }
  else                  { src = p9; base = 1622016; }
  const float4 v = ((const float4*)src)[i - base];
  us4 o;
  o.x = f2bf(v.x); o.y = f2bf(v.y); o.z = f2bf(v.z); o.w = f2bf(v.w);
  ((us4*)dst)[i] = o;
}

// memf[b,s,:] = slots[s,:]; memb[b,s,:] = bf16(LN(slots[s,:])). One block per slot.
__global__ __launch_bounds__(256) void init_mem(
    const float* __restrict__ slots, const float* __restrict__ g,
    const float* __restrict__ b, float* __restrict__ memf,
    unsigned short* __restrict__ memb)
{
  __shared__ float ps[4], pq[4];
  const int s = blockIdx.x;            // 0..127
  const int tid = threadIdx.x, wv = tid >> 6, lane = tid & 63;
  const float* sr = slots + (size_t)s * 768;
  float v[3];
  float su = 0.f, qu = 0.f;
#pragma unroll
  for (int k = 0; k < 3; ++k) { v[k] = sr[tid + 256 * k]; su += v[k]; qu += v[k] * v[k]; }
  su = wsum(su); qu = wsum(qu);
  if (lane == 0) { ps[wv] = su; pq[wv] = qu; }
  __syncthreads();
  su = ps[0] + ps[1] + ps[2] + ps[3];
  qu = pq[0] + pq[1] + pq[2] + pq[3];
  const float mu = su * (1.f / 768.f);
  const float rstd = rsqrtf(qu * (1.f / 768.f) - mu * mu + 1e-5f);
  unsigned short lb[3];
#pragma unroll
  for (int k = 0; k < 3; ++k) {
    const int c = tid + 256 * k;
    lb[k] = f2bf((v[k] - mu) * rstd * g[c] + b[c]);
  }
  for (int bb = 0; bb < 64; ++bb) {
    float* mrow = memf + ((size_t)bb * 128 + s) * 768;
    unsigned short* brow = memb + ((size_t)bb * 128 + s) * 768;
#pragma unroll
    for (int k = 0; k < 3; ++k) { mrow[tid + 256 * k] = v[k]; brow[tid + 256 * k] = lb[k]; }
  }
}

// Batched bf16 transpose: in [R,C] -> out [C,R], batch stride R*C.
__global__ void transpose_bf16(const unsigned short* __restrict__ in,
                               unsigned short* __restrict__ out, int R, int C)
{
  __shared__ unsigned short t[32][33];
  const size_t bofs = (size_t)blockIdx.z * R * C;
  const int c0 = blockIdx.x * 32, r0 = blockIdx.y * 32;
  const int x = threadIdx.x, y = threadIdx.y;
#pragma unroll
  for (int k = 0; k < 32; k += 8)
    t[y + k][x] = in[bofs + (size_t)(r0 + y + k) * C + c0 + x];
  __syncthreads();
#pragma unroll
  for (int k = 0; k < 32; k += 8)
    out[bofs + (size_t)(c0 + y + k) * R + r0 + x] = t[x][y + k];
}

// 6 independent 768x768 transposes in one launch.
struct TPtrs { const unsigned short* s[6]; unsigned short* d[6]; };
__global__ void transpose_multi(TPtrs p) {
  __shared__ unsigned short t[32][33];
  const unsigned short* in = p.s[blockIdx.z];
  unsigned short* out = p.d[blockIdx.z];
  const int c0 = blockIdx.x * 32, r0 = blockIdx.y * 32;
  const int x = threadIdx.x, y = threadIdx.y;
#pragma unroll
  for (int k = 0; k < 32; k += 8)
    t[y + k][x] = in[(size_t)(r0 + y + k) * 768 + c0 + x];
  __syncthreads();
#pragma unroll
  for (int k = 0; k < 32; k += 8)
    out[(size_t)(c0 + y + k) * 768 + r0 + x] = t[x][y + k];
}

// Two y = W^T x jobs in one launch (grid 6: task = bx/3).
__global__ __launch_bounds__(256) void matvec_T2(
    const float* __restrict__ W0, const float* __restrict__ x0, float* __restrict__ y0,
    const float* __restrict__ W1, const float* __restrict__ x1, float* __restrict__ y1)
{
  const int task = blockIdx.x / 3;
  const int j = (blockIdx.x % 3) * 256 + threadIdx.x;
  const float* W = task ? W1 : W0;
  const float* x = task ? x1 : x0;
  float* y = task ? y1 : y0;
  float s = 0.f;
  for (int k = 0; k < 768; ++k) s += W[(size_t)k * 768 + j] * x[k];
  y[j] = s;
}

// Two y[row]=add[row]+dot(W[row,:],x) jobs (grid 384: task = bx/192).
__global__ __launch_bounds__(256) void matvec_row2(
    const float* __restrict__ W0, const float* __restrict__ x0,
    const float* __restrict__ a0, float* __restrict__ y0,
    const float* __restrict__ W1, const float* __restrict__ x1,
    const float* __restrict__ a1, float* __restrict__ y1)
{
  const int task = blockIdx.x / 192;
  const int row = (blockIdx.x % 192) * 4 + (threadIdx.x >> 6);
  const int lane = threadIdx.x & 63;
  const float* W = task ? W1 : W0;
  const float* x = task ? x1 : x0;
  const float* ad = task ? a1 : a0;
  float* y = task ? y1 : y0;
  const float* r = W + (size_t)row * 768;
  float s = 0.f;
#pragma unroll
  for (int j = 0; j < 12; ++j) s += r[lane + 64 * j] * x[lane + 64 * j];
  s = wsum(s);
  if (lane == 0) y[row] = s + ad[row];
}

// out[i] = scl * (dot(src_i, vec) + (cadd ? cadd[0] : 0))
__global__ __launch_bounds__(256) void rowdot768(
    const float* __restrict__ src, const float* __restrict__ vec,
    const float* __restrict__ cadd, float* __restrict__ out, float scl, int rows)
{
  const int row  = blockIdx.x * 4 + (threadIdx.x >> 6);
  if (row >= rows) return;
  const int lane = threadIdx.x & 63;
  const float* r = src + (size_t)row * 768;
  float s = 0.f;
#pragma unroll
  for (int j = 0; j < 12; ++j) s += r[lane + 64 * j] * vec[lane + 64 * j];
  s = wsum(s);
  if (lane == 0) out[row] = scl * (s + (cadd ? cadd[0] : 0.f));
}

// Fused: zb = bf16(z) AND zv[row] = scl*(dot(z_row, vw) + cw[0]). Wave per row.
__global__ __launch_bounds__(256) void cvt_z_zv(
    const float* __restrict__ z, unsigned short* __restrict__ zb,
    const float* __restrict__ vw, const float* __restrict__ cw,
    float* __restrict__ zv, float scl)
{
  const int row = blockIdx.x * 4 + (threadIdx.x >> 6);
  const int lane = threadIdx.x & 63;
  const float* zr = z + (size_t)row * 768;
  unsigned short* zbr = zb + (size_t)row * 768;
  float s = 0.f;
#pragma unroll
  for (int j = 0; j < 12; ++j) {
    const float v = zr[lane + 64 * j];
    s += v * vw[lane + 64 * j];
    zbr[lane + 64 * j] = f2bf(v);
  }
  s = wsum(s);
  if (lane == 0) zv[row] = scl * (s + cw[0]);
}

__global__ __launch_bounds__(256) void diag_ws(float* __restrict__ out, float wsz, int n) {
  const int i = blockIdx.x * 256 + threadIdx.x;
  if (i < n) out[i] = (i == 0) ? wsz : 0.f;
}

extern "C" void kernel_launch(void* const* d_in, const int* in_sizes, int n_in,
                              void* d_out, int out_size, void* d_ws, size_t ws_size,
                              hipStream_t stream)
{
  const float* z     = (const float*)d_in[0];
  const float* slots = (const float*)d_in[1];
  const float* ln_g  = (const float*)d_in[2];
  const float* ln_b  = (const float*)d_in[3];
  const float* w_wq = (const float*)d_in[4];  const float* w_bq = (const float*)d_in[5];
  const float* w_wk = (const float*)d_in[6];  const float* w_bk = (const float*)d_in[7];
  const float* w_wv = (const float*)d_in[8];  const float* w_bv = (const float*)d_in[9];
  const float* w_wo = (const float*)d_in[10]; const float* w_bo = (const float*)d_in[11];
  const float* r_wq = (const float*)d_in[12]; const float* r_bq = (const float*)d_in[13];
  const float* r_wk = (const float*)d_in[14]; const float* r_bk = (const float*)d_in[15];
  const float* r_wv = (const float*)d_in[16]; const float* r_bv = (const float*)d_in[17];
  const float* r_wo = (const float*)d_in[18]; const float* r_bo = (const float*)d_in[19];
  const float* g_wih = (const float*)d_in[20]; const float* g_bih = (const float*)d_in[21];
  const float* g_whh = (const float*)d_in[22]; const float* g_bhh = (const float*)d_in[23];

  // ---- arena (bytes) ----
  constexpr size_t O_F    = 16515072;    // Fqk,Fwv,Fvo,Frq
  constexpr size_t O_T6   = 21233664;    // 6 transposed weights
  constexpr size_t O_GH0  = 28311552;    // 589824
  constexpr size_t O_FL   = 28901376;    // float vectors
  constexpr size_t O_memf = 29096192;    // 25165824
  constexpr size_t O_Kz   = 54262016;    // 50331648: tmpV -> Kz | end: memFr
  constexpr size_t O_VwoT = 104593664;   // 50331648: VwoT | end: memVo/memVoT/Sbr/Abr
  constexpr size_t O_L    = 154925312;   // 62914560 scratch
  constexpr size_t NEED   = 217839872;

  if (ws_size < NEED) {
    hipLaunchKernelGGL(diag_ws, dim3((out_size + 255) / 256), dim3(256), 0, stream,
                       (float*)d_out, (float)ws_size, out_size);
    return;
  }

  char* ws = (char*)d_ws;
  unsigned short* wqb  = (unsigned short*)(ws + 0);
  unsigned short* wkb  = wqb + 589824;
  unsigned short* wvb  = wkb + 589824;
  unsigned short* wob  = wvb + 589824;
  unsigned short* rqb  = wob + 589824;
  unsigned short* rkb  = rqb + 589824;
  unsigned short* rvb  = rkb + 589824;
  unsigned short* rob  = rvb + 589824;
  unsigned short* wihb = rob + 589824;
  unsigned short* whhb = wihb + 1769472;
  unsigned short* Fqk  = (unsigned short*)(ws + O_F);
  unsigned short* Fwv  = Fqk + 589824;
  unsigned short* Fvo  = Fwv + 589824;
  unsigned short* Frq  = Fvo + 589824;
  unsigned short* T0   = (unsigned short*)(ws + O_T6);
  unsigned short* T1   = T0 + 589824;
  unsigned short* T2   = T1 + 589824;
  unsigned short* T3   = T2 + 589824;
  unsigned short* T4   = T3 + 589824;
  unsigned short* T5   = T4 + 589824;
  unsigned short* gh0  = (unsigned short*)(ws + O_GH0);
  float* bih_c   = (float*)(ws + O_FL);     // 2304 (+2304 bhh adjacent)
  float* bhh_c   = bih_c + 2304;
  float* const_o = bhh_c + 2304;
  float* bvo     = const_o + 768;
  float* vw      = bvo + 768;
  float* vr      = vw + 768;
  float* cw      = vr + 768;
  float* zv      = cw + 64;                 // 32768
  float* colb    = zv + 32768;              // 8192
  float* memf = (float*)(ws + O_memf);
  unsigned short* tmpV  = (unsigned short*)(ws + O_Kz);
  unsigned short* Kz    = (unsigned short*)(ws + O_Kz);
  unsigned short* memFr = (unsigned short*)(ws + O_Kz);            // end
  unsigned short* VwoT  = (unsigned short*)(ws + O_VwoT);
  unsigned short* memVo   = (unsigned short*)(ws + O_VwoT);             // end
  unsigned short* memVoT  = (unsigned short*)(ws + O_VwoT + 12582912);  // end
  float*          Sbr     = (float*)(ws + O_VwoT + 25165824);           // end
  unsigned short* Abr     = (unsigned short*)(ws + O_VwoT + 41943040);  // end
  char* L = ws + O_L;
  unsigned short* zb    = (unsigned short*)(L + 0);          // prologue 48MiB
  unsigned short* memb  = (unsigned short*)(L + 0);          // loop (aliases zb!)
  unsigned short* updb  = (unsigned short*)(L + 12582912);
  float*          Sbuf  = (float*)(L + 25165824);            // 16MiB
  unsigned short* Abuf  = (unsigned short*)(L + 41943040);   // 8MiB
  unsigned short* gib   = (unsigned short*)(L + 25165824);   // 37.7MiB (S/A dead)
  unsigned short* ghb   = (unsigned short*)d_out;            // 37.7MiB in d_out scratch
  unsigned short* zb2   = (unsigned short*)(L + 12582912);   // end 48MiB

  const float scale = 1.0f / sqrtf(768.f);

  // ---- prologue ----
  hipLaunchKernelGGL(cvt_weights, dim3(8064), dim3(256), 0, stream,
      w_wq, w_wk, w_wv, w_wo, r_wq, r_wk, r_wv, r_wo, g_wih, g_whh, wqb);
  hipMemcpyAsync(bih_c, g_bih, 2304 * 4, hipMemcpyDeviceToDevice, stream);
  hipMemcpyAsync(bhh_c, g_bhh, 2304 * 4, hipMemcpyDeviceToDevice, stream);

  {
    TPtrs tp;
    tp.s[0] = wqb; tp.d[0] = T0;
    tp.s[1] = wkb; tp.d[1] = T1;
    tp.s[2] = wvb; tp.d[2] = T2;
    tp.s[3] = rvb; tp.d[3] = T3;
    tp.s[4] = rqb; tp.d[4] = T4;
    tp.s[5] = rkb; tp.d[5] = T5;
    hipLaunchKernelGGL(transpose_multi, dim3(24, 24, 6), dim3(32, 8), 0, stream, tp);
  }
  {
    QuadPtrs qp;
    qp.a[0] = T0;  qp.b[0] = T1; qp.c[0] = Fqk;  // Wq^T Wk
    qp.a[1] = wob; qp.b[1] = T2; qp.c[1] = Fwv;  // Wo Wv
    qp.a[2] = rob; qp.b[2] = T3; qp.c[2] = Fvo;  // Ro Rv
    qp.a[3] = T4;  qp.b[3] = T5; qp.c[3] = Frq;  // Rq^T Rk
    hipLaunchKernelGGL(gemm_nt_quad, dim3(6, 6, 4), dim3(256), 0, stream, qp);
  }

  hipLaunchKernelGGL(matvec_T2, dim3(6), dim3(256), 0, stream,
      w_wk, w_bq, vw, r_wk, r_bq, vr);
  hipLaunchKernelGGL(matvec_row2, dim3(384), dim3(256), 0, stream,
      w_wo, w_bv, w_bo, const_o, r_wo, r_bv, r_bo, bvo);
  hipLaunchKernelGGL(rowdot768, dim3(1), dim3(256), 0, stream,
      w_bq, w_bk, (const float*)nullptr, cw, 1.0f, 1);
  hipLaunchKernelGGL(cvt_z_zv, dim3(8192), dim3(256), 0, stream, z, zb, vw, cw, zv, scale);

  // Vwo = z.Fwv^T -> tmpV -> transpose -> VwoT; then Kz = z.Fqk^T.
  hipLaunchKernelGGL((gemm_nt8<1, false>), dim3(3, 128, 1), dim3(512), 0, stream,
      zb, Fwv, (const float*)nullptr, (void*)tmpV, 32768, 768, 768, 0ll, 0ll, 0ll, 0ll, 1.0f);
  hipLaunchKernelGGL(transpose_bf16, dim3(24, 16, 64), dim3(32, 8), 0, stream,
      tmpV, VwoT, 512, 768);
  hipLaunchKernelGGL((gemm_nt8<1, false>), dim3(3, 128, 1), dim3(512), 0, stream,
      zb, Fqk, (const float*)nullptr, (void*)Kz, 32768, 768, 768, 0ll, 0ll, 0ll, 0ll, 1.0f);

  // init AFTER last zb reader (memb aliases zb)
  hipLaunchKernelGGL(init_mem, dim3(128), dim3(256), 0, stream,
      slots, ln_g, ln_b, memf, memb);

  const long long sA_g = (long long)(memb - updb);  // z=1 -> memb
  const long long sC_g = (long long)(ghb - gib);    // z=1 -> gh in d_out scratch

  // ---- T=3 recurrence ----
  for (int t = 0; t < 3; ++t) {
    hipLaunchKernelGGL((gemm_nt<0, true>), dim3(4, 1, 64), dim3(256), 0, stream,
        memb, Kz, zv, (void*)Sbuf, 128, 512, 768,
        98304ll, 393216ll, 65536ll, 512ll, scale);
    hipLaunchKernelGGL((softmax_kernel<512>), dim3(2048), dim3(256), 0, stream, Sbuf, Abuf);
    hipLaunchKernelGGL((gemm_nt<1, true>), dim3(6, 1, 64), dim3(256), 0, stream,
        Abuf, VwoT, const_o, (void*)updb, 128, 768, 512,
        65536ll, 393216ll, 98304ll, 0ll, 1.0f);
    if (t == 0) {
      hipLaunchKernelGGL((gemm_nt<1, true>), dim3(18, 1, 1), dim3(256), 0, stream,
          memb, whhb, bhh_c, (void*)gh0, 128, 2304, 768, 0ll, 0ll, 0ll, 0ll, 1.0f);
      hipLaunchKernelGGL((gemm_nt8<1, true>), dim3(9, 32, 1), dim3(512), 0, stream,
          updb, wihb, bih_c, (void*)gib, 8192, 2304, 768, 0ll, 0ll, 0ll, 0ll, 1.0f);
      hipLaunchKernelGGL((gru_ln_combine<true, true>), dim3(8192), dim3(256), 0, stream,
          gib, gh0, memf, ln_g, ln_b, memb);
    } else {
      hipLaunchKernelGGL((gemm_nt8<1, true>), dim3(9, 32, 2), dim3(512), 0, stream,
          updb, wihb, bih_c, (void*)gib, 8192, 2304, 768,
          sA_g, 1769472ll, sC_g, 2304ll, 1.0f);
      if (t < 2)
        hipLaunchKernelGGL((gru_ln_combine<false, true>), dim3(8192), dim3(256), 0, stream,
            gib, ghb, memf, ln_g, ln_b, memb);
      else
        hipLaunchKernelGGL((gru_ln_combine<false, false>), dim3(8192), dim3(256), 0, stream,
            gib, ghb, memf, ln_g, ln_b, memb);
    }
  }
  // memb now holds bf16(mem_final)

  // ---- read attention ----
  hipLaunchKernelGGL((gemm_nt8<1, false>), dim3(3, 32, 2), dim3(512), 0, stream,
      memb, Frq, (const float*)nullptr, (void*)memFr, 8192, 768, 768,
      0ll, (long long)(Fvo - Frq), 25165824ll, 0ll, 1.0f);
  hipLaunchKernelGGL(transpose_bf16, dim3(24, 4, 64), dim3(32, 8), 0, stream,
      memVo, memVoT, 128, 768);
  hipLaunchKernelGGL(rowdot768, dim3(2048), dim3(256), 0, stream,
      memf, vr, (const float*)nullptr, colb, scale, 8192);
  {
    const int n4 = 6291456;
    hipLaunchKernelGGL(cvt_bf16, dim3(24576), dim3(256), 0, stream, z, zb2, n4);
  }
  hipLaunchKernelGGL((gemm_nt<0, true>), dim3(1, 4, 64), dim3(256), 0, stream,
      zb2, memFr, colb, (void*)Sbr, 512, 128, 768,
      393216ll, 98304ll, 65536ll, 128ll, scale);
  hipLaunchKernelGGL((softmax_kernel<128>), dim3(8192), dim3(256), 0, stream, Sbr, Abr);
  hipLaunchKernelGGL((gemm_nt8<0, true>), dim3(3, 2, 64), dim3(512), 0, stream,
      Abr, memVoT, bvo, d_out, 512, 768, 128,
      65536ll, 98304ll, 393216ll, 0ll, 1.0f);
}

// Round 10
// 857.559 us; speedup vs baseline: 1.3959x; 1.0102x over previous
//
#include <hip/hip_runtime.h>
#include <hip/hip_bf16.h>
#include <math.h>

// Memory module: E=768, S=128, T=3, B=64, L=512. fp32 in/out.
// bf16 MFMA GEMMs (fp32 accum). Folds: Fqk=Wq^T Wk, Fwv=Wo Wv, Fvo=Ro Rv, Frq=Rq^T Rk.
// Engine selection by shape (round-10 finding):
//  - narrow-N fold GEMMs (N=768, K=768/128): gemm_nt8 256x256 deep-pipelined
//  - wide-N gate GEMMs (N=2304): m97 gemm_nt 128x128 (3-4 concurrent blocks/CU wins)
// gh gates for t>=1 staged in d_out scratch (final GEMM overwrites d_out last).

typedef __attribute__((ext_vector_type(4))) float f32x4;
typedef __attribute__((ext_vector_type(8))) short short8;
typedef __attribute__((ext_vector_type(4))) unsigned short us4;

__device__ __forceinline__ unsigned short f2bf(float x) {
  union { float f; unsigned u; } v; v.f = x;
  unsigned r = v.u + 0x7fffu + ((v.u >> 16) & 1u);  // RNE
  return (unsigned short)(r >> 16);
}
__device__ __forceinline__ float bf2f(unsigned short u) {
  union { unsigned u; float f; } v; v.u = (unsigned)u << 16; return v.f;
}

__device__ __forceinline__ void g2l16(const void* g, void* l) {
  __builtin_amdgcn_global_load_lds(
      (const __attribute__((address_space(1))) unsigned int*)g,
      (__attribute__((address_space(3))) unsigned int*)l, 16, 0, 0);
}

__device__ __forceinline__ float wsum(float v) {
#pragma unroll
  for (int o = 32; o > 0; o >>= 1) v += __shfl_xor(v, o, 64);
  return v;
}
__device__ __forceinline__ float wmax(float v) {
#pragma unroll
  for (int o = 32; o > 0; o >>= 1) v = fmaxf(v, __shfl_xor(v, o, 64));
  return v;
}

// m204 bijective XCD swizzle of flattened grid -> (tn, tm, bz)
__device__ __forceinline__ void xcd_map(int& tn, int& tm, long long& bz) {
  const int gx = gridDim.x, gy = gridDim.y, gz = gridDim.z;
  const int nwg = gx * gy * gz;
  const int lin = blockIdx.x + gx * (blockIdx.y + gy * blockIdx.z);
  const int q = nwg >> 3, r = nwg & 7;
  const int xcd = lin & 7, jj = lin >> 3;
  const int w = (xcd < r ? xcd * (q + 1) : r * (q + 1) + (xcd - r) * q) + jj;
  tn = w % gx;
  const int t2 = w / gx;
  tm = t2 % gy;
  bz = t2 / gy;
}

// ---- m97 128x128 NT GEMM body ----
template<int OMODE, bool BIAS>
__device__ __forceinline__ void gemm_body(
    const unsigned short* __restrict__ A, const unsigned short* __restrict__ B,
    const float* __restrict__ bias, void* __restrict__ Cg, size_t cb,
    int N, int K, int tm, int tn, float alpha,
    unsigned short* As, unsigned short* Bs)
{
  const int tid  = threadIdx.x;
  const int lane = tid & 63;
  const int wv   = tid >> 6;
  const int wr   = wv >> 1, wc = wv & 1;

  A += (size_t)tm * 128 * K;
  B += (size_t)tn * 128 * K;

  const int srow = wv * 16 + (lane >> 2);
  const int kby  = (lane & 3) * 16;

  f32x4 acc[4][4];
#pragma unroll
  for (int a = 0; a < 4; ++a)
#pragma unroll
    for (int b = 0; b < 4; ++b) acc[a][b] = (f32x4)(0.f);

  const int mrow = wr * 64 + (lane & 15);
  const int nrow = wc * 64 + (lane & 15);
  const int koff = (lane >> 4) * 8;

  for (int kt = 0; kt < K; kt += 32) {
#pragma unroll
    for (int i = 0; i < 2; ++i) {
      g2l16((const char*)(A + (size_t)(i * 64 + srow) * K + kt) + kby,
            (char*)As + i * 4096 + wv * 1024);
      g2l16((const char*)(B + (size_t)(i * 64 + srow) * K + kt) + kby,
            (char*)Bs + i * 4096 + wv * 1024);
    }
    __syncthreads();
    short8 af[4], bf[4];
#pragma unroll
    for (int a = 0; a < 4; ++a) af[a] = *(const short8*)&As[(mrow + a * 16) * 32 + koff];
#pragma unroll
    for (int b = 0; b < 4; ++b) bf[b] = *(const short8*)&Bs[(nrow + b * 16) * 32 + koff];
#pragma unroll
    for (int a = 0; a < 4; ++a)
#pragma unroll
      for (int b = 0; b < 4; ++b)
        acc[a][b] = __builtin_amdgcn_mfma_f32_16x16x32_bf16(af[a], bf[b], acc[a][b], 0, 0, 0);
    __syncthreads();
  }

#pragma unroll
  for (int a = 0; a < 4; ++a) {
    const int row0 = tm * 128 + wr * 64 + a * 16 + (lane >> 4) * 4;
#pragma unroll
    for (int b = 0; b < 4; ++b) {
      const int col = tn * 128 + wc * 64 + b * 16 + (lane & 15);
      float bv = 0.f;
      if (BIAS) bv = bias[col];
#pragma unroll
      for (int rr = 0; rr < 4; ++rr) {
        float v = acc[a][b][rr] * alpha + bv;
        if constexpr (OMODE == 0)
          ((float*)Cg)[cb + (size_t)(row0 + rr) * N + col] = v;
        else
          ((unsigned short*)Cg)[cb + (size_t)(row0 + rr) * N + col] = f2bf(v);
      }
    }
  }
}

template<int OMODE, bool BIAS>
__global__ __launch_bounds__(256) void gemm_nt(
    const unsigned short* __restrict__ Ag, const unsigned short* __restrict__ Bg,
    const float* __restrict__ bias, void* __restrict__ Cg,
    int M, int N, int K, long long sA, long long sB, long long sC,
    long long sBias, float alpha)
{
  __shared__ __align__(16) unsigned short As[128 * 32];
  __shared__ __align__(16) unsigned short Bs[128 * 32];
  int tn, tm; long long bz;
  xcd_map(tn, tm, bz);
  const float* bp = BIAS ? bias + bz * sBias : (const float*)nullptr;
  gemm_body<OMODE, BIAS>(Ag + bz * sA, Bg + bz * sB, bp, Cg,
                         (size_t)(bz * sC), N, K, tm, tn, alpha, As, Bs);
}

// ---- 256x256 8-wave per-phase-scheduled NT GEMM (narrow-N fold shapes) ----
template<int OMODE, bool BIAS>
__global__ __launch_bounds__(512, 2) void gemm_nt8(
    const unsigned short* __restrict__ Ag, const unsigned short* __restrict__ Bg,
    const float* __restrict__ bias, void* __restrict__ Cg,
    int M, int N, int K, long long sA, long long sB, long long sC,
    long long sBias, float alpha)
{
  __shared__ __align__(16) unsigned short As[2][2][8192];  // [buf][khalf][256x32]
  __shared__ __align__(16) unsigned short Bs[2][2][8192];

  const int tid  = threadIdx.x;
  const int lane = tid & 63;
  const int wv   = tid >> 6;      // 0..7
  const int wr   = wv >> 2;       // 0..1 (M half)
  const int wc   = wv & 3;        // 0..3 (N quarter)
  const int kb16 = (lane >> 4) * 16;

  int tn, tm; long long bz;
  xcd_map(tn, tm, bz);

  const unsigned short* A = Ag + bz * sA + (size_t)tm * 256 * K;
  const unsigned short* B = Bg + bz * sB + (size_t)tn * 256 * K;

  auto stageU = [&](const unsigned short* P, int ktile, int ks, char* ldsbase) {
#pragma unroll
    for (int c = 0; c < 2; ++c) {
      const int olin = c * 8192 + tid * 16;
      const int olog = olin ^ (((olin >> 7) & 3) << 4);
      const int row = olog >> 6, kbyte = olog & 63;
      g2l16((const char*)(P + (size_t)row * K) + ktile * 128 + ks * 64 + kbyte,
            ldsbase + c * 8192 + wv * 1024);
    }
  };

  f32x4 acc[8][4];
#pragma unroll
  for (int i = 0; i < 8; ++i)
#pragma unroll
    for (int j = 0; j < 4; ++j) acc[i][j] = (f32x4)(0.f);

  const int nt = K >> 6;

  stageU(A, 0, 0, (char*)&As[0][0][0]);
  stageU(B, 0, 0, (char*)&Bs[0][0][0]);
  stageU(A, 0, 1, (char*)&As[0][1][0]);
  stageU(B, 0, 1, (char*)&Bs[0][1][0]);
  stageU(A, 1, 0, (char*)&As[1][0][0]);
  stageU(B, 1, 0, (char*)&Bs[1][0][0]);
  asm volatile("s_waitcnt vmcnt(8)" ::: "memory");   // t0.k0 landed
  __builtin_amdgcn_s_barrier();
  __builtin_amdgcn_sched_barrier(0);

  short8 bf[4];
  for (int u = 0; u < nt; ++u) {
    const int bi = u & 1;
#pragma unroll
    for (int p = 0; p < 4; ++p) {
      const int ks = p >> 1, pr = p & 1;
      short8 af[4];
      {
        const char* base = (const char*)&As[bi][ks][0];
#pragma unroll
        for (int i = 0; i < 4; ++i) {
          int byt = (wr * 128 + (pr * 4 + i) * 16 + (lane & 15)) * 64 + kb16;
          byt ^= ((byt >> 7) & 3) << 4;
          af[i] = *(const short8*)(base + byt);
        }
      }
      if (pr == 0) {
        const char* base = (const char*)&Bs[bi][ks][0];
#pragma unroll
        for (int j = 0; j < 4; ++j) {
          int byt = (wc * 64 + j * 16 + (lane & 15)) * 64 + kb16;
          byt ^= ((byt >> 7) & 3) << 4;
          bf[j] = *(const short8*)(base + byt);
        }
      }
      if (p == 0 && u + 1 < nt) stageU(A, u + 1, 1, (char*)&As[(u + 1) & 1][1][0]);
      if (p == 1 && u + 1 < nt) stageU(B, u + 1, 1, (char*)&Bs[(u + 1) & 1][1][0]);
      if (p == 2 && u + 2 < nt) stageU(A, u + 2, 0, (char*)&As[bi][0][0]);
      if (p == 3 && u + 2 < nt) stageU(B, u + 2, 0, (char*)&Bs[bi][0][0]);

      __builtin_amdgcn_s_barrier();
      asm volatile("s_waitcnt lgkmcnt(0)" ::: "memory");
      __builtin_amdgcn_sched_barrier(0);
      __builtin_amdgcn_s_setprio(1);
#pragma unroll
      for (int i = 0; i < 4; ++i)
#pragma unroll
        for (int j = 0; j < 4; ++j)
          acc[pr * 4 + i][j] = __builtin_amdgcn_mfma_f32_16x16x32_bf16(
              af[i], bf[j], acc[pr * 4 + i][j], 0, 0, 0);
      __builtin_amdgcn_s_setprio(0);
      if (p == 1) {
        if (u < nt - 1) asm volatile("s_waitcnt vmcnt(8)" ::: "memory");
        else            asm volatile("s_waitcnt vmcnt(0)" ::: "memory");
      }
      if (p == 3) {
        if (u < nt - 2)       asm volatile("s_waitcnt vmcnt(8)" ::: "memory");
        else if (u == nt - 2) asm volatile("s_waitcnt vmcnt(4)" ::: "memory");
      }
      __builtin_amdgcn_s_barrier();
    }
  }

  const size_t cb = (size_t)(bz * sC);
#pragma unroll
  for (int i = 0; i < 8; ++i) {
    const int row0 = tm * 256 + wr * 128 + i * 16 + (lane >> 4) * 4;
#pragma unroll
    for (int j = 0; j < 4; ++j) {
      const int col = tn * 256 + wc * 64 + j * 16 + (lane & 15);
      float bv = 0.f;
      if (BIAS) bv = bias[bz * sBias + col];
#pragma unroll
      for (int rr = 0; rr < 4; ++rr) {
        float v = acc[i][j][rr] * alpha + bv;
        if constexpr (OMODE == 0)
          ((float*)Cg)[cb + (size_t)(row0 + rr) * N + col] = v;
        else
          ((unsigned short*)Cg)[cb + (size_t)(row0 + rr) * N + col] = f2bf(v);
      }
    }
  }
}

// 4 independent 768^3 NT GEMMs in one launch (fold products). bf16 out, no bias.
struct QuadPtrs {
  const unsigned short* a[4];
  const unsigned short* b[4];
  unsigned short* c[4];
};
__global__ __launch_bounds__(256) void gemm_nt_quad(QuadPtrs p) {
  __shared__ __align__(16) unsigned short As[128 * 32];
  __shared__ __align__(16) unsigned short Bs[128 * 32];
  const int zi = blockIdx.z;
  gemm_body<1, false>(p.a[zi], p.b[zi], nullptr, (void*)p.c[zi], 0,
                      768, 768, blockIdx.y, blockIdx.x, 1.0f, As, Bs);
}

template<int LR>
__global__ __launch_bounds__(256) void softmax_kernel(
    const float* __restrict__ sc, unsigned short* __restrict__ p)
{
  const int row  = blockIdx.x * 4 + (threadIdx.x >> 6);
  const int lane = threadIdx.x & 63;
  constexpr int PER = LR / 64;
  const float* sr = sc + (size_t)row * LR;
  float v[PER];
  float m = -1e30f;
#pragma unroll
  for (int j = 0; j < PER; ++j) { v[j] = sr[lane + 64 * j]; m = fmaxf(m, v[j]); }
  m = wmax(m);
  float s = 0.f;
#pragma unroll
  for (int j = 0; j < PER; ++j) { v[j] = __expf(v[j] - m); s += v[j]; }
  s = wsum(s);
  const float inv = 1.f / s;
  unsigned short* pr = p + (size_t)row * LR;
#pragma unroll
  for (int j = 0; j < PER; ++j) pr[lane + 64 * j] = f2bf(v[j] * inv);
}

// GRU combine with inline LN of old mem (h) + emit next operand.
template<bool GHB, bool EMITLN>
__global__ __launch_bounds__(256) void gru_ln_combine(
    const unsigned short* __restrict__ gi, const unsigned short* __restrict__ gh,
    float* __restrict__ mem, const float* __restrict__ g, const float* __restrict__ b,
    unsigned short* __restrict__ outb)
{
  __shared__ float ps[4], pq[4];
  const size_t row = blockIdx.x;
  const int tid = threadIdx.x, wv = tid >> 6, lane = tid & 63;
  float* mr = mem + row * 768;
  const size_t ghrow = GHB ? (row & 127) : row;
  float v[3];
  float s = 0.f, q = 0.f;
#pragma unroll
  for (int k = 0; k < 3; ++k) {
    v[k] = mr[tid + 256 * k];
    s += v[k]; q += v[k] * v[k];
  }
  s = wsum(s); q = wsum(q);
  if (lane == 0) { ps[wv] = s; pq[wv] = q; }
  __syncthreads();
  s = ps[0] + ps[1] + ps[2] + ps[3];
  q = pq[0] + pq[1] + pq[2] + pq[3];
  const float mu = s * (1.f / 768.f);
  const float rstd = rsqrtf(q * (1.f / 768.f) - mu * mu + 1e-5f);
  float nv[3];
  float s2 = 0.f, q2 = 0.f;
#pragma unroll
  for (int k = 0; k < 3; ++k) {
    const int c = tid + 256 * k;
    const float h = (v[k] - mu) * rstd * g[c] + b[c];
    const float ir  = bf2f(gi[row * 2304 + c]);
    const float iz  = bf2f(gi[row * 2304 + 768 + c]);
    const float in_ = bf2f(gi[row * 2304 + 1536 + c]);
    const float hr  = bf2f(gh[ghrow * 2304 + c]);
    const float hz  = bf2f(gh[ghrow * 2304 + 768 + c]);
    const float hn  = bf2f(gh[ghrow * 2304 + 1536 + c]);
    const float rg = 1.f / (1.f + __expf(-(ir + hr)));
    const float zg = 1.f / (1.f + __expf(-(iz + hz)));
    const float n  = tanhf(in_ + rg * hn);
    nv[k] = (1.f - zg) * n + zg * h;
    mr[c] = nv[k];
    s2 += nv[k]; q2 += nv[k] * nv[k];
  }
  if (EMITLN) {
    s2 = wsum(s2); q2 = wsum(q2);
    __syncthreads();
    if (lane == 0) { ps[wv] = s2; pq[wv] = q2; }
    __syncthreads();
    s2 = ps[0] + ps[1] + ps[2] + ps[3];
    q2 = pq[0] + pq[1] + pq[2] + pq[3];
    const float mu2 = s2 * (1.f / 768.f);
    const float rstd2 = rsqrtf(q2 * (1.f / 768.f) - mu2 * mu2 + 1e-5f);
#pragma unroll
    for (int k = 0; k < 3; ++k) {
      const int c = tid + 256 * k;
      outb[row * 768 + c] = f2bf((nv[k] - mu2) * rstd2 * g[c] + b[c]);
    }
  } else {
#pragma unroll
    for (int k = 0; k < 3; ++k) {
      const int c = tid + 256 * k;
      outb[row * 768 + c] = f2bf(nv[k]);
    }
  }
}

__global__ __launch_bounds__(256) void cvt_bf16(
    const float* __restrict__ in, unsigned short* __restrict__ out, int n4)
{
  const int i = blockIdx.x * 256 + threadIdx.x;
  if (i >= n4) return;
  const float4 v = ((const float4*)in)[i];
  us4 o;
  o.x = f2bf(v.x); o.y = f2bf(v.y); o.z = f2bf(v.z); o.w = f2bf(v.w);
  ((us4*)out)[i] = o;
}

// Merged weight conversion: 10 fp32 sources -> contiguous bf16 region.
__global__ __launch_bounds__(256) void cvt_weights(
    const float* p0, const float* p1, const float* p2, const float* p3,
    const float* p4, const float* p5, const float* p6, const float* p7,
    const float* p8, const float* p9, unsigned short* __restrict__ dst)
{
  const int i = blockIdx.x * 256 + threadIdx.x;  // f4 index, total 2064384
  if (i >= 2064384) return;
  const float* src; int base;
  if      (i < 147456)  { src = p0; base = 0; }
  else if (i < 294912)  { src = p1; base = 147456; }
  else if (i < 442368)  { src = p2; base = 294912; }
  else if (i < 589824)  { src = p3; base = 442368; }
  else if (i < 737280)  { src = p4; base = 589824; }
  else if (i < 884736)  { src = p5; base = 737280; }
  else if (i < 1032192) { src = p6; base = 884736; }
  else if (i < 1179648) { src = p7; base = 1032192; }
  else if (i < 1622016) { src = p8; base = 1179648; }
  else                  { src = p9; base = 1622016; }
  const float4 v = ((const float4*)src)[i - base];
  us4 o;
  o.x = f2bf(v.x); o.y = f2bf(v.y); o.z = f2bf(v.z); o.w = f2bf(v.w);
  ((us4*)dst)[i] = o;
}

// memf[b,s,:] = slots[s,:]; memb[b,s,:] = bf16(LN(slots[s,:])). One block per slot.
__global__ __launch_bounds__(256) void init_mem(
    const float* __restrict__ slots, const float* __restrict__ g,
    const float* __restrict__ b, float* __restrict__ memf,
    unsigned short* __restrict__ memb)
{
  __shared__ float ps[4], pq[4];
  const int s = blockIdx.x;            // 0..127
  const int tid = threadIdx.x, wv = tid >> 6, lane = tid & 63;
  const float* sr = slots + (size_t)s * 768;
  float v[3];
  float su = 0.f, qu = 0.f;
#pragma unroll
  for (int k = 0; k < 3; ++k) { v[k] = sr[tid + 256 * k]; su += v[k]; qu += v[k] * v[k]; }
  su = wsum(su); qu = wsum(qu);
  if (lane == 0) { ps[wv] = su; pq[wv] = qu; }
  __syncthreads();
  su = ps[0] + ps[1] + ps[2] + ps[3];
  qu = pq[0] + pq[1] + pq[2] + pq[3];
  const float mu = su * (1.f / 768.f);
  const float rstd = rsqrtf(qu * (1.f / 768.f) - mu * mu + 1e-5f);
  unsigned short lb[3];
#pragma unroll
  for (int k = 0; k < 3; ++k) {
    const int c = tid + 256 * k;
    lb[k] = f2bf((v[k] - mu) * rstd * g[c] + b[c]);
  }
  for (int bb = 0; bb < 64; ++bb) {
    float* mrow = memf + ((size_t)bb * 128 + s) * 768;
    unsigned short* brow = memb + ((size_t)bb * 128 + s) * 768;
#pragma unroll
    for (int k = 0; k < 3; ++k) { mrow[tid + 256 * k] = v[k]; brow[tid + 256 * k] = lb[k]; }
  }
}

// Batched bf16 transpose: in [R,C] -> out [C,R], batch stride R*C.
__global__ void transpose_bf16(const unsigned short* __restrict__ in,
                               unsigned short* __restrict__ out, int R, int C)
{
  __shared__ unsigned short t[32][33];
  const size_t bofs = (size_t)blockIdx.z * R * C;
  const int c0 = blockIdx.x * 32, r0 = blockIdx.y * 32;
  const int x = threadIdx.x, y = threadIdx.y;
#pragma unroll
  for (int k = 0; k < 32; k += 8)
    t[y + k][x] = in[bofs + (size_t)(r0 + y + k) * C + c0 + x];
  __syncthreads();
#pragma unroll
  for (int k = 0; k < 32; k += 8)
    out[bofs + (size_t)(c0 + y + k) * R + r0 + x] = t[x][y + k];
}

// 6 independent 768x768 transposes in one launch.
struct TPtrs { const unsigned short* s[6]; unsigned short* d[6]; };
__global__ void transpose_multi(TPtrs p) {
  __shared__ unsigned short t[32][33];
  const unsigned short* in = p.s[blockIdx.z];
  unsigned short* out = p.d[blockIdx.z];
  const int c0 = blockIdx.x * 32, r0 = blockIdx.y * 32;
  const int x = threadIdx.x, y = threadIdx.y;
#pragma unroll
  for (int k = 0; k < 32; k += 8)
    t[y + k][x] = in[(size_t)(r0 + y + k) * 768 + c0 + x];
  __syncthreads();
#pragma unroll
  for (int k = 0; k < 32; k += 8)
    out[(size_t)(c0 + y + k) * 768 + r0 + x] = t[x][y + k];
}

// Two y = W^T x jobs in one launch (grid 6: task = bx/3).
__global__ __launch_bounds__(256) void matvec_T2(
    const float* __restrict__ W0, const float* __restrict__ x0, float* __restrict__ y0,
    const float* __restrict__ W1, const float* __restrict__ x1, float* __restrict__ y1)
{
  const int task = blockIdx.x / 3;
  const int j = (blockIdx.x % 3) * 256 + threadIdx.x;
  const float* W = task ? W1 : W0;
  const float* x = task ? x1 : x0;
  float* y = task ? y1 : y0;
  float s = 0.f;
  for (int k = 0; k < 768; ++k) s += W[(size_t)k * 768 + j] * x[k];
  y[j] = s;
}

// Two y[row]=add[row]+dot(W[row,:],x) jobs (grid 384: task = bx/192).
__global__ __launch_bounds__(256) void matvec_row2(
    const float* __restrict__ W0, const float* __restrict__ x0,
    const float* __restrict__ a0, float* __restrict__ y0,
    const float* __restrict__ W1, const float* __restrict__ x1,
    const float* __restrict__ a1, float* __restrict__ y1)
{
  const int task = blockIdx.x / 192;
  const int row = (blockIdx.x % 192) * 4 + (threadIdx.x >> 6);
  const int lane = threadIdx.x & 63;
  const float* W = task ? W1 : W0;
  const float* x = task ? x1 : x0;
  const float* ad = task ? a1 : a0;
  float* y = task ? y1 : y0;
  const float* r = W + (size_t)row * 768;
  float s = 0.f;
#pragma unroll
  for (int j = 0; j < 12; ++j) s += r[lane + 64 * j] * x[lane + 64 * j];
  s = wsum(s);
  if (lane == 0) y[row] = s + ad[row];
}

// out[i] = scl * (dot(src_i, vec) + (cadd ? cadd[0] : 0))
__global__ __launch_bounds__(256) void rowdot768(
    const float* __restrict__ src, const float* __restrict__ vec,
    const float* __restrict__ cadd, float* __restrict__ out, float scl, int rows)
{
  const int row  = blockIdx.x * 4 + (threadIdx.x >> 6);
  if (row >= rows) return;
  const int lane = threadIdx.x & 63;
  const float* r = src + (size_t)row * 768;
  float s = 0.f;
#pragma unroll
  for (int j = 0; j < 12; ++j) s += r[lane + 64 * j] * vec[lane + 64 * j];
  s = wsum(s);
  if (lane == 0) out[row] = scl * (s + (cadd ? cadd[0] : 0.f));
}

// Fused: zb = bf16(z) AND zv[row] = scl*(dot(z_row, vw) + cw[0]). Wave per row.
__global__ __launch_bounds__(256) void cvt_z_zv(
    const float* __restrict__ z, unsigned short* __restrict__ zb,
    const float* __restrict__ vw, const float* __restrict__ cw,
    float* __restrict__ zv, float scl)
{
  const int row = blockIdx.x * 4 + (threadIdx.x >> 6);
  const int lane = threadIdx.x & 63;
  const float* zr = z + (size_t)row * 768;
  unsigned short* zbr = zb + (size_t)row * 768;
  float s = 0.f;
#pragma unroll
  for (int j = 0; j < 12; ++j) {
    const float v = zr[lane + 64 * j];
    s += v * vw[lane + 64 * j];
    zbr[lane + 64 * j] = f2bf(v);
  }
  s = wsum(s);
  if (lane == 0) zv[row] = scl * (s + cw[0]);
}

__global__ __launch_bounds__(256) void diag_ws(float* __restrict__ out, float wsz, int n) {
  const int i = blockIdx.x * 256 + threadIdx.x;
  if (i < n) out[i] = (i == 0) ? wsz : 0.f;
}

extern "C" void kernel_launch(void* const* d_in, const int* in_sizes, int n_in,
                              void* d_out, int out_size, void* d_ws, size_t ws_size,
                              hipStream_t stream)
{
  const float* z     = (const float*)d_in[0];
  const float* slots = (const float*)d_in[1];
  const float* ln_g  = (const float*)d_in[2];
  const float* ln_b  = (const float*)d_in[3];
  const float* w_wq = (const float*)d_in[4];  const float* w_bq = (const float*)d_in[5];
  const float* w_wk = (const float*)d_in[6];  const float* w_bk = (const float*)d_in[7];
  const float* w_wv = (const float*)d_in[8];  const float* w_bv = (const float*)d_in[9];
  const float* w_wo = (const float*)d_in[10]; const float* w_bo = (const float*)d_in[11];
  const float* r_wq = (const float*)d_in[12]; const float* r_bq = (const float*)d_in[13];
  const float* r_wk = (const float*)d_in[14]; const float* r_bk = (const float*)d_in[15];
  const float* r_wv = (const float*)d_in[16]; const float* r_bv = (const float*)d_in[17];
  const float* r_wo = (const float*)d_in[18]; const float* r_bo = (const float*)d_in[19];
  const float* g_wih = (const float*)d_in[20]; const float* g_bih = (const float*)d_in[21];
  const float* g_whh = (const float*)d_in[22]; const float* g_bhh = (const float*)d_in[23];

  // ---- arena (bytes) ----
  constexpr size_t O_F    = 16515072;    // Fqk,Fwv,Fvo,Frq
  constexpr size_t O_T6   = 21233664;    // 6 transposed weights
  constexpr size_t O_GH0  = 28311552;    // 589824
  constexpr size_t O_FL   = 28901376;    // float vectors
  constexpr size_t O_memf = 29096192;    // 25165824
  constexpr size_t O_Kz   = 54262016;    // 50331648: tmpV -> Kz | end: memFr
  constexpr size_t O_VwoT = 104593664;   // 50331648: VwoT | end: memVo/memVoT/Sbr/Abr
  constexpr size_t O_L    = 154925312;   // 62914560 scratch
  constexpr size_t NEED   = 217839872;

  if (ws_size < NEED) {
    hipLaunchKernelGGL(diag_ws, dim3((out_size + 255) / 256), dim3(256), 0, stream,
                       (float*)d_out, (float)ws_size, out_size);
    return;
  }

  char* ws = (char*)d_ws;
  unsigned short* wqb  = (unsigned short*)(ws + 0);
  unsigned short* wkb  = wqb + 589824;
  unsigned short* wvb  = wkb + 589824;
  unsigned short* wob  = wvb + 589824;
  unsigned short* rqb  = wob + 589824;
  unsigned short* rkb  = rqb + 589824;
  unsigned short* rvb  = rkb + 589824;
  unsigned short* rob  = rvb + 589824;
  unsigned short* wihb = rob + 589824;
  unsigned short* whhb = wihb + 1769472;
  unsigned short* Fqk  = (unsigned short*)(ws + O_F);
  unsigned short* Fwv  = Fqk + 589824;
  unsigned short* Fvo  = Fwv + 589824;
  unsigned short* Frq  = Fvo + 589824;
  unsigned short* T0   = (unsigned short*)(ws + O_T6);
  unsigned short* T1   = T0 + 589824;
  unsigned short* T2   = T1 + 589824;
  unsigned short* T3   = T2 + 589824;
  unsigned short* T4   = T3 + 589824;
  unsigned short* T5   = T4 + 589824;
  unsigned short* gh0  = (unsigned short*)(ws + O_GH0);
  float* bih_c   = (float*)(ws + O_FL);     // 2304 (+2304 bhh adjacent)
  float* bhh_c   = bih_c + 2304;
  float* const_o = bhh_c + 2304;
  float* bvo     = const_o + 768;
  float* vw      = bvo + 768;
  float* vr      = vw + 768;
  float* cw      = vr + 768;
  float* zv      = cw + 64;                 // 32768
  float* colb    = zv + 32768;              // 8192
  float* memf = (float*)(ws + O_memf);
  unsigned short* tmpV  = (unsigned short*)(ws + O_Kz);
  unsigned short* Kz    = (unsigned short*)(ws + O_Kz);
  unsigned short* memFr = (unsigned short*)(ws + O_Kz);            // end
  unsigned short* VwoT  = (unsigned short*)(ws + O_VwoT);
  unsigned short* memVo   = (unsigned short*)(ws + O_VwoT);             // end
  unsigned short* memVoT  = (unsigned short*)(ws + O_VwoT + 12582912);  // end
  float*          Sbr     = (float*)(ws + O_VwoT + 25165824);           // end
  unsigned short* Abr     = (unsigned short*)(ws + O_VwoT + 41943040);  // end
  char* L = ws + O_L;
  unsigned short* zb    = (unsigned short*)(L + 0);          // prologue 48MiB
  unsigned short* memb  = (unsigned short*)(L + 0);          // loop (aliases zb!)
  unsigned short* updb  = (unsigned short*)(L + 12582912);
  float*          Sbuf  = (float*)(L + 25165824);            // 16MiB
  unsigned short* Abuf  = (unsigned short*)(L + 41943040);   // 8MiB
  unsigned short* gib   = (unsigned short*)(L + 25165824);   // 37.7MiB (S/A dead)
  unsigned short* ghb   = (unsigned short*)d_out;            // 37.7MiB in d_out scratch
  unsigned short* zb2   = (unsigned short*)(L + 12582912);   // end 48MiB

  const float scale = 1.0f / sqrtf(768.f);

  // ---- prologue ----
  hipLaunchKernelGGL(cvt_weights, dim3(8064), dim3(256), 0, stream,
      w_wq, w_wk, w_wv, w_wo, r_wq, r_wk, r_wv, r_wo, g_wih, g_whh, wqb);
  hipMemcpyAsync(bih_c, g_bih, 2304 * 4, hipMemcpyDeviceToDevice, stream);
  hipMemcpyAsync(bhh_c, g_bhh, 2304 * 4, hipMemcpyDeviceToDevice, stream);

  {
    TPtrs tp;
    tp.s[0] = wqb; tp.d[0] = T0;
    tp.s[1] = wkb; tp.d[1] = T1;
    tp.s[2] = wvb; tp.d[2] = T2;
    tp.s[3] = rvb; tp.d[3] = T3;
    tp.s[4] = rqb; tp.d[4] = T4;
    tp.s[5] = rkb; tp.d[5] = T5;
    hipLaunchKernelGGL(transpose_multi, dim3(24, 24, 6), dim3(32, 8), 0, stream, tp);
  }
  {
    QuadPtrs qp;
    qp.a[0] = T0;  qp.b[0] = T1; qp.c[0] = Fqk;  // Wq^T Wk
    qp.a[1] = wob; qp.b[1] = T2; qp.c[1] = Fwv;  // Wo Wv
    qp.a[2] = rob; qp.b[2] = T3; qp.c[2] = Fvo;  // Ro Rv
    qp.a[3] = T4;  qp.b[3] = T5; qp.c[3] = Frq;  // Rq^T Rk
    hipLaunchKernelGGL(gemm_nt_quad, dim3(6, 6, 4), dim3(256), 0, stream, qp);
  }

  hipLaunchKernelGGL(matvec_T2, dim3(6), dim3(256), 0, stream,
      w_wk, w_bq, vw, r_wk, r_bq, vr);
  hipLaunchKernelGGL(matvec_row2, dim3(384), dim3(256), 0, stream,
      w_wo, w_bv, w_bo, const_o, r_wo, r_bv, r_bo, bvo);
  hipLaunchKernelGGL(rowdot768, dim3(1), dim3(256), 0, stream,
      w_bq, w_bk, (const float*)nullptr, cw, 1.0f, 1);
  hipLaunchKernelGGL(cvt_z_zv, dim3(8192), dim3(256), 0, stream, z, zb, vw, cw, zv, scale);

  // Vwo = z.Fwv^T -> tmpV -> transpose -> VwoT; then Kz = z.Fqk^T.  (nt8, narrow-N)
  hipLaunchKernelGGL((gemm_nt8<1, false>), dim3(3, 128, 1), dim3(512), 0, stream,
      zb, Fwv, (const float*)nullptr, (void*)tmpV, 32768, 768, 768, 0ll, 0ll, 0ll, 0ll, 1.0f);
  hipLaunchKernelGGL(transpose_bf16, dim3(24, 16, 64), dim3(32, 8), 0, stream,
      tmpV, VwoT, 512, 768);
  hipLaunchKernelGGL((gemm_nt8<1, false>), dim3(3, 128, 1), dim3(512), 0, stream,
      zb, Fqk, (const float*)nullptr, (void*)Kz, 32768, 768, 768, 0ll, 0ll, 0ll, 0ll, 1.0f);

  // init AFTER last zb reader (memb aliases zb)
  hipLaunchKernelGGL(init_mem, dim3(128), dim3(256), 0, stream,
      slots, ln_g, ln_b, memf, memb);

  const long long sA_g = (long long)(memb - updb);  // z=1 -> memb
  const long long sC_g = (long long)(ghb - gib);    // z=1 -> gh in d_out scratch

  // ---- T=3 recurrence ----
  for (int t = 0; t < 3; ++t) {
    hipLaunchKernelGGL((gemm_nt<0, true>), dim3(4, 1, 64), dim3(256), 0, stream,
        memb, Kz, zv, (void*)Sbuf, 128, 512, 768,
        98304ll, 393216ll, 65536ll, 512ll, scale);
    hipLaunchKernelGGL((softmax_kernel<512>), dim3(2048), dim3(256), 0, stream, Sbuf, Abuf);
    hipLaunchKernelGGL((gemm_nt<1, true>), dim3(6, 1, 64), dim3(256), 0, stream,
        Abuf, VwoT, const_o, (void*)updb, 128, 768, 512,
        65536ll, 393216ll, 98304ll, 0ll, 1.0f);
    if (t == 0) {
      hipLaunchKernelGGL((gemm_nt<1, true>), dim3(18, 1, 1), dim3(256), 0, stream,
          memb, whhb, bhh_c, (void*)gh0, 128, 2304, 768, 0ll, 0ll, 0ll, 0ll, 1.0f);
      hipLaunchKernelGGL((gemm_nt<1, true>), dim3(18, 64, 1), dim3(256), 0, stream,
          updb, wihb, bih_c, (void*)gib, 8192, 2304, 768, 0ll, 0ll, 0ll, 0ll, 1.0f);
      hipLaunchKernelGGL((gru_ln_combine<true, true>), dim3(8192), dim3(256), 0, stream,
          gib, gh0, memf, ln_g, ln_b, memb);
    } else {
      hipLaunchKernelGGL((gemm_nt<1, true>), dim3(18, 64, 2), dim3(256), 0, stream,
          updb, wihb, bih_c, (void*)gib, 8192, 2304, 768,
          sA_g, 1769472ll, sC_g, 2304ll, 1.0f);
      if (t < 2)
        hipLaunchKernelGGL((gru_ln_combine<false, true>), dim3(8192), dim3(256), 0, stream,
            gib, ghb, memf, ln_g, ln_b, memb);
      else
        hipLaunchKernelGGL((gru_ln_combine<false, false>), dim3(8192), dim3(256), 0, stream,
            gib, ghb, memf, ln_g, ln_b, memb);
    }
  }
  // memb now holds bf16(mem_final)

  // ---- read attention ----
  hipLaunchKernelGGL((gemm_nt8<1, false>), dim3(3, 32, 2), dim3(512), 0, stream,
      memb, Frq, (const float*)nullptr, (void*)memFr, 8192, 768, 768,
      0ll, (long long)(Fvo - Frq), 25165824ll, 0ll, 1.0f);
  hipLaunchKernelGGL(transpose_bf16, dim3(24, 4, 64), dim3(32, 8), 0, stream,
      memVo, memVoT, 128, 768);
  hipLaunchKernelGGL(rowdot768, dim3(2048), dim3(256), 0, stream,
      memf, vr, (const float*)nullptr, colb, scale, 8192);
  {
    const int n4 = 6291456;
    hipLaunchKernelGGL(cvt_bf16, dim3(24576), dim3(256), 0, stream, z, zb2, n4);
  }
  hipLaunchKernelGGL((gemm_nt<0, true>), dim3(1, 4, 64), dim3(256), 0, stream,
      zb2, memFr, colb, (void*)Sbr, 512, 128, 768,
      393216ll, 98304ll, 65536ll, 128ll, scale);
  hipLaunchKernelGGL((softmax_kernel<128>), dim3(8192), dim3(256), 0, stream, Sbr, Abr);
  hipLaunchKernelGGL((gemm_nt8<0, true>), dim3(3, 2, 64), dim3(512), 0, stream,
      Abr, memVoT, bvo, d_out, 512, 768, 128,
      65536ll, 98304ll, 393216ll, 0ll, 1.0f);
}

// Round 11
// 750.956 us; speedup vs baseline: 1.5940x; 1.1420x over previous
//
#include <hip/hip_runtime.h>
#include <hip/hip_bf16.h>
#include <math.h>

// Memory module: E=768, S=128, T=3, B=64, L=512. fp32 in/out.
// bf16 MFMA GEMMs (fp32 accum). Folds: Fqk=Wq^T Wk, Fwv=Wo Wv, Fvo=Ro Rv, Frq=Rq^T Rk.
// Transposed operands produced directly as NT GEMMs (VwoT=Fwv.z^T, memVoT=Fvo.memb^T).
// gemm_nt64: m97 structure with BK=64 (half the barriers/K) + both-sides XOR swizzle.
// d_out doubles as scratch: ghb at +0 (37.7MB), zb at +48MB (48MB); final GEMM
// overwrites all of d_out last; zb consumed by read-scores before that.

typedef __attribute__((ext_vector_type(4))) float f32x4;
typedef __attribute__((ext_vector_type(8))) short short8;
typedef __attribute__((ext_vector_type(4))) unsigned short us4;

__device__ __forceinline__ unsigned short f2bf(float x) {
  union { float f; unsigned u; } v; v.f = x;
  unsigned r = v.u + 0x7fffu + ((v.u >> 16) & 1u);  // RNE
  return (unsigned short)(r >> 16);
}
__device__ __forceinline__ float bf2f(unsigned short u) {
  union { unsigned u; float f; } v; v.u = (unsigned)u << 16; return v.f;
}

__device__ __forceinline__ void g2l16(const void* g, void* l) {
  __builtin_amdgcn_global_load_lds(
      (const __attribute__((address_space(1))) unsigned int*)g,
      (__attribute__((address_space(3))) unsigned int*)l, 16, 0, 0);
}

__device__ __forceinline__ float wsum(float v) {
#pragma unroll
  for (int o = 32; o > 0; o >>= 1) v += __shfl_xor(v, o, 64);
  return v;
}
__device__ __forceinline__ float wmax(float v) {
#pragma unroll
  for (int o = 32; o > 0; o >>= 1) v = fmaxf(v, __shfl_xor(v, o, 64));
  return v;
}

// m204 bijective XCD swizzle of flattened grid -> (tn, tm, bz)
__device__ __forceinline__ void xcd_map(int& tn, int& tm, long long& bz) {
  const int gx = gridDim.x, gy = gridDim.y, gz = gridDim.z;
  const int nwg = gx * gy * gz;
  const int lin = blockIdx.x + gx * (blockIdx.y + gy * blockIdx.z);
  const int q = nwg >> 3, r = nwg & 7;
  const int xcd = lin & 7, jj = lin >> 3;
  const int w = (xcd < r ? xcd * (q + 1) : r * (q + 1) + (xcd - r) * q) + jj;
  tn = w % gx;
  const int t2 = w / gx;
  tm = t2 % gy;
  bz = t2 / gy;
}

__device__ __forceinline__ void c_write_128(
    void* Cg, size_t cb, int N, int tm, int tn, int wr, int wc, int lane,
    const f32x4 acc[4][4], const float* bias, bool has_bias, float alpha, int omode)
{
#pragma unroll
  for (int a = 0; a < 4; ++a) {
    const int row0 = tm * 128 + wr * 64 + a * 16 + (lane >> 4) * 4;
#pragma unroll
    for (int b = 0; b < 4; ++b) {
      const int col = tn * 128 + wc * 64 + b * 16 + (lane & 15);
      float bv = has_bias ? bias[col] : 0.f;
#pragma unroll
      for (int rr = 0; rr < 4; ++rr) {
        float v = acc[a][b][rr] * alpha + bv;
        if (omode == 0)
          ((float*)Cg)[cb + (size_t)(row0 + rr) * N + col] = v;
        else
          ((unsigned short*)Cg)[cb + (size_t)(row0 + rr) * N + col] = f2bf(v);
      }
    }
  }
}

// ---- m97 128x128 NT GEMM body (BK=32) ----
template<int OMODE, bool BIAS>
__device__ __forceinline__ void gemm_body(
    const unsigned short* __restrict__ A, const unsigned short* __restrict__ B,
    const float* __restrict__ bias, void* __restrict__ Cg, size_t cb,
    int N, int K, int tm, int tn, float alpha,
    unsigned short* As, unsigned short* Bs)
{
  const int tid  = threadIdx.x;
  const int lane = tid & 63;
  const int wv   = tid >> 6;
  const int wr   = wv >> 1, wc = wv & 1;

  A += (size_t)tm * 128 * K;
  B += (size_t)tn * 128 * K;

  const int srow = wv * 16 + (lane >> 2);
  const int kby  = (lane & 3) * 16;

  f32x4 acc[4][4];
#pragma unroll
  for (int a = 0; a < 4; ++a)
#pragma unroll
    for (int b = 0; b < 4; ++b) acc[a][b] = (f32x4)(0.f);

  const int mrow = wr * 64 + (lane & 15);
  const int nrow = wc * 64 + (lane & 15);
  const int koff = (lane >> 4) * 8;

  for (int kt = 0; kt < K; kt += 32) {
#pragma unroll
    for (int i = 0; i < 2; ++i) {
      g2l16((const char*)(A + (size_t)(i * 64 + srow) * K + kt) + kby,
            (char*)As + i * 4096 + wv * 1024);
      g2l16((const char*)(B + (size_t)(i * 64 + srow) * K + kt) + kby,
            (char*)Bs + i * 4096 + wv * 1024);
    }
    __syncthreads();
    short8 af[4], bf[4];
#pragma unroll
    for (int a = 0; a < 4; ++a) af[a] = *(const short8*)&As[(mrow + a * 16) * 32 + koff];
#pragma unroll
    for (int b = 0; b < 4; ++b) bf[b] = *(const short8*)&Bs[(nrow + b * 16) * 32 + koff];
#pragma unroll
    for (int a = 0; a < 4; ++a)
#pragma unroll
      for (int b = 0; b < 4; ++b)
        acc[a][b] = __builtin_amdgcn_mfma_f32_16x16x32_bf16(af[a], bf[b], acc[a][b], 0, 0, 0);
    __syncthreads();
  }
  c_write_128(Cg, cb, N, tm, tn, wr, wc, lane, acc, bias, BIAS, alpha, OMODE);
}

template<int OMODE, bool BIAS>
__global__ __launch_bounds__(256) void gemm_nt(
    const unsigned short* __restrict__ Ag, const unsigned short* __restrict__ Bg,
    const float* __restrict__ bias, void* __restrict__ Cg,
    int M, int N, int K, long long sA, long long sB, long long sC,
    long long sBias, float alpha)
{
  __shared__ __align__(16) unsigned short As[128 * 32];
  __shared__ __align__(16) unsigned short Bs[128 * 32];
  int tn, tm; long long bz;
  xcd_map(tn, tm, bz);
  const float* bp = BIAS ? bias + bz * sBias : (const float*)nullptr;
  gemm_body<OMODE, BIAS>(Ag + bz * sA, Bg + bz * sB, bp, Cg,
                         (size_t)(bz * sC), N, K, tm, tn, alpha, As, Bs);
}

// ---- BK=64 variant: half the barrier pairs per K; 32KB LDS; XOR-swizzled.
// Swizzle involution s(o) = o ^ (((o>>7)&7)<<4) on both stage-source and read.
// Requires K%64==0, M%128==0, N%128==0.
template<int OMODE, bool BIAS>
__global__ __launch_bounds__(256) void gemm_nt64(
    const unsigned short* __restrict__ Ag, const unsigned short* __restrict__ Bg,
    const float* __restrict__ bias, void* __restrict__ Cg,
    int M, int N, int K, long long sA, long long sB, long long sC,
    long long sBias, float alpha)
{
  __shared__ __align__(16) unsigned short As[128 * 64];  // 16KB
  __shared__ __align__(16) unsigned short Bs[128 * 64];

  const int tid  = threadIdx.x;
  const int lane = tid & 63;
  const int wv   = tid >> 6;
  const int wr   = wv >> 1, wc = wv & 1;

  int tn, tm; long long bz;
  xcd_map(tn, tm, bz);

  const unsigned short* A = Ag + bz * sA + (size_t)tm * 128 * K;
  const unsigned short* B = Bg + bz * sB + (size_t)tn * 128 * K;

  auto swz = [](int o) { return o ^ (((o >> 7) & 7) << 4); };
  // per-lane pre-swizzled source coords for staging (4 units of 4KB)
  int srow[4], scb[4];
#pragma unroll
  for (int c = 0; c < 4; ++c) {
    const int olog = swz(c * 4096 + tid * 16);
    srow[c] = olog >> 7;
    scb[c]  = olog & 127;
  }

  f32x4 acc[4][4];
#pragma unroll
  for (int a = 0; a < 4; ++a)
#pragma unroll
    for (int b = 0; b < 4; ++b) acc[a][b] = (f32x4)(0.f);

  const int mrow = wr * 64 + (lane & 15);
  const int nrow = wc * 64 + (lane & 15);
  const int kb   = (lane >> 4) * 16;   // byte offset

  for (int kt = 0; kt < K; kt += 64) {
#pragma unroll
    for (int c = 0; c < 4; ++c) {
      g2l16((const char*)(A + (size_t)srow[c] * K + kt) + scb[c],
            (char*)As + c * 4096 + wv * 1024);
      g2l16((const char*)(B + (size_t)srow[c] * K + kt) + scb[c],
            (char*)Bs + c * 4096 + wv * 1024);
    }
    __syncthreads();
#pragma unroll
    for (int h = 0; h < 2; ++h) {
      short8 af[4], bf[4];
#pragma unroll
      for (int a = 0; a < 4; ++a)
        af[a] = *(const short8*)((char*)As + swz((mrow + a * 16) * 128 + h * 64 + kb));
#pragma unroll
      for (int b = 0; b < 4; ++b)
        bf[b] = *(const short8*)((char*)Bs + swz((nrow + b * 16) * 128 + h * 64 + kb));
#pragma unroll
      for (int a = 0; a < 4; ++a)
#pragma unroll
        for (int b = 0; b < 4; ++b)
          acc[a][b] = __builtin_amdgcn_mfma_f32_16x16x32_bf16(af[a], bf[b], acc[a][b], 0, 0, 0);
    }
    __syncthreads();
  }

  const float* bp = BIAS ? bias + bz * sBias : (const float*)nullptr;
  c_write_128(Cg, (size_t)(bz * sC), N, tm, tn, wr, wc, lane, acc, bp, BIAS, alpha, OMODE);
}

// 4 independent 768^3 NT GEMMs in one launch (fold products). bf16 out, no bias.
struct QuadPtrs {
  const unsigned short* a[4];
  const unsigned short* b[4];
  unsigned short* c[4];
};
__global__ __launch_bounds__(256) void gemm_nt_quad(QuadPtrs p) {
  __shared__ __align__(16) unsigned short As[128 * 32];
  __shared__ __align__(16) unsigned short Bs[128 * 32];
  const int zi = blockIdx.z;
  gemm_body<1, false>(p.a[zi], p.b[zi], nullptr, (void*)p.c[zi], 0,
                      768, 768, blockIdx.y, blockIdx.x, 1.0f, As, Bs);
}

template<int LR>
__global__ __launch_bounds__(256) void softmax_kernel(
    const float* __restrict__ sc, unsigned short* __restrict__ p)
{
  const int row  = blockIdx.x * 4 + (threadIdx.x >> 6);
  const int lane = threadIdx.x & 63;
  constexpr int PER = LR / 64;
  const float* sr = sc + (size_t)row * LR;
  float v[PER];
  float m = -1e30f;
#pragma unroll
  for (int j = 0; j < PER; ++j) { v[j] = sr[lane + 64 * j]; m = fmaxf(m, v[j]); }
  m = wmax(m);
  float s = 0.f;
#pragma unroll
  for (int j = 0; j < PER; ++j) { v[j] = __expf(v[j] - m); s += v[j]; }
  s = wsum(s);
  const float inv = 1.f / s;
  unsigned short* pr = p + (size_t)row * LR;
#pragma unroll
  for (int j = 0; j < PER; ++j) pr[lane + 64 * j] = f2bf(v[j] * inv);
}

// GRU combine with inline LN of old mem (h) + emit next operand.
template<bool GHB, bool EMITLN>
__global__ __launch_bounds__(256) void gru_ln_combine(
    const unsigned short* __restrict__ gi, const unsigned short* __restrict__ gh,
    float* __restrict__ mem, const float* __restrict__ g, const float* __restrict__ b,
    unsigned short* __restrict__ outb)
{
  __shared__ float ps[4], pq[4];
  const size_t row = blockIdx.x;
  const int tid = threadIdx.x, wv = tid >> 6, lane = tid & 63;
  float* mr = mem + row * 768;
  const size_t ghrow = GHB ? (row & 127) : row;
  float v[3];
  float s = 0.f, q = 0.f;
#pragma unroll
  for (int k = 0; k < 3; ++k) {
    v[k] = mr[tid + 256 * k];
    s += v[k]; q += v[k] * v[k];
  }
  s = wsum(s); q = wsum(q);
  if (lane == 0) { ps[wv] = s; pq[wv] = q; }
  __syncthreads();
  s = ps[0] + ps[1] + ps[2] + ps[3];
  q = pq[0] + pq[1] + pq[2] + pq[3];
  const float mu = s * (1.f / 768.f);
  const float rstd = rsqrtf(q * (1.f / 768.f) - mu * mu + 1e-5f);
  float nv[3];
  float s2 = 0.f, q2 = 0.f;
#pragma unroll
  for (int k = 0; k < 3; ++k) {
    const int c = tid + 256 * k;
    const float h = (v[k] - mu) * rstd * g[c] + b[c];
    const float ir  = bf2f(gi[row * 2304 + c]);
    const float iz  = bf2f(gi[row * 2304 + 768 + c]);
    const float in_ = bf2f(gi[row * 2304 + 1536 + c]);
    const float hr  = bf2f(gh[ghrow * 2304 + c]);
    const float hz  = bf2f(gh[ghrow * 2304 + 768 + c]);
    const float hn  = bf2f(gh[ghrow * 2304 + 1536 + c]);
    const float rg = 1.f / (1.f + __expf(-(ir + hr)));
    const float zg = 1.f / (1.f + __expf(-(iz + hz)));
    const float n  = tanhf(in_ + rg * hn);
    nv[k] = (1.f - zg) * n + zg * h;
    mr[c] = nv[k];
    s2 += nv[k]; q2 += nv[k] * nv[k];
  }
  if (EMITLN) {
    s2 = wsum(s2); q2 = wsum(q2);
    __syncthreads();
    if (lane == 0) { ps[wv] = s2; pq[wv] = q2; }
    __syncthreads();
    s2 = ps[0] + ps[1] + ps[2] + ps[3];
    q2 = pq[0] + pq[1] + pq[2] + pq[3];
    const float mu2 = s2 * (1.f / 768.f);
    const float rstd2 = rsqrtf(q2 * (1.f / 768.f) - mu2 * mu2 + 1e-5f);
#pragma unroll
    for (int k = 0; k < 3; ++k) {
      const int c = tid + 256 * k;
      outb[row * 768 + c] = f2bf((nv[k] - mu2) * rstd2 * g[c] + b[c]);
    }
  } else {
#pragma unroll
    for (int k = 0; k < 3; ++k) {
      const int c = tid + 256 * k;
      outb[row * 768 + c] = f2bf(nv[k]);
    }
  }
}

// Merged weight conversion: 10 fp32 sources -> contiguous bf16 region.
__global__ __launch_bounds__(256) void cvt_weights(
    const float* p0, const float* p1, const float* p2, const float* p3,
    const float* p4, const float* p5, const float* p6, const float* p7,
    const float* p8, const float* p9, unsigned short* __restrict__ dst)
{
  const int i = blockIdx.x * 256 + threadIdx.x;  // f4 index, total 2064384
  if (i >= 2064384) return;
  const float* src; int base;
  if      (i < 147456)  { src = p0; base = 0; }
  else if (i < 294912)  { src = p1; base = 147456; }
  else if (i < 442368)  { src = p2; base = 294912; }
  else if (i < 589824)  { src = p3; base = 442368; }
  else if (i < 737280)  { src = p4; base = 589824; }
  else if (i < 884736)  { src = p5; base = 737280; }
  else if (i < 1032192) { src = p6; base = 884736; }
  else if (i < 1179648) { src = p7; base = 1032192; }
  else if (i < 1622016) { src = p8; base = 1179648; }
  else                  { src = p9; base = 1622016; }
  const float4 v = ((const float4*)src)[i - base];
  us4 o;
  o.x = f2bf(v.x); o.y = f2bf(v.y); o.z = f2bf(v.z); o.w = f2bf(v.w);
  ((us4*)dst)[i] = o;
}

// memf[b,s,:] = slots[s,:]; memb[b,s,:] = bf16(LN(slots[s,:])). One block per slot.
__global__ __launch_bounds__(256) void init_mem(
    const float* __restrict__ slots, const float* __restrict__ g,
    const float* __restrict__ b, float* __restrict__ memf,
    unsigned short* __restrict__ memb)
{
  __shared__ float ps[4], pq[4];
  const int s = blockIdx.x;            // 0..127
  const int tid = threadIdx.x, wv = tid >> 6, lane = tid & 63;
  const float* sr = slots + (size_t)s * 768;
  float v[3];
  float su = 0.f, qu = 0.f;
#pragma unroll
  for (int k = 0; k < 3; ++k) { v[k] = sr[tid + 256 * k]; su += v[k]; qu += v[k] * v[k]; }
  su = wsum(su); qu = wsum(qu);
  if (lane == 0) { ps[wv] = su; pq[wv] = qu; }
  __syncthreads();
  su = ps[0] + ps[1] + ps[2] + ps[3];
  qu = pq[0] + pq[1] + pq[2] + pq[3];
  const float mu = su * (1.f / 768.f);
  const float rstd = rsqrtf(qu * (1.f / 768.f) - mu * mu + 1e-5f);
  unsigned short lb[3];
#pragma unroll
  for (int k = 0; k < 3; ++k) {
    const int c = tid + 256 * k;
    lb[k] = f2bf((v[k] - mu) * rstd * g[c] + b[c]);
  }
  for (int bb = 0; bb < 64; ++bb) {
    float* mrow = memf + ((size_t)bb * 128 + s) * 768;
    unsigned short* brow = memb + ((size_t)bb * 128 + s) * 768;
#pragma unroll
    for (int k = 0; k < 3; ++k) { mrow[tid + 256 * k] = v[k]; brow[tid + 256 * k] = lb[k]; }
  }
}

// 6 independent 768x768 transposes in one launch (weight prologue only).
struct TPtrs { const unsigned short* s[6]; unsigned short* d[6]; };
__global__ void transpose_multi(TPtrs p) {
  __shared__ unsigned short t[32][33];
  const unsigned short* in = p.s[blockIdx.z];
  unsigned short* out = p.d[blockIdx.z];
  const int c0 = blockIdx.x * 32, r0 = blockIdx.y * 32;
  const int x = threadIdx.x, y = threadIdx.y;
#pragma unroll
  for (int k = 0; k < 32; k += 8)
    t[y + k][x] = in[(size_t)(r0 + y + k) * 768 + c0 + x];
  __syncthreads();
#pragma unroll
  for (int k = 0; k < 32; k += 8)
    out[(size_t)(c0 + y + k) * 768 + r0 + x] = t[x][y + k];
}

// Two y = W^T x jobs in one launch (grid 6: task = bx/3).
__global__ __launch_bounds__(256) void matvec_T2(
    const float* __restrict__ W0, const float* __restrict__ x0, float* __restrict__ y0,
    const float* __restrict__ W1, const float* __restrict__ x1, float* __restrict__ y1)
{
  const int task = blockIdx.x / 3;
  const int j = (blockIdx.x % 3) * 256 + threadIdx.x;
  const float* W = task ? W1 : W0;
  const float* x = task ? x1 : x0;
  float* y = task ? y1 : y0;
  float s = 0.f;
  for (int k = 0; k < 768; ++k) s += W[(size_t)k * 768 + j] * x[k];
  y[j] = s;
}

// Two y[row]=add[row]+dot(W[row,:],x) jobs (grid 384: task = bx/192).
__global__ __launch_bounds__(256) void matvec_row2(
    const float* __restrict__ W0, const float* __restrict__ x0,
    const float* __restrict__ a0, float* __restrict__ y0,
    const float* __restrict__ W1, const float* __restrict__ x1,
    const float* __restrict__ a1, float* __restrict__ y1)
{
  const int task = blockIdx.x / 192;
  const int row = (blockIdx.x % 192) * 4 + (threadIdx.x >> 6);
  const int lane = threadIdx.x & 63;
  const float* W = task ? W1 : W0;
  const float* x = task ? x1 : x0;
  const float* ad = task ? a1 : a0;
  float* y = task ? y1 : y0;
  const float* r = W + (size_t)row * 768;
  float s = 0.f;
#pragma unroll
  for (int j = 0; j < 12; ++j) s += r[lane + 64 * j] * x[lane + 64 * j];
  s = wsum(s);
  if (lane == 0) y[row] = s + ad[row];
}

// out[i] = scl * (dot(src_i, vec) + (cadd ? cadd[0] : 0))
__global__ __launch_bounds__(256) void rowdot768(
    const float* __restrict__ src, const float* __restrict__ vec,
    const float* __restrict__ cadd, float* __restrict__ out, float scl, int rows)
{
  const int row  = blockIdx.x * 4 + (threadIdx.x >> 6);
  if (row >= rows) return;
  const int lane = threadIdx.x & 63;
  const float* r = src + (size_t)row * 768;
  float s = 0.f;
#pragma unroll
  for (int j = 0; j < 12; ++j) s += r[lane + 64 * j] * vec[lane + 64 * j];
  s = wsum(s);
  if (lane == 0) out[row] = scl * (s + (cadd ? cadd[0] : 0.f));
}

// Fused: zb = bf16(z) AND zv[row] = scl*(dot(z_row, vw) + cw[0]). Wave per row.
__global__ __launch_bounds__(256) void cvt_z_zv(
    const float* __restrict__ z, unsigned short* __restrict__ zb,
    const float* __restrict__ vw, const float* __restrict__ cw,
    float* __restrict__ zv, float scl)
{
  const int row = blockIdx.x * 4 + (threadIdx.x >> 6);
  const int lane = threadIdx.x & 63;
  const float* zr = z + (size_t)row * 768;
  unsigned short* zbr = zb + (size_t)row * 768;
  float s = 0.f;
#pragma unroll
  for (int j = 0; j < 12; ++j) {
    const float v = zr[lane + 64 * j];
    s += v * vw[lane + 64 * j];
    zbr[lane + 64 * j] = f2bf(v);
  }
  s = wsum(s);
  if (lane == 0) zv[row] = scl * (s + cw[0]);
}

__global__ __launch_bounds__(256) void diag_ws(float* __restrict__ out, float wsz, int n) {
  const int i = blockIdx.x * 256 + threadIdx.x;
  if (i < n) out[i] = (i == 0) ? wsz : 0.f;
}

extern "C" void kernel_launch(void* const* d_in, const int* in_sizes, int n_in,
                              void* d_out, int out_size, void* d_ws, size_t ws_size,
                              hipStream_t stream)
{
  const float* z     = (const float*)d_in[0];
  const float* slots = (const float*)d_in[1];
  const float* ln_g  = (const float*)d_in[2];
  const float* ln_b  = (const float*)d_in[3];
  const float* w_wq = (const float*)d_in[4];  const float* w_bq = (const float*)d_in[5];
  const float* w_wk = (const float*)d_in[6];  const float* w_bk = (const float*)d_in[7];
  const float* w_wv = (const float*)d_in[8];  const float* w_bv = (const float*)d_in[9];
  const float* w_wo = (const float*)d_in[10]; const float* w_bo = (const float*)d_in[11];
  const float* r_wq = (const float*)d_in[12]; const float* r_bq = (const float*)d_in[13];
  const float* r_wk = (const float*)d_in[14]; const float* r_bk = (const float*)d_in[15];
  const float* r_wv = (const float*)d_in[16]; const float* r_bv = (const float*)d_in[17];
  const float* r_wo = (const float*)d_in[18]; const float* r_bo = (const float*)d_in[19];
  const float* g_wih = (const float*)d_in[20]; const float* g_bih = (const float*)d_in[21];
  const float* g_whh = (const float*)d_in[22]; const float* g_bhh = (const float*)d_in[23];

  // ---- arena (bytes) ----
  constexpr size_t O_F    = 16515072;    // Fqk,Fwv,Fvo,Frq
  constexpr size_t O_T6   = 21233664;    // 6 transposed weights
  constexpr size_t O_GH0  = 28311552;    // 589824
  constexpr size_t O_FL   = 28901376;    // float vectors
  constexpr size_t O_memf = 29096192;    // 25165824
  constexpr size_t O_Kz   = 54262016;    // 50331648: Kz | end: memFr
  constexpr size_t O_VwoT = 104593664;   // 50331648: VwoT | end: memVoT/Sbr/Abr
  constexpr size_t O_L    = 154925312;   // 62914560 scratch
  constexpr size_t NEED   = 217839872;

  if (ws_size < NEED) {
    hipLaunchKernelGGL(diag_ws, dim3((out_size + 255) / 256), dim3(256), 0, stream,
                       (float*)d_out, (float)ws_size, out_size);
    return;
  }

  char* ws = (char*)d_ws;
  unsigned short* wqb  = (unsigned short*)(ws + 0);
  unsigned short* wkb  = wqb + 589824;
  unsigned short* wvb  = wkb + 589824;
  unsigned short* wob  = wvb + 589824;
  unsigned short* rqb  = wob + 589824;
  unsigned short* rkb  = rqb + 589824;
  unsigned short* rvb  = rkb + 589824;
  unsigned short* rob  = rvb + 589824;
  unsigned short* wihb = rob + 589824;
  unsigned short* whhb = wihb + 1769472;
  unsigned short* Fqk  = (unsigned short*)(ws + O_F);
  unsigned short* Fwv  = Fqk + 589824;
  unsigned short* Fvo  = Fwv + 589824;
  unsigned short* Frq  = Fvo + 589824;
  unsigned short* T0   = (unsigned short*)(ws + O_T6);
  unsigned short* T1   = T0 + 589824;
  unsigned short* T2   = T1 + 589824;
  unsigned short* T3   = T2 + 589824;
  unsigned short* T4   = T3 + 589824;
  unsigned short* T5   = T4 + 589824;
  unsigned short* gh0  = (unsigned short*)(ws + O_GH0);
  float* bih_c   = (float*)(ws + O_FL);     // 2304 (+2304 bhh adjacent)
  float* bhh_c   = bih_c + 2304;
  float* const_o = bhh_c + 2304;
  float* bvo     = const_o + 768;
  float* vw      = bvo + 768;
  float* vr      = vw + 768;
  float* cw      = vr + 768;
  float* zv      = cw + 64;                 // 32768
  float* colb    = zv + 32768;              // 8192
  float* memf = (float*)(ws + O_memf);
  unsigned short* Kz    = (unsigned short*)(ws + O_Kz);
  unsigned short* memFr = (unsigned short*)(ws + O_Kz);            // end (Kz dead)
  unsigned short* VwoT  = (unsigned short*)(ws + O_VwoT);
  unsigned short* memVoT  = (unsigned short*)(ws + O_VwoT);             // end (VwoT dead)
  float*          Sbr     = (float*)(ws + O_VwoT + 25165824);           // end
  unsigned short* Abr     = (unsigned short*)(ws + O_VwoT + 41943040);  // end
  char* L = ws + O_L;
  unsigned short* memb  = (unsigned short*)(L + 0);          // 12.6MB (no aliasing now)
  unsigned short* updb  = (unsigned short*)(L + 12582912);
  float*          Sbuf  = (float*)(L + 25165824);            // 16.8MB
  unsigned short* Abuf  = (unsigned short*)(L + 41943040);   // 8.4MB
  unsigned short* gib   = (unsigned short*)(L + 25165824);   // 37.7MB (S/A dead)
  // d_out scratch: ghb [0..37.7MB), zb [48MB..96MB)
  unsigned short* ghb   = (unsigned short*)d_out;
  unsigned short* zb    = (unsigned short*)((char*)d_out + 50331648);

  const float scale = 1.0f / sqrtf(768.f);

  // ---- prologue ----
  hipLaunchKernelGGL(cvt_weights, dim3(8064), dim3(256), 0, stream,
      w_wq, w_wk, w_wv, w_wo, r_wq, r_wk, r_wv, r_wo, g_wih, g_whh, wqb);
  hipMemcpyAsync(bih_c, g_bih, 2304 * 4, hipMemcpyDeviceToDevice, stream);
  hipMemcpyAsync(bhh_c, g_bhh, 2304 * 4, hipMemcpyDeviceToDevice, stream);

  {
    TPtrs tp;
    tp.s[0] = wqb; tp.d[0] = T0;
    tp.s[1] = wkb; tp.d[1] = T1;
    tp.s[2] = wvb; tp.d[2] = T2;
    tp.s[3] = rvb; tp.d[3] = T3;
    tp.s[4] = rqb; tp.d[4] = T4;
    tp.s[5] = rkb; tp.d[5] = T5;
    hipLaunchKernelGGL(transpose_multi, dim3(24, 24, 6), dim3(32, 8), 0, stream, tp);
  }
  {
    QuadPtrs qp;
    qp.a[0] = T0;  qp.b[0] = T1; qp.c[0] = Fqk;  // Wq^T Wk
    qp.a[1] = wob; qp.b[1] = T2; qp.c[1] = Fwv;  // Wo Wv
    qp.a[2] = rob; qp.b[2] = T3; qp.c[2] = Fvo;  // Ro Rv
    qp.a[3] = T4;  qp.b[3] = T5; qp.c[3] = Frq;  // Rq^T Rk
    hipLaunchKernelGGL(gemm_nt_quad, dim3(6, 6, 4), dim3(256), 0, stream, qp);
  }

  hipLaunchKernelGGL(matvec_T2, dim3(6), dim3(256), 0, stream,
      w_wk, w_bq, vw, r_wk, r_bq, vr);
  hipLaunchKernelGGL(matvec_row2, dim3(384), dim3(256), 0, stream,
      w_wo, w_bv, w_bo, const_o, r_wo, r_bv, r_bo, bvo);
  hipLaunchKernelGGL(rowdot768, dim3(1), dim3(256), 0, stream,
      w_bq, w_bk, (const float*)nullptr, cw, 1.0f, 1);
  hipLaunchKernelGGL(cvt_z_zv, dim3(8192), dim3(256), 0, stream, z, zb, vw, cw, zv, scale);
  hipLaunchKernelGGL(init_mem, dim3(128), dim3(256), 0, stream,
      slots, ln_g, ln_b, memf, memb);

  // VwoT[b] = Fwv . z_b^T  (M=768, N=512, K=768, batched) — no transpose kernel
  hipLaunchKernelGGL((gemm_nt64<1, false>), dim3(4, 6, 64), dim3(256), 0, stream,
      Fwv, zb, (const float*)nullptr, (void*)VwoT, 768, 512, 768,
      0ll, 393216ll, 393216ll, 0ll, 1.0f);
  // Kz = z . Fqk^T
  hipLaunchKernelGGL((gemm_nt64<1, false>), dim3(6, 256, 1), dim3(256), 0, stream,
      zb, Fqk, (const float*)nullptr, (void*)Kz, 32768, 768, 768, 0ll, 0ll, 0ll, 0ll, 1.0f);

  const long long sA_g = (long long)(memb - updb);  // z=1 -> memb
  const long long sC_g = (long long)(ghb - gib);    // z=1 -> gh in d_out scratch

  // ---- T=3 recurrence ----
  for (int t = 0; t < 3; ++t) {
    hipLaunchKernelGGL((gemm_nt<0, true>), dim3(4, 1, 64), dim3(256), 0, stream,
        memb, Kz, zv, (void*)Sbuf, 128, 512, 768,
        98304ll, 393216ll, 65536ll, 512ll, scale);
    hipLaunchKernelGGL((softmax_kernel<512>), dim3(2048), dim3(256), 0, stream, Sbuf, Abuf);
    hipLaunchKernelGGL((gemm_nt<1, true>), dim3(6, 1, 64), dim3(256), 0, stream,
        Abuf, VwoT, const_o, (void*)updb, 128, 768, 512,
        65536ll, 393216ll, 98304ll, 0ll, 1.0f);
    if (t == 0) {
      hipLaunchKernelGGL((gemm_nt64<1, true>), dim3(18, 1, 1), dim3(256), 0, stream,
          memb, whhb, bhh_c, (void*)gh0, 128, 2304, 768, 0ll, 0ll, 0ll, 0ll, 1.0f);
      hipLaunchKernelGGL((gemm_nt64<1, true>), dim3(18, 64, 1), dim3(256), 0, stream,
          updb, wihb, bih_c, (void*)gib, 8192, 2304, 768, 0ll, 0ll, 0ll, 0ll, 1.0f);
      hipLaunchKernelGGL((gru_ln_combine<true, true>), dim3(8192), dim3(256), 0, stream,
          gib, gh0, memf, ln_g, ln_b, memb);
    } else {
      hipLaunchKernelGGL((gemm_nt64<1, true>), dim3(18, 64, 2), dim3(256), 0, stream,
          updb, wihb, bih_c, (void*)gib, 8192, 2304, 768,
          sA_g, 1769472ll, sC_g, 2304ll, 1.0f);
      if (t < 2)
        hipLaunchKernelGGL((gru_ln_combine<false, true>), dim3(8192), dim3(256), 0, stream,
            gib, ghb, memf, ln_g, ln_b, memb);
      else
        hipLaunchKernelGGL((gru_ln_combine<false, false>), dim3(8192), dim3(256), 0, stream,
            gib, ghb, memf, ln_g, ln_b, memb);
    }
  }
  // memb now holds bf16(mem_final)

  // ---- read attention ----
  // memFr = memb . Frq^T (into Kz region, Kz dead)
  hipLaunchKernelGGL((gemm_nt64<1, false>), dim3(6, 64, 1), dim3(256), 0, stream,
      memb, Frq, (const float*)nullptr, (void*)memFr, 8192, 768, 768,
      0ll, 0ll, 0ll, 0ll, 1.0f);
  // memVoT[b] = Fvo . memb_b^T (M=768, N=128, K=768, batched) — no transpose kernel
  hipLaunchKernelGGL((gemm_nt64<1, false>), dim3(1, 6, 64), dim3(256), 0, stream,
      Fvo, memb, (const float*)nullptr, (void*)memVoT, 768, 128, 768,
      0ll, 98304ll, 98304ll, 0ll, 1.0f);
  hipLaunchKernelGGL(rowdot768, dim3(2048), dim3(256), 0, stream,
      memf, vr, (const float*)nullptr, colb, scale, 8192);
  // read scores: A = zb (d_out high region, still live), B = memFr
  hipLaunchKernelGGL((gemm_nt<0, true>), dim3(1, 4, 64), dim3(256), 0, stream,
      zb, memFr, colb, (void*)Sbr, 512, 128, 768,
      393216ll, 98304ll, 65536ll, 128ll, scale);
  hipLaunchKernelGGL((softmax_kernel<128>), dim3(8192), dim3(256), 0, stream, Sbr, Abr);
  // final: overwrites ALL of d_out (zb/ghb scratch dead from here)
  hipLaunchKernelGGL((gemm_nt<0, true>), dim3(6, 4, 64), dim3(256), 0, stream,
      Abr, memVoT, bvo, d_out, 512, 768, 128,
      65536ll, 98304ll, 393216ll, 0ll, 1.0f);
}

// Round 12
// 738.114 us; speedup vs baseline: 1.6218x; 1.0174x over previous
//
#include <hip/hip_runtime.h>
#include <hip/hip_bf16.h>
#include <math.h>

// Memory module: E=768, S=128, T=3, B=64, L=512. fp32 in/out.
// bf16 MFMA GEMMs (fp32 accum). Folds: Fqk=Wq^T Wk, Fwv=Wo Wv, Fvo=Ro Rv, Frq=Rq^T Rk.
// All large GEMMs on gemm_nt64 (BK=64, both-sides XOR swizzle, 32KB LDS).
// d_out doubles as scratch: ghb at +0, zb at +48MB; final GEMM overwrites d_out last.

typedef __attribute__((ext_vector_type(4))) float f32x4;
typedef __attribute__((ext_vector_type(8))) short short8;
typedef __attribute__((ext_vector_type(4))) unsigned short us4;

__device__ __forceinline__ unsigned short f2bf(float x) {
  union { float f; unsigned u; } v; v.f = x;
  unsigned r = v.u + 0x7fffu + ((v.u >> 16) & 1u);  // RNE
  return (unsigned short)(r >> 16);
}
__device__ __forceinline__ float bf2f(unsigned short u) {
  union { unsigned u; float f; } v; v.u = (unsigned)u << 16; return v.f;
}

__device__ __forceinline__ void g2l16(const void* g, void* l) {
  __builtin_amdgcn_global_load_lds(
      (const __attribute__((address_space(1))) unsigned int*)g,
      (__attribute__((address_space(3))) unsigned int*)l, 16, 0, 0);
}

__device__ __forceinline__ float wsum(float v) {
#pragma unroll
  for (int o = 32; o > 0; o >>= 1) v += __shfl_xor(v, o, 64);
  return v;
}
__device__ __forceinline__ float wmax(float v) {
#pragma unroll
  for (int o = 32; o > 0; o >>= 1) v = fmaxf(v, __shfl_xor(v, o, 64));
  return v;
}

// m204 bijective XCD swizzle of flattened grid -> (tn, tm, bz)
__device__ __forceinline__ void xcd_map(int& tn, int& tm, long long& bz) {
  const int gx = gridDim.x, gy = gridDim.y, gz = gridDim.z;
  const int nwg = gx * gy * gz;
  const int lin = blockIdx.x + gx * (blockIdx.y + gy * blockIdx.z);
  const int q = nwg >> 3, r = nwg & 7;
  const int xcd = lin & 7, jj = lin >> 3;
  const int w = (xcd < r ? xcd * (q + 1) : r * (q + 1) + (xcd - r) * q) + jj;
  tn = w % gx;
  const int t2 = w / gx;
  tm = t2 % gy;
  bz = t2 / gy;
}

__device__ __forceinline__ void c_write_128(
    void* Cg, size_t cb, int N, int tm, int tn, int wr, int wc, int lane,
    const f32x4 acc[4][4], const float* bias, bool has_bias, float alpha, int omode)
{
#pragma unroll
  for (int a = 0; a < 4; ++a) {
    const int row0 = tm * 128 + wr * 64 + a * 16 + (lane >> 4) * 4;
#pragma unroll
    for (int b = 0; b < 4; ++b) {
      const int col = tn * 128 + wc * 64 + b * 16 + (lane & 15);
      float bv = has_bias ? bias[col] : 0.f;
#pragma unroll
      for (int rr = 0; rr < 4; ++rr) {
        float v = acc[a][b][rr] * alpha + bv;
        if (omode == 0)
          ((float*)Cg)[cb + (size_t)(row0 + rr) * N + col] = v;
        else
          ((unsigned short*)Cg)[cb + (size_t)(row0 + rr) * N + col] = f2bf(v);
      }
    }
  }
}

// ---- m97 128x128 BK=32 body (fold quad only) ----
template<int OMODE, bool BIAS>
__device__ __forceinline__ void gemm_body(
    const unsigned short* __restrict__ A, const unsigned short* __restrict__ B,
    const float* __restrict__ bias, void* __restrict__ Cg, size_t cb,
    int N, int K, int tm, int tn, float alpha,
    unsigned short* As, unsigned short* Bs)
{
  const int tid  = threadIdx.x;
  const int lane = tid & 63;
  const int wv   = tid >> 6;
  const int wr   = wv >> 1, wc = wv & 1;

  A += (size_t)tm * 128 * K;
  B += (size_t)tn * 128 * K;

  const int srow = wv * 16 + (lane >> 2);
  const int kby  = (lane & 3) * 16;

  f32x4 acc[4][4];
#pragma unroll
  for (int a = 0; a < 4; ++a)
#pragma unroll
    for (int b = 0; b < 4; ++b) acc[a][b] = (f32x4)(0.f);

  const int mrow = wr * 64 + (lane & 15);
  const int nrow = wc * 64 + (lane & 15);
  const int koff = (lane >> 4) * 8;

  for (int kt = 0; kt < K; kt += 32) {
#pragma unroll
    for (int i = 0; i < 2; ++i) {
      g2l16((const char*)(A + (size_t)(i * 64 + srow) * K + kt) + kby,
            (char*)As + i * 4096 + wv * 1024);
      g2l16((const char*)(B + (size_t)(i * 64 + srow) * K + kt) + kby,
            (char*)Bs + i * 4096 + wv * 1024);
    }
    __syncthreads();
    short8 af[4], bf[4];
#pragma unroll
    for (int a = 0; a < 4; ++a) af[a] = *(const short8*)&As[(mrow + a * 16) * 32 + koff];
#pragma unroll
    for (int b = 0; b < 4; ++b) bf[b] = *(const short8*)&Bs[(nrow + b * 16) * 32 + koff];
#pragma unroll
    for (int a = 0; a < 4; ++a)
#pragma unroll
      for (int b = 0; b < 4; ++b)
        acc[a][b] = __builtin_amdgcn_mfma_f32_16x16x32_bf16(af[a], bf[b], acc[a][b], 0, 0, 0);
    __syncthreads();
  }
  c_write_128(Cg, cb, N, tm, tn, wr, wc, lane, acc, bias, BIAS, alpha, OMODE);
}

// ---- BK=64 m97 variant: half the barrier pairs per K; 32KB LDS; XOR-swizzled.
// Involution s(o)=o^(((o>>7)&7)<<4) on stage-source and LDS read (both sides).
// Requires K%64==0, M%128==0, N%128==0.
template<int OMODE, bool BIAS>
__global__ __launch_bounds__(256) void gemm_nt64(
    const unsigned short* __restrict__ Ag, const unsigned short* __restrict__ Bg,
    const float* __restrict__ bias, void* __restrict__ Cg,
    int M, int N, int K, long long sA, long long sB, long long sC,
    long long sBias, float alpha)
{
  __shared__ __align__(16) unsigned short As[128 * 64];  // 16KB
  __shared__ __align__(16) unsigned short Bs[128 * 64];

  const int tid  = threadIdx.x;
  const int lane = tid & 63;
  const int wv   = tid >> 6;
  const int wr   = wv >> 1, wc = wv & 1;

  int tn, tm; long long bz;
  xcd_map(tn, tm, bz);

  const unsigned short* A = Ag + bz * sA + (size_t)tm * 128 * K;
  const unsigned short* B = Bg + bz * sB + (size_t)tn * 128 * K;

  auto swz = [](int o) { return o ^ (((o >> 7) & 7) << 4); };
  int srow[4], scb[4];
#pragma unroll
  for (int c = 0; c < 4; ++c) {
    const int olog = swz(c * 4096 + tid * 16);
    srow[c] = olog >> 7;
    scb[c]  = olog & 127;
  }

  f32x4 acc[4][4];
#pragma unroll
  for (int a = 0; a < 4; ++a)
#pragma unroll
    for (int b = 0; b < 4; ++b) acc[a][b] = (f32x4)(0.f);

  const int mrow = wr * 64 + (lane & 15);
  const int nrow = wc * 64 + (lane & 15);
  const int kb   = (lane >> 4) * 16;

  for (int kt = 0; kt < K; kt += 64) {
#pragma unroll
    for (int c = 0; c < 4; ++c) {
      g2l16((const char*)(A + (size_t)srow[c] * K + kt) + scb[c],
            (char*)As + c * 4096 + wv * 1024);
      g2l16((const char*)(B + (size_t)srow[c] * K + kt) + scb[c],
            (char*)Bs + c * 4096 + wv * 1024);
    }
    __syncthreads();
#pragma unroll
    for (int h = 0; h < 2; ++h) {
      short8 af[4], bf[4];
#pragma unroll
      for (int a = 0; a < 4; ++a)
        af[a] = *(const short8*)((char*)As + swz((mrow + a * 16) * 128 + h * 64 + kb));
#pragma unroll
      for (int b = 0; b < 4; ++b)
        bf[b] = *(const short8*)((char*)Bs + swz((nrow + b * 16) * 128 + h * 64 + kb));
#pragma unroll
      for (int a = 0; a < 4; ++a)
#pragma unroll
        for (int b = 0; b < 4; ++b)
          acc[a][b] = __builtin_amdgcn_mfma_f32_16x16x32_bf16(af[a], bf[b], acc[a][b], 0, 0, 0);
    }
    __syncthreads();
  }

  const float* bp = BIAS ? bias + bz * sBias : (const float*)nullptr;
  c_write_128(Cg, (size_t)(bz * sC), N, tm, tn, wr, wc, lane, acc, bp, BIAS, alpha, OMODE);
}

// 4 independent 768^3 NT GEMMs (fold products). bf16 out, no bias.
struct QuadPtrs {
  const unsigned short* a[4];
  const unsigned short* b[4];
  unsigned short* c[4];
};
__global__ __launch_bounds__(256) void gemm_nt_quad(QuadPtrs p) {
  __shared__ __align__(16) unsigned short As[128 * 32];
  __shared__ __align__(16) unsigned short Bs[128 * 32];
  const int zi = blockIdx.z;
  gemm_body<1, false>(p.a[zi], p.b[zi], nullptr, (void*)p.c[zi], 0,
                      768, 768, blockIdx.y, blockIdx.x, 1.0f, As, Bs);
}

// Softmax LR=512: float4-vectorized loads, us4 stores. One wave per row.
__global__ __launch_bounds__(256) void softmax512(
    const float* __restrict__ sc, unsigned short* __restrict__ p)
{
  const int row  = blockIdx.x * 4 + (threadIdx.x >> 6);
  const int lane = threadIdx.x & 63;
  const float4* sr = (const float4*)(sc + (size_t)row * 512);
  float4 v[2];
  float m = -1e30f;
#pragma unroll
  for (int j = 0; j < 2; ++j) {
    v[j] = sr[lane + 64 * j];
    m = fmaxf(m, fmaxf(fmaxf(v[j].x, v[j].y), fmaxf(v[j].z, v[j].w)));
  }
  m = wmax(m);
  float s = 0.f;
#pragma unroll
  for (int j = 0; j < 2; ++j) {
    v[j].x = __expf(v[j].x - m); v[j].y = __expf(v[j].y - m);
    v[j].z = __expf(v[j].z - m); v[j].w = __expf(v[j].w - m);
    s += v[j].x + v[j].y + v[j].z + v[j].w;
  }
  s = wsum(s);
  const float inv = 1.f / s;
  us4* pr = (us4*)(p + (size_t)row * 512);
#pragma unroll
  for (int j = 0; j < 2; ++j) {
    us4 o;
    o.x = f2bf(v[j].x * inv); o.y = f2bf(v[j].y * inv);
    o.z = f2bf(v[j].z * inv); o.w = f2bf(v[j].w * inv);
    pr[lane + 64 * j] = o;
  }
}

// Softmax LR=128 (scalar; small). One wave per row.
__global__ __launch_bounds__(256) void softmax128(
    const float* __restrict__ sc, unsigned short* __restrict__ p)
{
  const int row  = blockIdx.x * 4 + (threadIdx.x >> 6);
  const int lane = threadIdx.x & 63;
  const float* sr = sc + (size_t)row * 128;
  float v[2];
  float m = -1e30f;
#pragma unroll
  for (int j = 0; j < 2; ++j) { v[j] = sr[lane + 64 * j]; m = fmaxf(m, v[j]); }
  m = wmax(m);
  float s = 0.f;
#pragma unroll
  for (int j = 0; j < 2; ++j) { v[j] = __expf(v[j] - m); s += v[j]; }
  s = wsum(s);
  const float inv = 1.f / s;
  unsigned short* pr = p + (size_t)row * 128;
#pragma unroll
  for (int j = 0; j < 2; ++j) pr[lane + 64 * j] = f2bf(v[j] * inv);
}

// GRU combine with inline LN of old mem (h) + emit next operand.
template<bool GHB, bool EMITLN>
__global__ __launch_bounds__(256) void gru_ln_combine(
    const unsigned short* __restrict__ gi, const unsigned short* __restrict__ gh,
    float* __restrict__ mem, const float* __restrict__ g, const float* __restrict__ b,
    unsigned short* __restrict__ outb)
{
  __shared__ float ps[4], pq[4];
  const size_t row = blockIdx.x;
  const int tid = threadIdx.x, wv = tid >> 6, lane = tid & 63;
  float* mr = mem + row * 768;
  const size_t ghrow = GHB ? (row & 127) : row;
  float v[3];
  float s = 0.f, q = 0.f;
#pragma unroll
  for (int k = 0; k < 3; ++k) {
    v[k] = mr[tid + 256 * k];
    s += v[k]; q += v[k] * v[k];
  }
  s = wsum(s); q = wsum(q);
  if (lane == 0) { ps[wv] = s; pq[wv] = q; }
  __syncthreads();
  s = ps[0] + ps[1] + ps[2] + ps[3];
  q = pq[0] + pq[1] + pq[2] + pq[3];
  const float mu = s * (1.f / 768.f);
  const float rstd = rsqrtf(q * (1.f / 768.f) - mu * mu + 1e-5f);
  float nv[3];
  float s2 = 0.f, q2 = 0.f;
#pragma unroll
  for (int k = 0; k < 3; ++k) {
    const int c = tid + 256 * k;
    const float h = (v[k] - mu) * rstd * g[c] + b[c];
    const float ir  = bf2f(gi[row * 2304 + c]);
    const float iz  = bf2f(gi[row * 2304 + 768 + c]);
    const float in_ = bf2f(gi[row * 2304 + 1536 + c]);
    const float hr  = bf2f(gh[ghrow * 2304 + c]);
    const float hz  = bf2f(gh[ghrow * 2304 + 768 + c]);
    const float hn  = bf2f(gh[ghrow * 2304 + 1536 + c]);
    const float rg = 1.f / (1.f + __expf(-(ir + hr)));
    const float zg = 1.f / (1.f + __expf(-(iz + hz)));
    const float n  = tanhf(in_ + rg * hn);
    nv[k] = (1.f - zg) * n + zg * h;
    mr[c] = nv[k];
    s2 += nv[k]; q2 += nv[k] * nv[k];
  }
  if (EMITLN) {
    s2 = wsum(s2); q2 = wsum(q2);
    __syncthreads();
    if (lane == 0) { ps[wv] = s2; pq[wv] = q2; }
    __syncthreads();
    s2 = ps[0] + ps[1] + ps[2] + ps[3];
    q2 = pq[0] + pq[1] + pq[2] + pq[3];
    const float mu2 = s2 * (1.f / 768.f);
    const float rstd2 = rsqrtf(q2 * (1.f / 768.f) - mu2 * mu2 + 1e-5f);
#pragma unroll
    for (int k = 0; k < 3; ++k) {
      const int c = tid + 256 * k;
      outb[row * 768 + c] = f2bf((nv[k] - mu2) * rstd2 * g[c] + b[c]);
    }
  } else {
#pragma unroll
    for (int k = 0; k < 3; ++k) {
      const int c = tid + 256 * k;
      outb[row * 768 + c] = f2bf(nv[k]);
    }
  }
}

// Merged weight conversion: 10 fp32 sources -> contiguous bf16 region.
__global__ __launch_bounds__(256) void cvt_weights(
    const float* p0, const float* p1, const float* p2, const float* p3,
    const float* p4, const float* p5, const float* p6, const float* p7,
    const float* p8, const float* p9, unsigned short* __restrict__ dst)
{
  const int i = blockIdx.x * 256 + threadIdx.x;  // f4 index, total 2064384
  if (i >= 2064384) return;
  const float* src; int base;
  if      (i < 147456)  { src = p0; base = 0; }
  else if (i < 294912)  { src = p1; base = 147456; }
  else if (i < 442368)  { src = p2; base = 294912; }
  else if (i < 589824)  { src = p3; base = 442368; }
  else if (i < 737280)  { src = p4; base = 589824; }
  else if (i < 884736)  { src = p5; base = 737280; }
  else if (i < 1032192) { src = p6; base = 884736; }
  else if (i < 1179648) { src = p7; base = 1032192; }
  else if (i < 1622016) { src = p8; base = 1179648; }
  else                  { src = p9; base = 1622016; }
  const float4 v = ((const float4*)src)[i - base];
  us4 o;
  o.x = f2bf(v.x); o.y = f2bf(v.y); o.z = f2bf(v.z); o.w = f2bf(v.w);
  ((us4*)dst)[i] = o;
}

// memf[b,s,:] = slots[s,:]; memb[b,s,:] = bf16(LN(slots[s,:])). Grid (128, 8).
__global__ __launch_bounds__(256) void init_mem(
    const float* __restrict__ slots, const float* __restrict__ g,
    const float* __restrict__ b, float* __restrict__ memf,
    unsigned short* __restrict__ memb)
{
  __shared__ float ps[4], pq[4];
  const int s = blockIdx.x;            // 0..127
  const int g0 = blockIdx.y * 8;       // batch group
  const int tid = threadIdx.x, wv = tid >> 6, lane = tid & 63;
  const float* sr = slots + (size_t)s * 768;
  float v[3];
  float su = 0.f, qu = 0.f;
#pragma unroll
  for (int k = 0; k < 3; ++k) { v[k] = sr[tid + 256 * k]; su += v[k]; qu += v[k] * v[k]; }
  su = wsum(su); qu = wsum(qu);
  if (lane == 0) { ps[wv] = su; pq[wv] = qu; }
  __syncthreads();
  su = ps[0] + ps[1] + ps[2] + ps[3];
  qu = pq[0] + pq[1] + pq[2] + pq[3];
  const float mu = su * (1.f / 768.f);
  const float rstd = rsqrtf(qu * (1.f / 768.f) - mu * mu + 1e-5f);
  unsigned short lb[3];
#pragma unroll
  for (int k = 0; k < 3; ++k) {
    const int c = tid + 256 * k;
    lb[k] = f2bf((v[k] - mu) * rstd * g[c] + b[c]);
  }
  for (int bb = g0; bb < g0 + 8; ++bb) {
    float* mrow = memf + ((size_t)bb * 128 + s) * 768;
    unsigned short* brow = memb + ((size_t)bb * 128 + s) * 768;
#pragma unroll
    for (int k = 0; k < 3; ++k) { mrow[tid + 256 * k] = v[k]; brow[tid + 256 * k] = lb[k]; }
  }
}

// 6 independent 768x768 transposes in one launch (weight prologue only).
struct TPtrs { const unsigned short* s[6]; unsigned short* d[6]; };
__global__ void transpose_multi(TPtrs p) {
  __shared__ unsigned short t[32][33];
  const unsigned short* in = p.s[blockIdx.z];
  unsigned short* out = p.d[blockIdx.z];
  const int c0 = blockIdx.x * 32, r0 = blockIdx.y * 32;
  const int x = threadIdx.x, y = threadIdx.y;
#pragma unroll
  for (int k = 0; k < 32; k += 8)
    t[y + k][x] = in[(size_t)(r0 + y + k) * 768 + c0 + x];
  __syncthreads();
#pragma unroll
  for (int k = 0; k < 32; k += 8)
    out[(size_t)(c0 + y + k) * 768 + r0 + x] = t[x][y + k];
}

// Two y = W^T x jobs in one launch (grid 6: task = bx/3).
__global__ __launch_bounds__(256) void matvec_T2(
    const float* __restrict__ W0, const float* __restrict__ x0, float* __restrict__ y0,
    const float* __restrict__ W1, const float* __restrict__ x1, float* __restrict__ y1)
{
  const int task = blockIdx.x / 3;
  const int j = (blockIdx.x % 3) * 256 + threadIdx.x;
  const float* W = task ? W1 : W0;
  const float* x = task ? x1 : x0;
  float* y = task ? y1 : y0;
  float s = 0.f;
  for (int k = 0; k < 768; ++k) s += W[(size_t)k * 768 + j] * x[k];
  y[j] = s;
}

// Two y[row]=add[row]+dot(W[row,:],x) jobs (grid 384: task = bx/192).
__global__ __launch_bounds__(256) void matvec_row2(
    const float* __restrict__ W0, const float* __restrict__ x0,
    const float* __restrict__ a0, float* __restrict__ y0,
    const float* __restrict__ W1, const float* __restrict__ x1,
    const float* __restrict__ a1, float* __restrict__ y1)
{
  const int task = blockIdx.x / 192;
  const int row = (blockIdx.x % 192) * 4 + (threadIdx.x >> 6);
  const int lane = threadIdx.x & 63;
  const float* W = task ? W1 : W0;
  const float* x = task ? x1 : x0;
  const float* ad = task ? a1 : a0;
  float* y = task ? y1 : y0;
  const float4* r = (const float4*)(W + (size_t)row * 768);
  const float4* xv = (const float4*)x;
  float s = 0.f;
#pragma unroll
  for (int j = 0; j < 3; ++j) {
    const float4 a = r[lane + 64 * j], c = xv[lane + 64 * j];
    s += a.x * c.x + a.y * c.y + a.z * c.z + a.w * c.w;
  }
  s = wsum(s);
  if (lane == 0) y[row] = s + ad[row];
}

// out[i] = scl * (dot(src_i, vec) + (cadd ? cadd[0] : 0)). float4 loads.
__global__ __launch_bounds__(256) void rowdot768(
    const float* __restrict__ src, const float* __restrict__ vec,
    const float* __restrict__ cadd, float* __restrict__ out, float scl, int rows)
{
  const int row  = blockIdx.x * 4 + (threadIdx.x >> 6);
  if (row >= rows) return;
  const int lane = threadIdx.x & 63;
  const float4* r = (const float4*)(src + (size_t)row * 768);
  const float4* vv = (const float4*)vec;
  float s = 0.f;
#pragma unroll
  for (int j = 0; j < 3; ++j) {
    const float4 a = r[lane + 64 * j], c = vv[lane + 64 * j];
    s += a.x * c.x + a.y * c.y + a.z * c.z + a.w * c.w;
  }
  s = wsum(s);
  if (lane == 0) out[row] = scl * (s + (cadd ? cadd[0] : 0.f));
}

// Fused: zb = bf16(z) AND zv[row] = scl*(dot(z_row, vw) + cw[0]). float4 loads.
__global__ __launch_bounds__(256) void cvt_z_zv(
    const float* __restrict__ z, unsigned short* __restrict__ zb,
    const float* __restrict__ vw, const float* __restrict__ cw,
    float* __restrict__ zv, float scl)
{
  const int row = blockIdx.x * 4 + (threadIdx.x >> 6);
  const int lane = threadIdx.x & 63;
  const float4* zr = (const float4*)(z + (size_t)row * 768);
  const float4* wv = (const float4*)vw;
  us4* zbr = (us4*)(zb + (size_t)row * 768);
  float s = 0.f;
#pragma unroll
  for (int j = 0; j < 3; ++j) {
    const float4 v = zr[lane + 64 * j];
    const float4 w = wv[lane + 64 * j];
    s += v.x * w.x + v.y * w.y + v.z * w.z + v.w * w.w;
    us4 o;
    o.x = f2bf(v.x); o.y = f2bf(v.y); o.z = f2bf(v.z); o.w = f2bf(v.w);
    zbr[lane + 64 * j] = o;
  }
  s = wsum(s);
  if (lane == 0) zv[row] = scl * (s + cw[0]);
}

__global__ __launch_bounds__(256) void diag_ws(float* __restrict__ out, float wsz, int n) {
  const int i = blockIdx.x * 256 + threadIdx.x;
  if (i < n) out[i] = (i == 0) ? wsz : 0.f;
}

extern "C" void kernel_launch(void* const* d_in, const int* in_sizes, int n_in,
                              void* d_out, int out_size, void* d_ws, size_t ws_size,
                              hipStream_t stream)
{
  const float* z     = (const float*)d_in[0];
  const float* slots = (const float*)d_in[1];
  const float* ln_g  = (const float*)d_in[2];
  const float* ln_b  = (const float*)d_in[3];
  const float* w_wq = (const float*)d_in[4];  const float* w_bq = (const float*)d_in[5];
  const float* w_wk = (const float*)d_in[6];  const float* w_bk = (const float*)d_in[7];
  const float* w_wv = (const float*)d_in[8];  const float* w_bv = (const float*)d_in[9];
  const float* w_wo = (const float*)d_in[10]; const float* w_bo = (const float*)d_in[11];
  const float* r_wq = (const float*)d_in[12]; const float* r_bq = (const float*)d_in[13];
  const float* r_wk = (const float*)d_in[14]; const float* r_bk = (const float*)d_in[15];
  const float* r_wv = (const float*)d_in[16]; const float* r_bv = (const float*)d_in[17];
  const float* r_wo = (const float*)d_in[18]; const float* r_bo = (const float*)d_in[19];
  const float* g_wih = (const float*)d_in[20]; const float* g_bih = (const float*)d_in[21];
  const float* g_whh = (const float*)d_in[22]; const float* g_bhh = (const float*)d_in[23];

  // ---- arena (bytes) ----
  constexpr size_t O_F    = 16515072;
  constexpr size_t O_T6   = 21233664;
  constexpr size_t O_GH0  = 28311552;
  constexpr size_t O_FL   = 28901376;
  constexpr size_t O_memf = 29096192;
  constexpr size_t O_Kz   = 54262016;
  constexpr size_t O_VwoT = 104593664;
  constexpr size_t O_L    = 154925312;
  constexpr size_t NEED   = 217839872;

  if (ws_size < NEED) {
    hipLaunchKernelGGL(diag_ws, dim3((out_size + 255) / 256), dim3(256), 0, stream,
                       (float*)d_out, (float)ws_size, out_size);
    return;
  }

  char* ws = (char*)d_ws;
  unsigned short* wqb  = (unsigned short*)(ws + 0);
  unsigned short* wkb  = wqb + 589824;
  unsigned short* wvb  = wkb + 589824;
  unsigned short* wob  = wvb + 589824;
  unsigned short* rqb  = wob + 589824;
  unsigned short* rkb  = rqb + 589824;
  unsigned short* rvb  = rkb + 589824;
  unsigned short* rob  = rvb + 589824;
  unsigned short* wihb = rob + 589824;
  unsigned short* whhb = wihb + 1769472;
  unsigned short* Fqk  = (unsigned short*)(ws + O_F);
  unsigned short* Fwv  = Fqk + 589824;
  unsigned short* Fvo  = Fwv + 589824;
  unsigned short* Frq  = Fvo + 589824;
  unsigned short* T0   = (unsigned short*)(ws + O_T6);
  unsigned short* T1   = T0 + 589824;
  unsigned short* T2   = T1 + 589824;
  unsigned short* T3   = T2 + 589824;
  unsigned short* T4   = T3 + 589824;
  unsigned short* T5   = T4 + 589824;
  unsigned short* gh0  = (unsigned short*)(ws + O_GH0);
  float* bih_c   = (float*)(ws + O_FL);
  float* bhh_c   = bih_c + 2304;
  float* const_o = bhh_c + 2304;
  float* bvo     = const_o + 768;
  float* vw      = bvo + 768;
  float* vr      = vw + 768;
  float* cw      = vr + 768;
  float* zv      = cw + 64;
  float* colb    = zv + 32768;
  float* memf = (float*)(ws + O_memf);
  unsigned short* Kz    = (unsigned short*)(ws + O_Kz);
  unsigned short* memFr = (unsigned short*)(ws + O_Kz);            // end (Kz dead)
  unsigned short* VwoT  = (unsigned short*)(ws + O_VwoT);
  unsigned short* memVoT  = (unsigned short*)(ws + O_VwoT);             // end
  float*          Sbr     = (float*)(ws + O_VwoT + 25165824);           // end
  unsigned short* Abr     = (unsigned short*)(ws + O_VwoT + 41943040);  // end
  char* L = ws + O_L;
  unsigned short* memb  = (unsigned short*)(L + 0);
  unsigned short* updb  = (unsigned short*)(L + 12582912);
  float*          Sbuf  = (float*)(L + 25165824);
  unsigned short* Abuf  = (unsigned short*)(L + 41943040);
  unsigned short* gib   = (unsigned short*)(L + 25165824);   // (S/A dead)
  unsigned short* ghb   = (unsigned short*)d_out;
  unsigned short* zb    = (unsigned short*)((char*)d_out + 50331648);

  const float scale = 1.0f / sqrtf(768.f);

  // ---- prologue ----
  hipLaunchKernelGGL(cvt_weights, dim3(8064), dim3(256), 0, stream,
      w_wq, w_wk, w_wv, w_wo, r_wq, r_wk, r_wv, r_wo, g_wih, g_whh, wqb);
  hipMemcpyAsync(bih_c, g_bih, 2304 * 4, hipMemcpyDeviceToDevice, stream);
  hipMemcpyAsync(bhh_c, g_bhh, 2304 * 4, hipMemcpyDeviceToDevice, stream);

  {
    TPtrs tp;
    tp.s[0] = wqb; tp.d[0] = T0;
    tp.s[1] = wkb; tp.d[1] = T1;
    tp.s[2] = wvb; tp.d[2] = T2;
    tp.s[3] = rvb; tp.d[3] = T3;
    tp.s[4] = rqb; tp.d[4] = T4;
    tp.s[5] = rkb; tp.d[5] = T5;
    hipLaunchKernelGGL(transpose_multi, dim3(24, 24, 6), dim3(32, 8), 0, stream, tp);
  }
  {
    QuadPtrs qp;
    qp.a[0] = T0;  qp.b[0] = T1; qp.c[0] = Fqk;
    qp.a[1] = wob; qp.b[1] = T2; qp.c[1] = Fwv;
    qp.a[2] = rob; qp.b[2] = T3; qp.c[2] = Fvo;
    qp.a[3] = T4;  qp.b[3] = T5; qp.c[3] = Frq;
    hipLaunchKernelGGL(gemm_nt_quad, dim3(6, 6, 4), dim3(256), 0, stream, qp);
  }

  hipLaunchKernelGGL(matvec_T2, dim3(6), dim3(256), 0, stream,
      w_wk, w_bq, vw, r_wk, r_bq, vr);
  hipLaunchKernelGGL(matvec_row2, dim3(384), dim3(256), 0, stream,
      w_wo, w_bv, w_bo, const_o, r_wo, r_bv, r_bo, bvo);
  hipLaunchKernelGGL(rowdot768, dim3(1), dim3(256), 0, stream,
      w_bq, w_bk, (const float*)nullptr, cw, 1.0f, 1);
  hipLaunchKernelGGL(cvt_z_zv, dim3(8192), dim3(256), 0, stream, z, zb, vw, cw, zv, scale);
  hipLaunchKernelGGL(init_mem, dim3(128, 8), dim3(256), 0, stream,
      slots, ln_g, ln_b, memf, memb);

  // VwoT[b] = Fwv . z_b^T ; Kz = z . Fqk^T
  hipLaunchKernelGGL((gemm_nt64<1, false>), dim3(4, 6, 64), dim3(256), 0, stream,
      Fwv, zb, (const float*)nullptr, (void*)VwoT, 768, 512, 768,
      0ll, 393216ll, 393216ll, 0ll, 1.0f);
  hipLaunchKernelGGL((gemm_nt64<1, false>), dim3(6, 256, 1), dim3(256), 0, stream,
      zb, Fqk, (const float*)nullptr, (void*)Kz, 32768, 768, 768, 0ll, 0ll, 0ll, 0ll, 1.0f);

  const long long sA_g = (long long)(memb - updb);
  const long long sC_g = (long long)(ghb - gib);

  // ---- T=3 recurrence ----
  for (int t = 0; t < 3; ++t) {
    hipLaunchKernelGGL((gemm_nt64<0, true>), dim3(4, 1, 64), dim3(256), 0, stream,
        memb, Kz, zv, (void*)Sbuf, 128, 512, 768,
        98304ll, 393216ll, 65536ll, 512ll, scale);
    hipLaunchKernelGGL(softmax512, dim3(2048), dim3(256), 0, stream, Sbuf, Abuf);
    hipLaunchKernelGGL((gemm_nt64<1, true>), dim3(6, 1, 64), dim3(256), 0, stream,
        Abuf, VwoT, const_o, (void*)updb, 128, 768, 512,
        65536ll, 393216ll, 98304ll, 0ll, 1.0f);
    if (t == 0) {
      hipLaunchKernelGGL((gemm_nt64<1, true>), dim3(18, 1, 1), dim3(256), 0, stream,
          memb, whhb, bhh_c, (void*)gh0, 128, 2304, 768, 0ll, 0ll, 0ll, 0ll, 1.0f);
      hipLaunchKernelGGL((gemm_nt64<1, true>), dim3(18, 64, 1), dim3(256), 0, stream,
          updb, wihb, bih_c, (void*)gib, 8192, 2304, 768, 0ll, 0ll, 0ll, 0ll, 1.0f);
      hipLaunchKernelGGL((gru_ln_combine<true, true>), dim3(8192), dim3(256), 0, stream,
          gib, gh0, memf, ln_g, ln_b, memb);
    } else {
      hipLaunchKernelGGL((gemm_nt64<1, true>), dim3(18, 64, 2), dim3(256), 0, stream,
          updb, wihb, bih_c, (void*)gib, 8192, 2304, 768,
          sA_g, 1769472ll, sC_g, 2304ll, 1.0f);
      if (t < 2)
        hipLaunchKernelGGL((gru_ln_combine<false, true>), dim3(8192), dim3(256), 0, stream,
            gib, ghb, memf, ln_g, ln_b, memb);
      else
        hipLaunchKernelGGL((gru_ln_combine<false, false>), dim3(8192), dim3(256), 0, stream,
            gib, ghb, memf, ln_g, ln_b, memb);
    }
  }
  // memb now holds bf16(mem_final)

  // ---- read attention ----
  hipLaunchKernelGGL((gemm_nt64<1, false>), dim3(6, 64, 1), dim3(256), 0, stream,
      memb, Frq, (const float*)nullptr, (void*)memFr, 8192, 768, 768,
      0ll, 0ll, 0ll, 0ll, 1.0f);
  hipLaunchKernelGGL((gemm_nt64<1, false>), dim3(1, 6, 64), dim3(256), 0, stream,
      Fvo, memb, (const float*)nullptr, (void*)memVoT, 768, 128, 768,
      0ll, 98304ll, 98304ll, 0ll, 1.0f);
  hipLaunchKernelGGL(rowdot768, dim3(2048), dim3(256), 0, stream,
      memf, vr, (const float*)nullptr, colb, scale, 8192);
  hipLaunchKernelGGL((gemm_nt64<0, true>), dim3(1, 4, 64), dim3(256), 0, stream,
      zb, memFr, colb, (void*)Sbr, 512, 128, 768,
      393216ll, 98304ll, 65536ll, 128ll, scale);
  hipLaunchKernelGGL(softmax128, dim3(8192), dim3(256), 0, stream, Sbr, Abr);
  // final: overwrites ALL of d_out (zb/ghb scratch dead from here)
  hipLaunchKernelGGL((gemm_nt64<0, true>), dim3(6, 4, 64), dim3(256), 0, stream,
      Abr, memVoT, bvo, d_out, 512, 768, 128,
      65536ll, 98304ll, 393216ll, 0ll, 1.0f);
}

// Round 13
// 685.607 us; speedup vs baseline: 1.7460x; 1.0766x over previous
//
#include <hip/hip_runtime.h>
#include <hip/hip_bf16.h>
#include <math.h>

// Memory module: E=768, S=128, T=3, B=64, L=512. fp32 in/out.
// bf16 MFMA GEMMs (fp32 accum). Folds: Fqk=Wq^T Wk, Fwv=Wo Wv, Fvo=Ro Rv, Frq=Rq^T Rk.
// gemm_nt64 (BK=64, both-sides XOR swizzle, 32KB LDS) with LOOP-INVARIANT address
// hoisting: LDS read offsets + staging source pointers precomputed (round-12 counters
// showed VALUBusy 50% > MfmaUtil 33% => VALU-bound on swizzle address recompute).
// d_out doubles as scratch: ghb at +0, zb at +48MB; final GEMM overwrites d_out last.

typedef __attribute__((ext_vector_type(4))) float f32x4;
typedef __attribute__((ext_vector_type(8))) short short8;
typedef __attribute__((ext_vector_type(4))) unsigned short us4;

__device__ __forceinline__ unsigned short f2bf(float x) {
  union { float f; unsigned u; } v; v.f = x;
  unsigned r = v.u + 0x7fffu + ((v.u >> 16) & 1u);  // RNE
  return (unsigned short)(r >> 16);
}
__device__ __forceinline__ float bf2f(unsigned short u) {
  union { unsigned u; float f; } v; v.u = (unsigned)u << 16; return v.f;
}

__device__ __forceinline__ void g2l16(const void* g, void* l) {
  __builtin_amdgcn_global_load_lds(
      (const __attribute__((address_space(1))) unsigned int*)g,
      (__attribute__((address_space(3))) unsigned int*)l, 16, 0, 0);
}

__device__ __forceinline__ float wsum(float v) {
#pragma unroll
  for (int o = 32; o > 0; o >>= 1) v += __shfl_xor(v, o, 64);
  return v;
}
__device__ __forceinline__ float wmax(float v) {
#pragma unroll
  for (int o = 32; o > 0; o >>= 1) v = fmaxf(v, __shfl_xor(v, o, 64));
  return v;
}

// m204 bijective XCD swizzle of flattened grid -> (tn, tm, bz)
__device__ __forceinline__ void xcd_map(int& tn, int& tm, long long& bz) {
  const int gx = gridDim.x, gy = gridDim.y, gz = gridDim.z;
  const int nwg = gx * gy * gz;
  const int lin = blockIdx.x + gx * (blockIdx.y + gy * blockIdx.z);
  const int q = nwg >> 3, r = nwg & 7;
  const int xcd = lin & 7, jj = lin >> 3;
  const int w = (xcd < r ? xcd * (q + 1) : r * (q + 1) + (xcd - r) * q) + jj;
  tn = w % gx;
  const int t2 = w / gx;
  tm = t2 % gy;
  bz = t2 / gy;
}

__device__ __forceinline__ void c_write_128(
    void* Cg, size_t cb, int N, int tm, int tn, int wr, int wc, int lane,
    const f32x4 acc[4][4], const float* bias, bool has_bias, float alpha, int omode)
{
#pragma unroll
  for (int a = 0; a < 4; ++a) {
    const int row0 = tm * 128 + wr * 64 + a * 16 + (lane >> 4) * 4;
#pragma unroll
    for (int b = 0; b < 4; ++b) {
      const int col = tn * 128 + wc * 64 + b * 16 + (lane & 15);
      float bv = has_bias ? bias[col] : 0.f;
#pragma unroll
      for (int rr = 0; rr < 4; ++rr) {
        float v = acc[a][b][rr] * alpha + bv;
        if (omode == 0)
          ((float*)Cg)[cb + (size_t)(row0 + rr) * N + col] = v;
        else
          ((unsigned short*)Cg)[cb + (size_t)(row0 + rr) * N + col] = f2bf(v);
      }
    }
  }
}

// ---- m97 128x128 BK=32 body (fold quad only) ----
template<int OMODE, bool BIAS>
__device__ __forceinline__ void gemm_body(
    const unsigned short* __restrict__ A, const unsigned short* __restrict__ B,
    const float* __restrict__ bias, void* __restrict__ Cg, size_t cb,
    int N, int K, int tm, int tn, float alpha,
    unsigned short* As, unsigned short* Bs)
{
  const int tid  = threadIdx.x;
  const int lane = tid & 63;
  const int wv   = tid >> 6;
  const int wr   = wv >> 1, wc = wv & 1;

  A += (size_t)tm * 128 * K;
  B += (size_t)tn * 128 * K;

  const int srow = wv * 16 + (lane >> 2);
  const int kby  = (lane & 3) * 16;

  f32x4 acc[4][4];
#pragma unroll
  for (int a = 0; a < 4; ++a)
#pragma unroll
    for (int b = 0; b < 4; ++b) acc[a][b] = (f32x4)(0.f);

  const int mrow = wr * 64 + (lane & 15);
  const int nrow = wc * 64 + (lane & 15);
  const int koff = (lane >> 4) * 8;

  for (int kt = 0; kt < K; kt += 32) {
#pragma unroll
    for (int i = 0; i < 2; ++i) {
      g2l16((const char*)(A + (size_t)(i * 64 + srow) * K + kt) + kby,
            (char*)As + i * 4096 + wv * 1024);
      g2l16((const char*)(B + (size_t)(i * 64 + srow) * K + kt) + kby,
            (char*)Bs + i * 4096 + wv * 1024);
    }
    __syncthreads();
    short8 af[4], bf[4];
#pragma unroll
    for (int a = 0; a < 4; ++a) af[a] = *(const short8*)&As[(mrow + a * 16) * 32 + koff];
#pragma unroll
    for (int b = 0; b < 4; ++b) bf[b] = *(const short8*)&Bs[(nrow + b * 16) * 32 + koff];
#pragma unroll
    for (int a = 0; a < 4; ++a)
#pragma unroll
      for (int b = 0; b < 4; ++b)
        acc[a][b] = __builtin_amdgcn_mfma_f32_16x16x32_bf16(af[a], bf[b], acc[a][b], 0, 0, 0);
    __syncthreads();
  }
  c_write_128(Cg, cb, N, tm, tn, wr, wc, lane, acc, bias, BIAS, alpha, OMODE);
}

// ---- BK=64 variant with hoisted addresses. 32KB LDS, XOR-swizzled (both sides).
// Requires K%64==0, M%128==0, N%128==0.
template<int OMODE, bool BIAS>
__global__ __launch_bounds__(256) void gemm_nt64(
    const unsigned short* __restrict__ Ag, const unsigned short* __restrict__ Bg,
    const float* __restrict__ bias, void* __restrict__ Cg,
    int M, int N, int K, long long sA, long long sB, long long sC,
    long long sBias, float alpha)
{
  __shared__ __align__(16) unsigned short As[128 * 64];  // 16KB
  __shared__ __align__(16) unsigned short Bs[128 * 64];

  const int tid  = threadIdx.x;
  const int lane = tid & 63;
  const int wv   = tid >> 6;
  const int wr   = wv >> 1, wc = wv & 1;

  int tn, tm; long long bz;
  xcd_map(tn, tm, bz);

  const unsigned short* A = Ag + bz * sA + (size_t)tm * 128 * K;
  const unsigned short* B = Bg + bz * sB + (size_t)tn * 128 * K;

  auto swz = [](int o) { return o ^ (((o >> 7) & 7) << 4); };

  // ---- loop-invariant staging source pointers (pre-swizzled global coords) ----
  const char* aSrc[4];
  const char* bSrc[4];
#pragma unroll
  for (int c = 0; c < 4; ++c) {
    const int olog = swz(c * 4096 + tid * 16);
    const int row = olog >> 7, cbyte = olog & 127;
    aSrc[c] = (const char*)(A + (size_t)row * K) + cbyte;
    bSrc[c] = (const char*)(B + (size_t)row * K) + cbyte;
  }
  // ---- loop-invariant LDS read byte-offsets (static-indexed -> registers) ----
  const int mrow = wr * 64 + (lane & 15);
  const int nrow = wc * 64 + (lane & 15);
  const int kb   = (lane >> 4) * 16;
  int aoff[4][2], boff[4][2];
#pragma unroll
  for (int a = 0; a < 4; ++a)
#pragma unroll
    for (int h = 0; h < 2; ++h) {
      aoff[a][h] = swz((mrow + a * 16) * 128 + h * 64 + kb);
      boff[a][h] = swz((nrow + a * 16) * 128 + h * 64 + kb);
    }

  f32x4 acc[4][4];
#pragma unroll
  for (int a = 0; a < 4; ++a)
#pragma unroll
    for (int b = 0; b < 4; ++b) acc[a][b] = (f32x4)(0.f);

  size_t ktB = 0;  // kt in bytes (64 bf16 = 128B per tile)
  for (int kt = 0; kt < K; kt += 64, ktB += 128) {
#pragma unroll
    for (int c = 0; c < 4; ++c) {
      g2l16(aSrc[c] + ktB, (char*)As + c * 4096 + wv * 1024);
      g2l16(bSrc[c] + ktB, (char*)Bs + c * 4096 + wv * 1024);
    }
    __syncthreads();
#pragma unroll
    for (int h = 0; h < 2; ++h) {
      short8 af[4], bf[4];
#pragma unroll
      for (int a = 0; a < 4; ++a)
        af[a] = *(const short8*)((char*)As + aoff[a][h]);
#pragma unroll
      for (int b = 0; b < 4; ++b)
        bf[b] = *(const short8*)((char*)Bs + boff[b][h]);
#pragma unroll
      for (int a = 0; a < 4; ++a)
#pragma unroll
        for (int b = 0; b < 4; ++b)
          acc[a][b] = __builtin_amdgcn_mfma_f32_16x16x32_bf16(af[a], bf[b], acc[a][b], 0, 0, 0);
    }
    __syncthreads();
  }

  const float* bp = BIAS ? bias + bz * sBias : (const float*)nullptr;
  c_write_128(Cg, (size_t)(bz * sC), N, tm, tn, wr, wc, lane, acc, bp, BIAS, alpha, OMODE);
}

// 4 independent 768^3 NT GEMMs (fold products). bf16 out, no bias.
struct QuadPtrs {
  const unsigned short* a[4];
  const unsigned short* b[4];
  unsigned short* c[4];
};
__global__ __launch_bounds__(256) void gemm_nt_quad(QuadPtrs p) {
  __shared__ __align__(16) unsigned short As[128 * 32];
  __shared__ __align__(16) unsigned short Bs[128 * 32];
  const int zi = blockIdx.z;
  gemm_body<1, false>(p.a[zi], p.b[zi], nullptr, (void*)p.c[zi], 0,
                      768, 768, blockIdx.y, blockIdx.x, 1.0f, As, Bs);
}

// Softmax LR=512: float4 loads, us4 stores. One wave per row.
__global__ __launch_bounds__(256) void softmax512(
    const float* __restrict__ sc, unsigned short* __restrict__ p)
{
  const int row  = blockIdx.x * 4 + (threadIdx.x >> 6);
  const int lane = threadIdx.x & 63;
  const float4* sr = (const float4*)(sc + (size_t)row * 512);
  float4 v[2];
  float m = -1e30f;
#pragma unroll
  for (int j = 0; j < 2; ++j) {
    v[j] = sr[lane + 64 * j];
    m = fmaxf(m, fmaxf(fmaxf(v[j].x, v[j].y), fmaxf(v[j].z, v[j].w)));
  }
  m = wmax(m);
  float s = 0.f;
#pragma unroll
  for (int j = 0; j < 2; ++j) {
    v[j].x = __expf(v[j].x - m); v[j].y = __expf(v[j].y - m);
    v[j].z = __expf(v[j].z - m); v[j].w = __expf(v[j].w - m);
    s += v[j].x + v[j].y + v[j].z + v[j].w;
  }
  s = wsum(s);
  const float inv = 1.f / s;
  us4* pr = (us4*)(p + (size_t)row * 512);
#pragma unroll
  for (int j = 0; j < 2; ++j) {
    us4 o;
    o.x = f2bf(v[j].x * inv); o.y = f2bf(v[j].y * inv);
    o.z = f2bf(v[j].z * inv); o.w = f2bf(v[j].w * inv);
    pr[lane + 64 * j] = o;
  }
}

// Softmax LR=128. One wave per row.
__global__ __launch_bounds__(256) void softmax128(
    const float* __restrict__ sc, unsigned short* __restrict__ p)
{
  const int row  = blockIdx.x * 4 + (threadIdx.x >> 6);
  const int lane = threadIdx.x & 63;
  const float* sr = sc + (size_t)row * 128;
  float v[2];
  float m = -1e30f;
#pragma unroll
  for (int j = 0; j < 2; ++j) { v[j] = sr[lane + 64 * j]; m = fmaxf(m, v[j]); }
  m = wmax(m);
  float s = 0.f;
#pragma unroll
  for (int j = 0; j < 2; ++j) { v[j] = __expf(v[j] - m); s += v[j]; }
  s = wsum(s);
  const float inv = 1.f / s;
  unsigned short* pr = p + (size_t)row * 128;
#pragma unroll
  for (int j = 0; j < 2; ++j) pr[lane + 64 * j] = f2bf(v[j] * inv);
}

// GRU combine with inline LN of old mem (h) + emit next operand.
template<bool GHB, bool EMITLN>
__global__ __launch_bounds__(256) void gru_ln_combine(
    const unsigned short* __restrict__ gi, const unsigned short* __restrict__ gh,
    float* __restrict__ mem, const float* __restrict__ g, const float* __restrict__ b,
    unsigned short* __restrict__ outb)
{
  __shared__ float ps[4], pq[4];
  const size_t row = blockIdx.x;
  const int tid = threadIdx.x, wv = tid >> 6, lane = tid & 63;
  float* mr = mem + row * 768;
  const size_t ghrow = GHB ? (row & 127) : row;
  float v[3];
  float s = 0.f, q = 0.f;
#pragma unroll
  for (int k = 0; k < 3; ++k) {
    v[k] = mr[tid + 256 * k];
    s += v[k]; q += v[k] * v[k];
  }
  s = wsum(s); q = wsum(q);
  if (lane == 0) { ps[wv] = s; pq[wv] = q; }
  __syncthreads();
  s = ps[0] + ps[1] + ps[2] + ps[3];
  q = pq[0] + pq[1] + pq[2] + pq[3];
  const float mu = s * (1.f / 768.f);
  const float rstd = rsqrtf(q * (1.f / 768.f) - mu * mu + 1e-5f);
  float nv[3];
  float s2 = 0.f, q2 = 0.f;
#pragma unroll
  for (int k = 0; k < 3; ++k) {
    const int c = tid + 256 * k;
    const float h = (v[k] - mu) * rstd * g[c] + b[c];
    const float ir  = bf2f(gi[row * 2304 + c]);
    const float iz  = bf2f(gi[row * 2304 + 768 + c]);
    const float in_ = bf2f(gi[row * 2304 + 1536 + c]);
    const float hr  = bf2f(gh[ghrow * 2304 + c]);
    const float hz  = bf2f(gh[ghrow * 2304 + 768 + c]);
    const float hn  = bf2f(gh[ghrow * 2304 + 1536 + c]);
    const float rg = 1.f / (1.f + __expf(-(ir + hr)));
    const float zg = 1.f / (1.f + __expf(-(iz + hz)));
    const float n  = tanhf(in_ + rg * hn);
    nv[k] = (1.f - zg) * n + zg * h;
    mr[c] = nv[k];
    s2 += nv[k]; q2 += nv[k] * nv[k];
  }
  if (EMITLN) {
    s2 = wsum(s2); q2 = wsum(q2);
    __syncthreads();
    if (lane == 0) { ps[wv] = s2; pq[wv] = q2; }
    __syncthreads();
    s2 = ps[0] + ps[1] + ps[2] + ps[3];
    q2 = pq[0] + pq[1] + pq[2] + pq[3];
    const float mu2 = s2 * (1.f / 768.f);
    const float rstd2 = rsqrtf(q2 * (1.f / 768.f) - mu2 * mu2 + 1e-5f);
#pragma unroll
    for (int k = 0; k < 3; ++k) {
      const int c = tid + 256 * k;
      outb[row * 768 + c] = f2bf((nv[k] - mu2) * rstd2 * g[c] + b[c]);
    }
  } else {
#pragma unroll
    for (int k = 0; k < 3; ++k) {
      const int c = tid + 256 * k;
      outb[row * 768 + c] = f2bf(nv[k]);
    }
  }
}

// Merged weight conversion: 10 fp32 sources -> contiguous bf16 region.
__global__ __launch_bounds__(256) void cvt_weights(
    const float* p0, const float* p1, const float* p2, const float* p3,
    const float* p4, const float* p5, const float* p6, const float* p7,
    const float* p8, const float* p9, unsigned short* __restrict__ dst)
{
  const int i = blockIdx.x * 256 + threadIdx.x;  // f4 index, total 2064384
  if (i >= 2064384) return;
  const float* src; int base;
  if      (i < 147456)  { src = p0; base = 0; }
  else if (i < 294912)  { src = p1; base = 147456; }
  else if (i < 442368)  { src = p2; base = 294912; }
  else if (i < 589824)  { src = p3; base = 442368; }
  else if (i < 737280)  { src = p4; base = 589824; }
  else if (i < 884736)  { src = p5; base = 737280; }
  else if (i < 1032192) { src = p6; base = 884736; }
  else if (i < 1179648) { src = p7; base = 1032192; }
  else if (i < 1622016) { src = p8; base = 1179648; }
  else                  { src = p9; base = 1622016; }
  const float4 v = ((const float4*)src)[i - base];
  us4 o;
  o.x = f2bf(v.x); o.y = f2bf(v.y); o.z = f2bf(v.z); o.w = f2bf(v.w);
  ((us4*)dst)[i] = o;
}

// memf[b,s,:] = slots[s,:]; memb[b,s,:] = bf16(LN(slots[s,:])). Grid (128, 8).
__global__ __launch_bounds__(256) void init_mem(
    const float* __restrict__ slots, const float* __restrict__ g,
    const float* __restrict__ b, float* __restrict__ memf,
    unsigned short* __restrict__ memb)
{
  __shared__ float ps[4], pq[4];
  const int s = blockIdx.x;
  const int g0 = blockIdx.y * 8;
  const int tid = threadIdx.x, wv = tid >> 6, lane = tid & 63;
  const float* sr = slots + (size_t)s * 768;
  float v[3];
  float su = 0.f, qu = 0.f;
#pragma unroll
  for (int k = 0; k < 3; ++k) { v[k] = sr[tid + 256 * k]; su += v[k]; qu += v[k] * v[k]; }
  su = wsum(su); qu = wsum(qu);
  if (lane == 0) { ps[wv] = su; pq[wv] = qu; }
  __syncthreads();
  su = ps[0] + ps[1] + ps[2] + ps[3];
  qu = pq[0] + pq[1] + pq[2] + pq[3];
  const float mu = su * (1.f / 768.f);
  const float rstd = rsqrtf(qu * (1.f / 768.f) - mu * mu + 1e-5f);
  unsigned short lb[3];
#pragma unroll
  for (int k = 0; k < 3; ++k) {
    const int c = tid + 256 * k;
    lb[k] = f2bf((v[k] - mu) * rstd * g[c] + b[c]);
  }
  for (int bb = g0; bb < g0 + 8; ++bb) {
    float* mrow = memf + ((size_t)bb * 128 + s) * 768;
    unsigned short* brow = memb + ((size_t)bb * 128 + s) * 768;
#pragma unroll
    for (int k = 0; k < 3; ++k) { mrow[tid + 256 * k] = v[k]; brow[tid + 256 * k] = lb[k]; }
  }
}

// 6 independent 768x768 transposes in one launch (weight prologue only).
struct TPtrs { const unsigned short* s[6]; unsigned short* d[6]; };
__global__ void transpose_multi(TPtrs p) {
  __shared__ unsigned short t[32][33];
  const unsigned short* in = p.s[blockIdx.z];
  unsigned short* out = p.d[blockIdx.z];
  const int c0 = blockIdx.x * 32, r0 = blockIdx.y * 32;
  const int x = threadIdx.x, y = threadIdx.y;
#pragma unroll
  for (int k = 0; k < 32; k += 8)
    t[y + k][x] = in[(size_t)(r0 + y + k) * 768 + c0 + x];
  __syncthreads();
#pragma unroll
  for (int k = 0; k < 32; k += 8)
    out[(size_t)(c0 + y + k) * 768 + r0 + x] = t[x][y + k];
}

// Two y[row] = dot(Tmat[row,:], x) jobs over bf16 row-major mats (wave per row).
__global__ __launch_bounds__(256) void matvec_row2b(
    const unsigned short* __restrict__ A0, const float* __restrict__ x0,
    float* __restrict__ y0,
    const unsigned short* __restrict__ A1, const float* __restrict__ x1,
    float* __restrict__ y1)
{
  const int task = blockIdx.x / 192;
  const int row = (blockIdx.x % 192) * 4 + (threadIdx.x >> 6);
  const int lane = threadIdx.x & 63;
  const unsigned short* r = (task ? A1 : A0) + (size_t)row * 768;
  const float* x = task ? x1 : x0;
  float s = 0.f;
#pragma unroll
  for (int j = 0; j < 12; ++j) s += bf2f(r[lane + 64 * j]) * x[lane + 64 * j];
  s = wsum(s);
  if (lane == 0) (task ? y1 : y0)[row] = s;
}

// Two y[row]=add[row]+dot(W[row,:],x) fp32 jobs (grid 384: task = bx/192).
__global__ __launch_bounds__(256) void matvec_row2(
    const float* __restrict__ W0, const float* __restrict__ x0,
    const float* __restrict__ a0, float* __restrict__ y0,
    const float* __restrict__ W1, const float* __restrict__ x1,
    const float* __restrict__ a1, float* __restrict__ y1)
{
  const int task = blockIdx.x / 192;
  const int row = (blockIdx.x % 192) * 4 + (threadIdx.x >> 6);
  const int lane = threadIdx.x & 63;
  const float* W = task ? W1 : W0;
  const float* x = task ? x1 : x0;
  const float* ad = task ? a1 : a0;
  float* y = task ? y1 : y0;
  const float4* r = (const float4*)(W + (size_t)row * 768);
  const float4* xv = (const float4*)x;
  float s = 0.f;
#pragma unroll
  for (int j = 0; j < 3; ++j) {
    const float4 a = r[lane + 64 * j], c = xv[lane + 64 * j];
    s += a.x * c.x + a.y * c.y + a.z * c.z + a.w * c.w;
  }
  s = wsum(s);
  if (lane == 0) y[row] = s + ad[row];
}

// out[i] = scl * (dot(src_i, vec) + (cadd ? cadd[0] : 0)). float4 loads.
__global__ __launch_bounds__(256) void rowdot768(
    const float* __restrict__ src, const float* __restrict__ vec,
    const float* __restrict__ cadd, float* __restrict__ out, float scl, int rows)
{
  const int row  = blockIdx.x * 4 + (threadIdx.x >> 6);
  if (row >= rows) return;
  const int lane = threadIdx.x & 63;
  const float4* r = (const float4*)(src + (size_t)row * 768);
  const float4* vv = (const float4*)vec;
  float s = 0.f;
#pragma unroll
  for (int j = 0; j < 3; ++j) {
    const float4 a = r[lane + 64 * j], c = vv[lane + 64 * j];
    s += a.x * c.x + a.y * c.y + a.z * c.z + a.w * c.w;
  }
  s = wsum(s);
  if (lane == 0) out[row] = scl * (s + (cadd ? cadd[0] : 0.f));
}

// Fused: zb = bf16(z) AND zv[row] = scl*(dot(z_row, vw) + cw[0]). float4 loads.
__global__ __launch_bounds__(256) void cvt_z_zv(
    const float* __restrict__ z, unsigned short* __restrict__ zb,
    const float* __restrict__ vw, const float* __restrict__ cw,
    float* __restrict__ zv, float scl)
{
  const int row = blockIdx.x * 4 + (threadIdx.x >> 6);
  const int lane = threadIdx.x & 63;
  const float4* zr = (const float4*)(z + (size_t)row * 768);
  const float4* wv = (const float4*)vw;
  us4* zbr = (us4*)(zb + (size_t)row * 768);
  float s = 0.f;
#pragma unroll
  for (int j = 0; j < 3; ++j) {
    const float4 v = zr[lane + 64 * j];
    const float4 w = wv[lane + 64 * j];
    s += v.x * w.x + v.y * w.y + v.z * w.z + v.w * w.w;
    us4 o;
    o.x = f2bf(v.x); o.y = f2bf(v.y); o.z = f2bf(v.z); o.w = f2bf(v.w);
    zbr[lane + 64 * j] = o;
  }
  s = wsum(s);
  if (lane == 0) zv[row] = scl * (s + cw[0]);
}

__global__ __launch_bounds__(256) void diag_ws(float* __restrict__ out, float wsz, int n) {
  const int i = blockIdx.x * 256 + threadIdx.x;
  if (i < n) out[i] = (i == 0) ? wsz : 0.f;
}

extern "C" void kernel_launch(void* const* d_in, const int* in_sizes, int n_in,
                              void* d_out, int out_size, void* d_ws, size_t ws_size,
                              hipStream_t stream)
{
  const float* z     = (const float*)d_in[0];
  const float* slots = (const float*)d_in[1];
  const float* ln_g  = (const float*)d_in[2];
  const float* ln_b  = (const float*)d_in[3];
  const float* w_wq = (const float*)d_in[4];  const float* w_bq = (const float*)d_in[5];
  const float* w_wk = (const float*)d_in[6];  const float* w_bk = (const float*)d_in[7];
  const float* w_wv = (const float*)d_in[8];  const float* w_bv = (const float*)d_in[9];
  const float* w_wo = (const float*)d_in[10]; const float* w_bo = (const float*)d_in[11];
  const float* r_wq = (const float*)d_in[12]; const float* r_bq = (const float*)d_in[13];
  const float* r_wk = (const float*)d_in[14]; const float* r_bk = (const float*)d_in[15];
  const float* r_wv = (const float*)d_in[16]; const float* r_bv = (const float*)d_in[17];
  const float* r_wo = (const float*)d_in[18]; const float* r_bo = (const float*)d_in[19];
  const float* g_wih = (const float*)d_in[20]; const float* g_bih = (const float*)d_in[21];
  const float* g_whh = (const float*)d_in[22]; const float* g_bhh = (const float*)d_in[23];

  // ---- arena (bytes) ----
  constexpr size_t O_F    = 16515072;
  constexpr size_t O_T6   = 21233664;
  constexpr size_t O_GH0  = 28311552;
  constexpr size_t O_FL   = 28901376;
  constexpr size_t O_memf = 29096192;
  constexpr size_t O_Kz   = 54262016;
  constexpr size_t O_VwoT = 104593664;
  constexpr size_t O_L    = 154925312;
  constexpr size_t NEED   = 217839872;

  if (ws_size < NEED) {
    hipLaunchKernelGGL(diag_ws, dim3((out_size + 255) / 256), dim3(256), 0, stream,
                       (float*)d_out, (float)ws_size, out_size);
    return;
  }

  char* ws = (char*)d_ws;
  unsigned short* wqb  = (unsigned short*)(ws + 0);
  unsigned short* wkb  = wqb + 589824;
  unsigned short* wvb  = wkb + 589824;
  unsigned short* wob  = wvb + 589824;
  unsigned short* rqb  = wob + 589824;
  unsigned short* rkb  = rqb + 589824;
  unsigned short* rvb  = rkb + 589824;
  unsigned short* rob  = rvb + 589824;
  unsigned short* wihb = rob + 589824;
  unsigned short* whhb = wihb + 1769472;
  unsigned short* Fqk  = (unsigned short*)(ws + O_F);
  unsigned short* Fwv  = Fqk + 589824;
  unsigned short* Fvo  = Fwv + 589824;
  unsigned short* Frq  = Fvo + 589824;
  unsigned short* T0   = (unsigned short*)(ws + O_T6);
  unsigned short* T1   = T0 + 589824;
  unsigned short* T2   = T1 + 589824;
  unsigned short* T3   = T2 + 589824;
  unsigned short* T4   = T3 + 589824;
  unsigned short* T5   = T4 + 589824;
  unsigned short* gh0  = (unsigned short*)(ws + O_GH0);
  float* bih_c   = (float*)(ws + O_FL);
  float* bhh_c   = bih_c + 2304;
  float* const_o = bhh_c + 2304;
  float* bvo     = const_o + 768;
  float* vw      = bvo + 768;
  float* vr      = vw + 768;
  float* cw      = vr + 768;
  float* zv      = cw + 64;
  float* colb    = zv + 32768;
  float* memf = (float*)(ws + O_memf);
  unsigned short* Kz    = (unsigned short*)(ws + O_Kz);
  unsigned short* memFr = (unsigned short*)(ws + O_Kz);            // end (Kz dead)
  unsigned short* VwoT  = (unsigned short*)(ws + O_VwoT);
  unsigned short* memVoT  = (unsigned short*)(ws + O_VwoT);             // end
  float*          Sbr     = (float*)(ws + O_VwoT + 25165824);           // end
  unsigned short* Abr     = (unsigned short*)(ws + O_VwoT + 41943040);  // end
  char* L = ws + O_L;
  unsigned short* memb  = (unsigned short*)(L + 0);
  unsigned short* updb  = (unsigned short*)(L + 12582912);
  float*          Sbuf  = (float*)(L + 25165824);
  unsigned short* Abuf  = (unsigned short*)(L + 41943040);
  unsigned short* gib   = (unsigned short*)(L + 25165824);   // (S/A dead)
  unsigned short* ghb   = (unsigned short*)d_out;
  unsigned short* zb    = (unsigned short*)((char*)d_out + 50331648);

  const float scale = 1.0f / sqrtf(768.f);

  // ---- prologue ----
  hipLaunchKernelGGL(cvt_weights, dim3(8064), dim3(256), 0, stream,
      w_wq, w_wk, w_wv, w_wo, r_wq, r_wk, r_wv, r_wo, g_wih, g_whh, wqb);
  hipMemcpyAsync(bih_c, g_bih, 2304 * 4, hipMemcpyDeviceToDevice, stream);
  hipMemcpyAsync(bhh_c, g_bhh, 2304 * 4, hipMemcpyDeviceToDevice, stream);

  {
    TPtrs tp;
    tp.s[0] = wqb; tp.d[0] = T0;
    tp.s[1] = wkb; tp.d[1] = T1;
    tp.s[2] = wvb; tp.d[2] = T2;
    tp.s[3] = rvb; tp.d[3] = T3;
    tp.s[4] = rqb; tp.d[4] = T4;
    tp.s[5] = rkb; tp.d[5] = T5;
    hipLaunchKernelGGL(transpose_multi, dim3(24, 24, 6), dim3(32, 8), 0, stream, tp);
  }
  {
    QuadPtrs qp;
    qp.a[0] = T0;  qp.b[0] = T1; qp.c[0] = Fqk;
    qp.a[1] = wob; qp.b[1] = T2; qp.c[1] = Fwv;
    qp.a[2] = rob; qp.b[2] = T3; qp.c[2] = Fvo;
    qp.a[3] = T4;  qp.b[3] = T5; qp.c[3] = Frq;
    hipLaunchKernelGGL(gemm_nt_quad, dim3(6, 6, 4), dim3(256), 0, stream, qp);
  }

  // vw = Wk^T bq via T1 (bf16), vr = Rk^T bq_r via T5 (bf16) — wave-row dots
  hipLaunchKernelGGL(matvec_row2b, dim3(384), dim3(256), 0, stream,
      T1, w_bq, vw, T5, r_bq, vr);
  hipLaunchKernelGGL(matvec_row2, dim3(384), dim3(256), 0, stream,
      w_wo, w_bv, w_bo, const_o, r_wo, r_bv, r_bo, bvo);
  hipLaunchKernelGGL(rowdot768, dim3(1), dim3(256), 0, stream,
      w_bq, w_bk, (const float*)nullptr, cw, 1.0f, 1);
  hipLaunchKernelGGL(cvt_z_zv, dim3(8192), dim3(256), 0, stream, z, zb, vw, cw, zv, scale);
  hipLaunchKernelGGL(init_mem, dim3(128, 8), dim3(256), 0, stream,
      slots, ln_g, ln_b, memf, memb);

  // VwoT[b] = Fwv . z_b^T ; Kz = z . Fqk^T
  hipLaunchKernelGGL((gemm_nt64<1, false>), dim3(4, 6, 64), dim3(256), 0, stream,
      Fwv, zb, (const float*)nullptr, (void*)VwoT, 768, 512, 768,
      0ll, 393216ll, 393216ll, 0ll, 1.0f);
  hipLaunchKernelGGL((gemm_nt64<1, false>), dim3(6, 256, 1), dim3(256), 0, stream,
      zb, Fqk, (const float*)nullptr, (void*)Kz, 32768, 768, 768, 0ll, 0ll, 0ll, 0ll, 1.0f);

  const long long sA_g = (long long)(memb - updb);
  const long long sC_g = (long long)(ghb - gib);

  // ---- T=3 recurrence ----
  for (int t = 0; t < 3; ++t) {
    hipLaunchKernelGGL((gemm_nt64<0, true>), dim3(4, 1, 64), dim3(256), 0, stream,
        memb, Kz, zv, (void*)Sbuf, 128, 512, 768,
        98304ll, 393216ll, 65536ll, 512ll, scale);
    hipLaunchKernelGGL(softmax512, dim3(2048), dim3(256), 0, stream, Sbuf, Abuf);
    hipLaunchKernelGGL((gemm_nt64<1, true>), dim3(6, 1, 64), dim3(256), 0, stream,
        Abuf, VwoT, const_o, (void*)updb, 128, 768, 512,
        65536ll, 393216ll, 98304ll, 0ll, 1.0f);
    if (t == 0) {
      hipLaunchKernelGGL((gemm_nt64<1, true>), dim3(18, 1, 1), dim3(256), 0, stream,
          memb, whhb, bhh_c, (void*)gh0, 128, 2304, 768, 0ll, 0ll, 0ll, 0ll, 1.0f);
      hipLaunchKernelGGL((gemm_nt64<1, true>), dim3(18, 64, 1), dim3(256), 0, stream,
          updb, wihb, bih_c, (void*)gib, 8192, 2304, 768, 0ll, 0ll, 0ll, 0ll, 1.0f);
      hipLaunchKernelGGL((gru_ln_combine<true, true>), dim3(8192), dim3(256), 0, stream,
          gib, gh0, memf, ln_g, ln_b, memb);
    } else {
      hipLaunchKernelGGL((gemm_nt64<1, true>), dim3(18, 64, 2), dim3(256), 0, stream,
          updb, wihb, bih_c, (void*)gib, 8192, 2304, 768,
          sA_g, 1769472ll, sC_g, 2304ll, 1.0f);
      if (t < 2)
        hipLaunchKernelGGL((gru_ln_combine<false, true>), dim3(8192), dim3(256), 0, stream,
            gib, ghb, memf, ln_g, ln_b, memb);
      else
        hipLaunchKernelGGL((gru_ln_combine<false, false>), dim3(8192), dim3(256), 0, stream,
            gib, ghb, memf, ln_g, ln_b, memb);
    }
  }
  // memb now holds bf16(mem_final)

  // ---- read attention ----
  hipLaunchKernelGGL((gemm_nt64<1, false>), dim3(6, 64, 1), dim3(256), 0, stream,
      memb, Frq, (const float*)nullptr, (void*)memFr, 8192, 768, 768,
      0ll, 0ll, 0ll, 0ll, 1.0f);
  hipLaunchKernelGGL((gemm_nt64<1, false>), dim3(1, 6, 64), dim3(256), 0, stream,
      Fvo, memb, (const float*)nullptr, (void*)memVoT, 768, 128, 768,
      0ll, 98304ll, 98304ll, 0ll, 1.0f);
  hipLaunchKernelGGL(rowdot768, dim3(2048), dim3(256), 0, stream,
      memf, vr, (const float*)nullptr, colb, scale, 8192);
  hipLaunchKernelGGL((gemm_nt64<0, true>), dim3(1, 4, 64), dim3(256), 0, stream,
      zb, memFr, colb, (void*)Sbr, 512, 128, 768,
      393216ll, 98304ll, 65536ll, 128ll, scale);
  hipLaunchKernelGGL(softmax128, dim3(8192), dim3(256), 0, stream, Sbr, Abr);
  // final: overwrites ALL of d_out (zb/ghb scratch dead from here)
  hipLaunchKernelGGL((gemm_nt64<0, true>), dim3(6, 4, 64), dim3(256), 0, stream,
      Abr, memVoT, bvo, d_out, 512, 768, 128,
      65536ll, 98304ll, 393216ll, 0ll, 1.0f);
}